// Round 1
// baseline (2049.897 us; speedup 1.0000x reference)
//
#include <hip/hip_runtime.h>
#include <math.h>

#define L_SEQ   2048
#define NBATCH  2
#define DMODEL  1024
#define DHALF   512
#define DINNER  1024
#define DSTATE  128
#define NHEADS  16
#define HEADDIM 64
#define CONVDIM 1280
#define DINPROJ 2320
#define ROWS    4096  /* NBATCH * L_SEQ */

__device__ __forceinline__ float siluf(float v){ return v / (1.f + expf(-v)); }
__device__ __forceinline__ float softplusf(float v){ return v > 20.f ? v : log1pf(expf(v)); }

__device__ __forceinline__ float blockReduceSum256(float v, float* red){
  #pragma unroll
  for (int o = 32; o > 0; o >>= 1) v += __shfl_xor(v, o);
  int wid = threadIdx.x >> 6, lane = threadIdx.x & 63;
  if (lane == 0) red[wid] = v;
  __syncthreads();
  return red[0] + red[1] + red[2] + red[3];
}

// ---------------- rmsnorm + split into u_f and (pre-flipped) u_b ----------------
__global__ void rmsnorm_split_kernel(const float* __restrict__ x, const float* __restrict__ nw,
                                     float* __restrict__ uf, float* __restrict__ ub){
  __shared__ float red[4];
  int row = blockIdx.x;                       // b*L + t
  const float* xr = x + (size_t)row * DMODEL;
  float loc[4]; float ss = 0.f;
  #pragma unroll
  for (int k = 0; k < 4; k++){ float v = xr[threadIdx.x + k*256]; loc[k] = v; ss += v*v; }
  ss = blockReduceSum256(ss, red);
  float scale = rsqrtf(ss * (1.f/DMODEL) + 1e-5f);
  int t = row & (L_SEQ-1);
  int fliprow = (row ^ t) | (L_SEQ-1-t);
  #pragma unroll
  for (int k = 0; k < 4; k++){
    int d = threadIdx.x + k*256;
    float v = loc[k] * scale * nw[d];
    if (d < DHALF) uf[(size_t)row*DHALF + d] = v;
    else           ub[(size_t)fliprow*DHALF + (d - DHALF)] = v;
  }
}

// ---------------- generic fp32 GEMM: C[m, coff+n] = sum_k A[m,k]*Bw[n,k] (+bias+res) ----
// A: M x K row-major. Bw: N x K row-major. C uses ldc; optional flip of time index
// within each batch of L_SEQ rows. res (if set) indexed like C.
__global__ __launch_bounds__(256) void gemm_nt_kernel(
    const float* __restrict__ A, const float* __restrict__ Bw, float* __restrict__ C,
    int M, int N, int K, int ldc, int coff, int flip,
    const float* __restrict__ bias, const float* __restrict__ res){
  __shared__ __align__(16) float As[16][68];
  __shared__ __align__(16) float Bs[16][68];
  int bm = blockIdx.y * 64, bn = blockIdx.x * 64;
  int tid = threadIdx.x;
  int tx = tid & 15, ty = tid >> 4;
  int arow = tid >> 2, ac4 = (tid & 3) * 4;
  float acc[4][4] = {};
  for (int k0 = 0; k0 < K; k0 += 16){
    float4 av = *(const float4*)(A + (size_t)(bm + arow)*K + k0 + ac4);
    int gn = bn + arow;
    float4 bv = make_float4(0.f,0.f,0.f,0.f);
    if (gn < N) bv = *(const float4*)(Bw + (size_t)gn*K + k0 + ac4);
    As[ac4+0][arow]=av.x; As[ac4+1][arow]=av.y; As[ac4+2][arow]=av.z; As[ac4+3][arow]=av.w;
    Bs[ac4+0][arow]=bv.x; Bs[ac4+1][arow]=bv.y; Bs[ac4+2][arow]=bv.z; Bs[ac4+3][arow]=bv.w;
    __syncthreads();
    #pragma unroll
    for (int kk = 0; kk < 16; kk++){
      float4 aa = *(const float4*)&As[kk][ty*4];
      float4 bb = *(const float4*)&Bs[kk][tx*4];
      float a_[4] = {aa.x, aa.y, aa.z, aa.w};
      float b_[4] = {bb.x, bb.y, bb.z, bb.w};
      #pragma unroll
      for (int i = 0; i < 4; i++)
        #pragma unroll
        for (int j = 0; j < 4; j++)
          acc[i][j] += a_[i] * b_[j];
    }
    __syncthreads();
  }
  #pragma unroll
  for (int i = 0; i < 4; i++){
    int m = bm + ty*4 + i;
    int mo = m;
    if (flip){ int t = m & (L_SEQ-1); mo = (m ^ t) | (L_SEQ-1-t); }
    #pragma unroll
    for (int j = 0; j < 4; j++){
      int n = bn + tx*4 + j;
      if (n < N){
        float v = acc[i][j];
        if (bias) v += bias[n];
        if (res)  v += res[(size_t)mo*ldc + coff + n];
        C[(size_t)mo*ldc + coff + n] = v;
      }
    }
  }
}

// ---------------- causal depthwise conv (k=4) + silu over xBC channels ----------------
__global__ void conv_silu_kernel(const float* __restrict__ zxf, const float* __restrict__ zxb,
                                 const float* __restrict__ cwf, const float* __restrict__ cbf,
                                 const float* __restrict__ cwb, const float* __restrict__ cbb,
                                 float* __restrict__ cvf, float* __restrict__ cvb){
  int row = blockIdx.x; int dir = blockIdx.y;
  const float* zx = dir ? zxb : zxf;
  const float* cw = dir ? cwb : cwf;
  const float* cb = dir ? cbb : cbf;
  float* cv = dir ? cvb : cvf;
  int t = row & (L_SEQ-1);
  for (int c = threadIdx.x; c < CONVDIM; c += 256){
    const float* base = zx + (size_t)row*DINPROJ + DINNER + c;
    float v = cb[c];
    if (t >= 1) v += base[-1*(ptrdiff_t)DINPROJ] * cw[c*4+2];
    if (t >= 2) v += base[-2*(ptrdiff_t)DINPROJ] * cw[c*4+1];
    if (t >= 3) v += base[-3*(ptrdiff_t)DINPROJ] * cw[c*4+0];
    v += base[0] * cw[c*4+3];
    cv[(size_t)row*CONVDIM + c] = siluf(v);
  }
}

// ---------------- dt softplus + dA = exp(dt*A) ----------------
__global__ void dtprep_kernel(const float* __restrict__ zxf, const float* __restrict__ zxb,
                              const float* __restrict__ dbf, const float* __restrict__ alf,
                              const float* __restrict__ dbb, const float* __restrict__ alb,
                              float* __restrict__ dtf, float* __restrict__ dtb,
                              float* __restrict__ dAf, float* __restrict__ dAb){
  int idx = blockIdx.x*256 + threadIdx.x;   // 0 .. 2*ROWS*NHEADS-1
  int dir = idx >> 16;
  int r = idx & 65535;
  int h = r & 15, row = r >> 4;
  const float* zx = dir ? zxb : zxf;
  float raw = zx[(size_t)row*DINPROJ + DINNER + CONVDIM + h];
  float bias = (dir ? dbb : dbf)[h];
  float dtv = softplusf(raw + bias);
  float a = -expf((dir ? alb : alf)[h]);
  float dAv = expf(dtv * a);
  (dir ? dtb : dtf)[r] = dtv;
  (dir ? dAb : dAf)[r] = dAv;
}

// ---------------- sequential selective scan ----------------
// 64 wgs = (dir, b, h); 512 threads: p = tid>>3 (0..63), 16 n-values each.
__global__ __launch_bounds__(512) void scan_kernel(
    const float* __restrict__ cvf, const float* __restrict__ cvb,
    const float* __restrict__ dtf, const float* __restrict__ dtb,
    const float* __restrict__ dAf, const float* __restrict__ dAb,
    const float* __restrict__ Df,  const float* __restrict__ Db,
    float* __restrict__ yf, float* __restrict__ yb){
  int wg = blockIdx.x;
  int dir = wg >> 5;
  int b = (wg >> 4) & 1;
  int h = wg & 15;
  const float* cv  = dir ? cvb : cvf;
  const float* dtp = dir ? dtb : dtf;
  const float* dAp = dir ? dAb : dAf;
  float* y = dir ? yb : yf;
  float Dh = (dir ? Db : Df)[h];
  int tid = threadIdx.x;
  int p = tid >> 3, nb = tid & 7, n0 = nb * 16;
  float hreg[16];
  #pragma unroll
  for (int j = 0; j < 16; j++) hreg[j] = 0.f;
  __shared__ float sB[2][DSTATE], sC[2][DSTATE], sx[2][HEADDIM];
  size_t rowbase = (size_t)b * L_SEQ;
  { // stage t = 0
    size_t cbase = rowbase * CONVDIM;
    if (tid < 128)      sB[0][tid]     = cv[cbase + DINNER + tid];
    else if (tid < 256) sC[0][tid-128] = cv[cbase + DINNER + DSTATE + (tid-128)];
    else if (tid < 320) sx[0][tid-256] = cv[cbase + h*HEADDIM + (tid-256)];
  }
  __syncthreads();
  for (int t = 0; t < L_SEQ; ++t){
    int buf = t & 1;
    if (t + 1 < L_SEQ){
      size_t cbase = (rowbase + t + 1) * CONVDIM;
      if (tid < 128)      sB[buf^1][tid]     = cv[cbase + DINNER + tid];
      else if (tid < 256) sC[buf^1][tid-128] = cv[cbase + DINNER + DSTATE + (tid-128)];
      else if (tid < 320) sx[buf^1][tid-256] = cv[cbase + h*HEADDIM + (tid-256)];
    }
    float dtv = dtp[(rowbase + t)*NHEADS + h];
    float dAv = dAp[(rowbase + t)*NHEADS + h];
    float xv = sx[buf][p];
    float dtx = dtv * xv;
    float acc = 0.f;
    #pragma unroll
    for (int j = 0; j < 16; j++){
      float hv = dAv*hreg[j] + dtx*sB[buf][n0+j];
      hreg[j] = hv;
      acc += hv * sC[buf][n0+j];
    }
    acc += __shfl_xor(acc, 1);
    acc += __shfl_xor(acc, 2);
    acc += __shfl_xor(acc, 4);
    if (nb == 0) y[(rowbase + t)*DINNER + h*HEADDIM + p] = acc + Dh*xv;
    __syncthreads();
  }
}

// ---------------- gate (silu(z)) + rmsnorm, in place on y ----------------
__global__ void gate_norm_kernel(float* __restrict__ yf, float* __restrict__ yb,
                                 const float* __restrict__ zxf, const float* __restrict__ zxb,
                                 const float* __restrict__ gwf, const float* __restrict__ gwb){
  __shared__ float red[4];
  int row = blockIdx.x; int dir = blockIdx.y;
  float* y = (dir ? yb : yf) + (size_t)row*DINNER;
  const float* zx = (dir ? zxb : zxf) + (size_t)row*DINPROJ;
  const float* gw = dir ? gwb : gwf;
  float v[4]; float ss = 0.f;
  #pragma unroll
  for (int k = 0; k < 4; k++){
    int d = threadIdx.x + k*256;
    float val = y[d] * siluf(zx[d]);
    v[k] = val; ss += val*val;
  }
  ss = blockReduceSum256(ss, red);
  float scale = rsqrtf(ss*(1.f/DINNER) + 1e-5f);
  #pragma unroll
  for (int k = 0; k < 4; k++){
    int d = threadIdx.x + k*256;
    y[d] = v[k]*scale*gw[d];
  }
}

extern "C" void kernel_launch(void* const* d_in, const int* in_sizes, int n_in,
                              void* d_out, int out_size, void* d_ws, size_t ws_size,
                              hipStream_t stream) {
  const float* x      = (const float*)d_in[0];
  const float* norm_w = (const float*)d_in[1];
  const float* op_w   = (const float*)d_in[2];
  const float* op_b   = (const float*)d_in[3];
  const float* f_in_w    = (const float*)d_in[4];
  const float* f_conv_w  = (const float*)d_in[5];
  const float* f_conv_b  = (const float*)d_in[6];
  const float* f_dt_bias = (const float*)d_in[7];
  const float* f_A_log   = (const float*)d_in[8];
  const float* f_D       = (const float*)d_in[9];
  const float* f_gnorm_w = (const float*)d_in[10];
  const float* f_outp_w  = (const float*)d_in[11];
  const float* b_in_w    = (const float*)d_in[12];
  const float* b_conv_w  = (const float*)d_in[13];
  const float* b_conv_b  = (const float*)d_in[14];
  const float* b_dt_bias = (const float*)d_in[15];
  const float* b_A_log   = (const float*)d_in[16];
  const float* b_D       = (const float*)d_in[17];
  const float* b_gnorm_w = (const float*)d_in[18];
  const float* b_outp_w  = (const float*)d_in[19];
  float* out = (float*)d_out;

  float* ws = (float*)d_ws;
  size_t off = 0;
  float* u_f  = ws + off; off += (size_t)ROWS*DHALF;
  float* u_b  = ws + off; off += (size_t)ROWS*DHALF;
  float* zx_f = ws + off; off += (size_t)ROWS*DINPROJ;
  float* zx_b = ws + off; off += (size_t)ROWS*DINPROJ;
  float* cv_f = ws + off; off += (size_t)ROWS*CONVDIM;
  float* cv_b = ws + off; off += (size_t)ROWS*CONVDIM;
  float* dt_f = ws + off; off += (size_t)ROWS*NHEADS;
  float* dt_b = ws + off; off += (size_t)ROWS*NHEADS;
  float* dA_f = ws + off; off += (size_t)ROWS*NHEADS;
  float* dA_b = ws + off; off += (size_t)ROWS*NHEADS;
  float* y_f  = ws + off; off += (size_t)ROWS*DINNER;
  float* y_b  = ws + off; off += (size_t)ROWS*DINNER;
  float* cat  = ws + off; off += (size_t)ROWS*DINNER;

  // 1. rmsnorm + split (+pre-flip backward input)
  rmsnorm_split_kernel<<<ROWS, 256, 0, stream>>>(x, norm_w, u_f, u_b);
  // 2-3. in-proj GEMMs: [4096 x 512] @ [2320 x 512]^T
  gemm_nt_kernel<<<dim3((DINPROJ+63)/64, ROWS/64), 256, 0, stream>>>(
      u_f, f_in_w, zx_f, ROWS, DINPROJ, DHALF, DINPROJ, 0, 0, nullptr, nullptr);
  gemm_nt_kernel<<<dim3((DINPROJ+63)/64, ROWS/64), 256, 0, stream>>>(
      u_b, b_in_w, zx_b, ROWS, DINPROJ, DHALF, DINPROJ, 0, 0, nullptr, nullptr);
  // 4. conv + silu
  conv_silu_kernel<<<dim3(ROWS, 2), 256, 0, stream>>>(
      zx_f, zx_b, f_conv_w, f_conv_b, b_conv_w, b_conv_b, cv_f, cv_b);
  // 5. dt / dA
  dtprep_kernel<<<(2*ROWS*NHEADS)/256, 256, 0, stream>>>(
      zx_f, zx_b, f_dt_bias, f_A_log, b_dt_bias, b_A_log, dt_f, dt_b, dA_f, dA_b);
  // 6. scan
  scan_kernel<<<64, 512, 0, stream>>>(cv_f, cv_b, dt_f, dt_b, dA_f, dA_b,
                                      f_D, b_D, y_f, y_b);
  // 7. gate + rmsnorm (in place)
  gate_norm_kernel<<<dim3(ROWS, 2), 256, 0, stream>>>(
      y_f, y_b, zx_f, zx_b, f_gnorm_w, b_gnorm_w);
  // 8-9. out-proj GEMMs into concat buffer (backward written time-flipped)
  gemm_nt_kernel<<<dim3(DHALF/64, ROWS/64), 256, 0, stream>>>(
      y_f, f_outp_w, cat, ROWS, DHALF, DINNER, DMODEL, 0, 0, nullptr, nullptr);
  gemm_nt_kernel<<<dim3(DHALF/64, ROWS/64), 256, 0, stream>>>(
      y_b, b_outp_w, cat, ROWS, DHALF, DINNER, DMODEL, DHALF, 1, nullptr, nullptr);
  // 10. final projection + bias + residual
  gemm_nt_kernel<<<dim3(DMODEL/64, ROWS/64), 256, 0, stream>>>(
      cat, op_w, out, ROWS, DMODEL, DMODEL, DMODEL, 0, 0, op_b, x);
}

// Round 2
// 1242.562 us; speedup vs baseline: 1.6497x; 1.6497x over previous
//
#include <hip/hip_runtime.h>
#include <math.h>

#define L_SEQ   2048
#define NBATCH  2
#define DMODEL  1024
#define DHALF   512
#define DINNER  1024
#define DSTATE  128
#define NHEADS  16
#define HEADDIM 64
#define CONVDIM 1280
#define DINPROJ 2320
#define ROWS    4096  /* NBATCH * L_SEQ */

#define SCAN_T  16
#define NCHUNK  (L_SEQ / SCAN_T)   /* 128 */

__device__ __forceinline__ float siluf(float v){ return v / (1.f + expf(-v)); }
__device__ __forceinline__ float softplusf(float v){ return v > 20.f ? v : log1pf(expf(v)); }

__device__ __forceinline__ float blockReduceSum256(float v, float* red){
  #pragma unroll
  for (int o = 32; o > 0; o >>= 1) v += __shfl_xor(v, o);
  int wid = threadIdx.x >> 6, lane = threadIdx.x & 63;
  if (lane == 0) red[wid] = v;
  __syncthreads();
  return red[0] + red[1] + red[2] + red[3];
}

// ---------------- rmsnorm + split into u_f and (pre-flipped) u_b ----------------
__global__ void rmsnorm_split_kernel(const float* __restrict__ x, const float* __restrict__ nw,
                                     float* __restrict__ uf, float* __restrict__ ub){
  __shared__ float red[4];
  int row = blockIdx.x;                       // b*L + t
  const float* xr = x + (size_t)row * DMODEL;
  float loc[4]; float ss = 0.f;
  #pragma unroll
  for (int k = 0; k < 4; k++){ float v = xr[threadIdx.x + k*256]; loc[k] = v; ss += v*v; }
  ss = blockReduceSum256(ss, red);
  float scale = rsqrtf(ss * (1.f/DMODEL) + 1e-5f);
  int t = row & (L_SEQ-1);
  int fliprow = (row ^ t) | (L_SEQ-1-t);
  #pragma unroll
  for (int k = 0; k < 4; k++){
    int d = threadIdx.x + k*256;
    float v = loc[k] * scale * nw[d];
    if (d < DHALF) uf[(size_t)row*DHALF + d] = v;
    else           ub[(size_t)fliprow*DHALF + (d - DHALF)] = v;
  }
}

// ---------------- generic fp32 GEMM: C[m, coff+n] = sum_k A[m,k]*Bw[n,k] (+bias+res) ----
__global__ __launch_bounds__(256) void gemm_nt_kernel(
    const float* __restrict__ A, const float* __restrict__ Bw, float* __restrict__ C,
    int M, int N, int K, int ldc, int coff, int flip,
    const float* __restrict__ bias, const float* __restrict__ res){
  __shared__ __align__(16) float As[16][68];
  __shared__ __align__(16) float Bs[16][68];
  int bm = blockIdx.y * 64, bn = blockIdx.x * 64;
  int tid = threadIdx.x;
  int tx = tid & 15, ty = tid >> 4;
  int arow = tid >> 2, ac4 = (tid & 3) * 4;
  float acc[4][4] = {};
  for (int k0 = 0; k0 < K; k0 += 16){
    float4 av = *(const float4*)(A + (size_t)(bm + arow)*K + k0 + ac4);
    int gn = bn + arow;
    float4 bv = make_float4(0.f,0.f,0.f,0.f);
    if (gn < N) bv = *(const float4*)(Bw + (size_t)gn*K + k0 + ac4);
    As[ac4+0][arow]=av.x; As[ac4+1][arow]=av.y; As[ac4+2][arow]=av.z; As[ac4+3][arow]=av.w;
    Bs[ac4+0][arow]=bv.x; Bs[ac4+1][arow]=bv.y; Bs[ac4+2][arow]=bv.z; Bs[ac4+3][arow]=bv.w;
    __syncthreads();
    #pragma unroll
    for (int kk = 0; kk < 16; kk++){
      float4 aa = *(const float4*)&As[kk][ty*4];
      float4 bb = *(const float4*)&Bs[kk][tx*4];
      float a_[4] = {aa.x, aa.y, aa.z, aa.w};
      float b_[4] = {bb.x, bb.y, bb.z, bb.w};
      #pragma unroll
      for (int i = 0; i < 4; i++)
        #pragma unroll
        for (int j = 0; j < 4; j++)
          acc[i][j] += a_[i] * b_[j];
    }
    __syncthreads();
  }
  #pragma unroll
  for (int i = 0; i < 4; i++){
    int m = bm + ty*4 + i;
    int mo = m;
    if (flip){ int t = m & (L_SEQ-1); mo = (m ^ t) | (L_SEQ-1-t); }
    #pragma unroll
    for (int j = 0; j < 4; j++){
      int n = bn + tx*4 + j;
      if (n < N){
        float v = acc[i][j];
        if (bias) v += bias[n];
        if (res)  v += res[(size_t)mo*ldc + coff + n];
        C[(size_t)mo*ldc + coff + n] = v;
      }
    }
  }
}

// ---------------- causal depthwise conv (k=4) + silu over xBC channels ----------------
__global__ void conv_silu_kernel(const float* __restrict__ zxf, const float* __restrict__ zxb,
                                 const float* __restrict__ cwf, const float* __restrict__ cbf,
                                 const float* __restrict__ cwb, const float* __restrict__ cbb,
                                 float* __restrict__ cvf, float* __restrict__ cvb){
  int row = blockIdx.x; int dir = blockIdx.y;
  const float* zx = dir ? zxb : zxf;
  const float* cw = dir ? cwb : cwf;
  const float* cb = dir ? cbb : cbf;
  float* cv = dir ? cvb : cvf;
  int t = row & (L_SEQ-1);
  for (int c = threadIdx.x; c < CONVDIM; c += 256){
    const float* base = zx + (size_t)row*DINPROJ + DINNER + c;
    float v = cb[c];
    if (t >= 1) v += base[-1*(ptrdiff_t)DINPROJ] * cw[c*4+2];
    if (t >= 2) v += base[-2*(ptrdiff_t)DINPROJ] * cw[c*4+1];
    if (t >= 3) v += base[-3*(ptrdiff_t)DINPROJ] * cw[c*4+0];
    v += base[0] * cw[c*4+3];
    cv[(size_t)row*CONVDIM + c] = siluf(v);
  }
}

// ---------------- dt softplus + dA = exp(dt*A) ----------------
__global__ void dtprep_kernel(const float* __restrict__ zxf, const float* __restrict__ zxb,
                              const float* __restrict__ dbf, const float* __restrict__ alf,
                              const float* __restrict__ dbb, const float* __restrict__ alb,
                              float* __restrict__ dtf, float* __restrict__ dtb,
                              float* __restrict__ dAf, float* __restrict__ dAb){
  int idx = blockIdx.x*256 + threadIdx.x;   // 0 .. 2*ROWS*NHEADS-1
  int dir = idx >> 16;
  int r = idx & 65535;
  int h = r & 15, row = r >> 4;
  const float* zx = dir ? zxb : zxf;
  float raw = zx[(size_t)row*DINPROJ + DINNER + CONVDIM + h];
  float bias = (dir ? dbb : dbf)[h];
  float dtv = softplusf(raw + bias);
  float a = -expf((dir ? alb : alf)[h]);
  float dAv = expf(dtv * a);
  (dir ? dtb : dtf)[r] = dtv;
  (dir ? dAb : dAf)[r] = dAv;
}

// ---------------- parallel sequential scan ----------------
// 512 wgs = (dir, b, h, pblk); 256 threads; half-wave (32 lanes) owns one p,
// each lane owns 4 n. Chunked double-buffered LDS staging, T=16 steps/chunk.
__global__ __launch_bounds__(256) void scan_kernel(
    const float* __restrict__ cvf, const float* __restrict__ cvb,
    const float* __restrict__ dtf, const float* __restrict__ dtb,
    const float* __restrict__ dAf, const float* __restrict__ dAb,
    const float* __restrict__ Df,  const float* __restrict__ Db,
    float* __restrict__ yf, float* __restrict__ yb){
  int wg = blockIdx.x;
  int pblk = wg & 7;
  int h    = (wg >> 3) & 15;
  int b    = (wg >> 7) & 1;
  int dir  = wg >> 8;
  const float* cv  = dir ? cvb : cvf;
  const float* dtp = dir ? dtb : dtf;
  const float* dAp = dir ? dAb : dAf;
  float* y = dir ? yb : yf;
  float Dh = (dir ? Db : Df)[h];

  int tid = threadIdx.x;
  int nlane = tid & 31;
  int p_in = tid >> 5;          // 0..7 (half-wave id)
  int n0 = nlane * 4;

  __shared__ __align__(16) float sBC[2][SCAN_T][256];  // B: [0,128), C: [128,256)
  __shared__ float sx [2][SCAN_T][8];
  __shared__ float sdt[2][SCAN_T];
  __shared__ float sdA[2][SCAN_T];
  __shared__ __align__(16) float sy [2][SCAN_T][8];

  size_t rowbase = (size_t)b * L_SEQ;

  float4 pf[4];
  float spf = 0.f;

  auto issue_loads = [&](int c){
    size_t r0 = rowbase + (size_t)c * SCAN_T;
    #pragma unroll
    for (int k = 0; k < 4; k++){
      int f = tid + k*256;           // 0..1023 float4s
      int t = f >> 6, q = f & 63;
      pf[k] = *(const float4*)(cv + (r0 + t)*CONVDIM + DINNER + q*4);
    }
    if (tid < 128){
      int t = tid >> 3, pp = tid & 7;
      spf = cv[(r0 + t)*CONVDIM + h*HEADDIM + pblk*8 + pp];
    } else if (tid < 144){
      spf = dtp[(r0 + (tid-128))*NHEADS + h];
    } else if (tid < 160){
      spf = dAp[(r0 + (tid-144))*NHEADS + h];
    }
  };
  auto write_lds = [&](int bufi){
    #pragma unroll
    for (int k = 0; k < 4; k++){
      int f = tid + k*256;
      int t = f >> 6, q = f & 63;
      *(float4*)&sBC[bufi][t][q*4] = pf[k];
    }
    if (tid < 128)      sx [bufi][tid>>3][tid&7] = spf;
    else if (tid < 144) sdt[bufi][tid-128] = spf;
    else if (tid < 160) sdA[bufi][tid-144] = spf;
  };

  float h0=0.f, h1=0.f, h2=0.f, h3=0.f;

  issue_loads(0);
  write_lds(0);
  __syncthreads();

  for (int c = 0; c < NCHUNK; ++c){
    int buf = c & 1;
    // write out previous chunk's y (from the other sy buffer), coalesced
    if (c > 0 && tid < 32){
      int t = tid >> 1, half = tid & 1;
      size_t row = rowbase + (size_t)(c-1)*SCAN_T + t;
      *(float4*)(y + row*DINNER + h*HEADDIM + pblk*8 + half*4) =
          *(const float4*)&sy[buf^1][t][half*4];
    }
    if (c + 1 < NCHUNK) issue_loads(c+1);
    #pragma unroll
    for (int t = 0; t < SCAN_T; ++t){
      float4 Bv = *(const float4*)&sBC[buf][t][n0];
      float4 Cv = *(const float4*)&sBC[buf][t][128 + n0];
      float xv  = sx[buf][t][p_in];
      float dtv = sdt[buf][t];
      float dAv = sdA[buf][t];
      float dtx = dtv * xv;
      h0 = fmaf(dAv, h0, dtx*Bv.x);
      h1 = fmaf(dAv, h1, dtx*Bv.y);
      h2 = fmaf(dAv, h2, dtx*Bv.z);
      h3 = fmaf(dAv, h3, dtx*Bv.w);
      float acc = h0*Cv.x + h1*Cv.y + h2*Cv.z + h3*Cv.w;
      acc += __shfl_xor(acc, 1);
      acc += __shfl_xor(acc, 2);
      acc += __shfl_xor(acc, 4);
      acc += __shfl_xor(acc, 8);
      acc += __shfl_xor(acc, 16);
      if (nlane == 0) sy[buf][t][p_in] = fmaf(Dh, xv, acc);
    }
    if (c + 1 < NCHUNK) write_lds(buf ^ 1);
    __syncthreads();
  }
  // final chunk write-out ((NCHUNK-1)&1 == 1)
  if (tid < 32){
    int t = tid >> 1, half = tid & 1;
    size_t row = rowbase + (size_t)(NCHUNK-1)*SCAN_T + t;
    *(float4*)(y + row*DINNER + h*HEADDIM + pblk*8 + half*4) =
        *(const float4*)&sy[1][t][half*4];
  }
}

// ---------------- gate (silu(z)) + rmsnorm, in place on y ----------------
__global__ void gate_norm_kernel(float* __restrict__ yf, float* __restrict__ yb,
                                 const float* __restrict__ zxf, const float* __restrict__ zxb,
                                 const float* __restrict__ gwf, const float* __restrict__ gwb){
  __shared__ float red[4];
  int row = blockIdx.x; int dir = blockIdx.y;
  float* y = (dir ? yb : yf) + (size_t)row*DINNER;
  const float* zx = (dir ? zxb : zxf) + (size_t)row*DINPROJ;
  const float* gw = dir ? gwb : gwf;
  float v[4]; float ss = 0.f;
  #pragma unroll
  for (int k = 0; k < 4; k++){
    int d = threadIdx.x + k*256;
    float val = y[d] * siluf(zx[d]);
    v[k] = val; ss += val*val;
  }
  ss = blockReduceSum256(ss, red);
  float scale = rsqrtf(ss*(1.f/DINNER) + 1e-5f);
  #pragma unroll
  for (int k = 0; k < 4; k++){
    int d = threadIdx.x + k*256;
    y[d] = v[k]*scale*gw[d];
  }
}

extern "C" void kernel_launch(void* const* d_in, const int* in_sizes, int n_in,
                              void* d_out, int out_size, void* d_ws, size_t ws_size,
                              hipStream_t stream) {
  const float* x      = (const float*)d_in[0];
  const float* norm_w = (const float*)d_in[1];
  const float* op_w   = (const float*)d_in[2];
  const float* op_b   = (const float*)d_in[3];
  const float* f_in_w    = (const float*)d_in[4];
  const float* f_conv_w  = (const float*)d_in[5];
  const float* f_conv_b  = (const float*)d_in[6];
  const float* f_dt_bias = (const float*)d_in[7];
  const float* f_A_log   = (const float*)d_in[8];
  const float* f_D       = (const float*)d_in[9];
  const float* f_gnorm_w = (const float*)d_in[10];
  const float* f_outp_w  = (const float*)d_in[11];
  const float* b_in_w    = (const float*)d_in[12];
  const float* b_conv_w  = (const float*)d_in[13];
  const float* b_conv_b  = (const float*)d_in[14];
  const float* b_dt_bias = (const float*)d_in[15];
  const float* b_A_log   = (const float*)d_in[16];
  const float* b_D       = (const float*)d_in[17];
  const float* b_gnorm_w = (const float*)d_in[18];
  const float* b_outp_w  = (const float*)d_in[19];
  float* out = (float*)d_out;

  float* ws = (float*)d_ws;
  size_t off = 0;
  float* u_f  = ws + off; off += (size_t)ROWS*DHALF;
  float* u_b  = ws + off; off += (size_t)ROWS*DHALF;
  float* zx_f = ws + off; off += (size_t)ROWS*DINPROJ;
  float* zx_b = ws + off; off += (size_t)ROWS*DINPROJ;
  float* cv_f = ws + off; off += (size_t)ROWS*CONVDIM;
  float* cv_b = ws + off; off += (size_t)ROWS*CONVDIM;
  float* dt_f = ws + off; off += (size_t)ROWS*NHEADS;
  float* dt_b = ws + off; off += (size_t)ROWS*NHEADS;
  float* dA_f = ws + off; off += (size_t)ROWS*NHEADS;
  float* dA_b = ws + off; off += (size_t)ROWS*NHEADS;
  float* y_f  = ws + off; off += (size_t)ROWS*DINNER;
  float* y_b  = ws + off; off += (size_t)ROWS*DINNER;
  float* cat  = ws + off; off += (size_t)ROWS*DINNER;

  // 1. rmsnorm + split (+pre-flip backward input)
  rmsnorm_split_kernel<<<ROWS, 256, 0, stream>>>(x, norm_w, u_f, u_b);
  // 2-3. in-proj GEMMs: [4096 x 512] @ [2320 x 512]^T
  gemm_nt_kernel<<<dim3((DINPROJ+63)/64, ROWS/64), 256, 0, stream>>>(
      u_f, f_in_w, zx_f, ROWS, DINPROJ, DHALF, DINPROJ, 0, 0, nullptr, nullptr);
  gemm_nt_kernel<<<dim3((DINPROJ+63)/64, ROWS/64), 256, 0, stream>>>(
      u_b, b_in_w, zx_b, ROWS, DINPROJ, DHALF, DINPROJ, 0, 0, nullptr, nullptr);
  // 4. conv + silu
  conv_silu_kernel<<<dim3(ROWS, 2), 256, 0, stream>>>(
      zx_f, zx_b, f_conv_w, f_conv_b, b_conv_w, b_conv_b, cv_f, cv_b);
  // 5. dt / dA
  dtprep_kernel<<<(2*ROWS*NHEADS)/256, 256, 0, stream>>>(
      zx_f, zx_b, f_dt_bias, f_A_log, b_dt_bias, b_A_log, dt_f, dt_b, dA_f, dA_b);
  // 6. scan (parallelized over head-dim: 512 wgs)
  scan_kernel<<<512, 256, 0, stream>>>(cv_f, cv_b, dt_f, dt_b, dA_f, dA_b,
                                       f_D, b_D, y_f, y_b);
  // 7. gate + rmsnorm (in place)
  gate_norm_kernel<<<dim3(ROWS, 2), 256, 0, stream>>>(
      y_f, y_b, zx_f, zx_b, f_gnorm_w, b_gnorm_w);
  // 8-9. out-proj GEMMs into concat buffer (backward written time-flipped)
  gemm_nt_kernel<<<dim3(DHALF/64, ROWS/64), 256, 0, stream>>>(
      y_f, f_outp_w, cat, ROWS, DHALF, DINNER, DMODEL, 0, 0, nullptr, nullptr);
  gemm_nt_kernel<<<dim3(DHALF/64, ROWS/64), 256, 0, stream>>>(
      y_b, b_outp_w, cat, ROWS, DHALF, DINNER, DMODEL, DHALF, 1, nullptr, nullptr);
  // 10. final projection + bias + residual
  gemm_nt_kernel<<<dim3(DMODEL/64, ROWS/64), 256, 0, stream>>>(
      cat, op_w, out, ROWS, DMODEL, DMODEL, DMODEL, 0, 0, op_b, x);
}

// Round 3
// 867.479 us; speedup vs baseline: 2.3631x; 1.4324x over previous
//
#include <hip/hip_runtime.h>
#include <math.h>

#define L_SEQ   2048
#define NBATCH  2
#define DMODEL  1024
#define DHALF   512
#define DINNER  1024
#define DSTATE  128
#define NHEADS  16
#define HEADDIM 64
#define CONVDIM 1280
#define DINPROJ 2320
#define ROWS    4096  /* NBATCH * L_SEQ */
#define NPADIN  2432  /* DINPROJ padded to multiple of 128 */

#define SCAN_T  16
#define NCHUNK  (L_SEQ / SCAN_T)   /* 128 */

typedef __attribute__((ext_vector_type(8))) short bf16x8;
typedef __attribute__((ext_vector_type(4))) float f32x4;

__device__ __forceinline__ float siluf(float v){ return v / (1.f + expf(-v)); }
__device__ __forceinline__ float softplusf(float v){ return v > 20.f ? v : log1pf(expf(v)); }
__device__ __forceinline__ unsigned short f2bf(float f){
  union { float f; unsigned u; } x; x.f = f;
  unsigned r = (x.u + 0x7fffu + ((x.u >> 16) & 1u)) >> 16;
  return (unsigned short)r;
}
__device__ __forceinline__ void gload16(const void* g, void* l){
  __builtin_amdgcn_global_load_lds((const __attribute__((address_space(1))) void*)g,
                                   (__attribute__((address_space(3))) void*)l, 16, 0, 0);
}

__device__ __forceinline__ float blockReduceSum256(float v, float* red){
  #pragma unroll
  for (int o = 32; o > 0; o >>= 1) v += __shfl_xor(v, o);
  int wid = threadIdx.x >> 6, lane = threadIdx.x & 63;
  if (lane == 0) red[wid] = v;
  __syncthreads();
  return red[0] + red[1] + red[2] + red[3];
}

// ---------------- rmsnorm + split into bf16 u_f and (pre-flipped) u_b ----------------
__global__ void rmsnorm_split_kernel(const float* __restrict__ x, const float* __restrict__ nw,
                                     unsigned short* __restrict__ uf, unsigned short* __restrict__ ub){
  __shared__ float red[4];
  int row = blockIdx.x;                       // b*L + t
  const float* xr = x + (size_t)row * DMODEL;
  float loc[4]; float ss = 0.f;
  #pragma unroll
  for (int k = 0; k < 4; k++){ float v = xr[threadIdx.x + k*256]; loc[k] = v; ss += v*v; }
  ss = blockReduceSum256(ss, red);
  float scale = rsqrtf(ss * (1.f/DMODEL) + 1e-5f);
  int t = row & (L_SEQ-1);
  int fliprow = (row ^ t) | (L_SEQ-1-t);
  #pragma unroll
  for (int k = 0; k < 4; k++){
    int d = threadIdx.x + k*256;
    float v = loc[k] * scale * nw[d];
    if (d < DHALF) uf[(size_t)row*DHALF + d] = f2bf(v);
    else           ub[(size_t)fliprow*DHALF + (d - DHALF)] = f2bf(v);
  }
}

// ---------------- weight fp32 -> bf16 (+row pad) ----------------
__global__ void wconv_kernel(const float* __restrict__ src, unsigned short* __restrict__ dst,
                             int rows, int kshift, int total){
  int idx = blockIdx.x*256 + threadIdx.x;
  if (idx >= total) return;
  int row = idx >> kshift;
  dst[idx] = (row < rows) ? f2bf(src[idx]) : (unsigned short)0;
}

// ---------------- bf16 MFMA GEMM (m97-style): C[m, coff+n] = sum_k A[m,k]*W[n,k] ----------
// A: M x K bf16, row stride lda. W: Npad x K bf16 (rows >= gridDim.x*128).
// Output either fp32 (Cf) or bf16 (Ch), ldc stride, optional bias/res/flip.
__global__ __launch_bounds__(256) void gemm_bf16_kernel(
    const unsigned short* __restrict__ A, int lda,
    const unsigned short* __restrict__ W,
    float* __restrict__ Cf, unsigned short* __restrict__ Ch,
    int M, int Nreal, int K, int ldc, int coff, int flip,
    const float* __restrict__ bias, const float* __restrict__ res){
  __shared__ unsigned short As[128*32];
  __shared__ unsigned short Bs[128*32];
  int bm = blockIdx.y*128, bn = blockIdx.x*128;
  int tid = threadIdx.x;
  int lane = tid & 63;
  int wave = tid >> 6;
  int wm = (wave >> 1) * 64, wn = (wave & 1) * 64;
  int l15 = lane & 15, lhi = lane >> 4;    // lhi 0..3
  f32x4 acc[4][4];
  #pragma unroll
  for (int i = 0; i < 4; i++)
    #pragma unroll
    for (int j = 0; j < 4; j++)
      acc[i][j] = (f32x4){0.f,0.f,0.f,0.f};

  for (int k0 = 0; k0 < K; k0 += 32){
    #pragma unroll
    for (int j = 0; j < 2; j++){
      int f = j*256 + tid;                 // 0..511 16B-chunks (128 rows x 4 chunks)
      int row = f >> 2, c8 = (f & 3) * 8;
      gload16(A + (size_t)(bm+row)*lda + k0 + c8, &As[f*8]);
      gload16(W + (size_t)(bn+row)*K   + k0 + c8, &Bs[f*8]);
    }
    __syncthreads();
    bf16x8 af[4], bfr[4];
    #pragma unroll
    for (int i = 0; i < 4; i++){
      af[i]  = *(const bf16x8*)&As[(wm + i*16 + l15)*32 + lhi*8];
      bfr[i] = *(const bf16x8*)&Bs[(wn + i*16 + l15)*32 + lhi*8];
    }
    #pragma unroll
    for (int i = 0; i < 4; i++)
      #pragma unroll
      for (int j = 0; j < 4; j++)
        acc[i][j] = __builtin_amdgcn_mfma_f32_16x16x32_bf16(af[i], bfr[j], acc[i][j], 0, 0, 0);
    __syncthreads();
  }
  #pragma unroll
  for (int i = 0; i < 4; i++){
    #pragma unroll
    for (int r = 0; r < 4; r++){
      int m = bm + wm + i*16 + lhi*4 + r;
      int mo = m;
      if (flip){ int t = m & (L_SEQ-1); mo = (m ^ t) | (L_SEQ-1-t); }
      #pragma unroll
      for (int j = 0; j < 4; j++){
        int n = bn + wn + j*16 + l15;
        if (n < Nreal){
          float v = acc[i][j][r];
          if (bias) v += bias[n];
          if (res)  v += res[(size_t)mo*ldc + coff + n];
          size_t o = (size_t)mo*ldc + coff + n;
          if (Cf) Cf[o] = v;
          else    Ch[o] = f2bf(v);
        }
      }
    }
  }
}

// ---------------- causal depthwise conv (k=4) + silu over xBC channels ----------------
__global__ void conv_silu_kernel(const float* __restrict__ zxf, const float* __restrict__ zxb,
                                 const float* __restrict__ cwf, const float* __restrict__ cbf,
                                 const float* __restrict__ cwb, const float* __restrict__ cbb,
                                 float* __restrict__ cvf, float* __restrict__ cvb){
  int row = blockIdx.x; int dir = blockIdx.y;
  const float* zx = dir ? zxb : zxf;
  const float* cw = dir ? cwb : cwf;
  const float* cb = dir ? cbb : cbf;
  float* cv = dir ? cvb : cvf;
  int t = row & (L_SEQ-1);
  for (int c = threadIdx.x; c < CONVDIM; c += 256){
    const float* base = zx + (size_t)row*DINPROJ + DINNER + c;
    float v = cb[c];
    if (t >= 1) v += base[-1*(ptrdiff_t)DINPROJ] * cw[c*4+2];
    if (t >= 2) v += base[-2*(ptrdiff_t)DINPROJ] * cw[c*4+1];
    if (t >= 3) v += base[-3*(ptrdiff_t)DINPROJ] * cw[c*4+0];
    v += base[0] * cw[c*4+3];
    cv[(size_t)row*CONVDIM + c] = siluf(v);
  }
}

// ---------------- dt softplus + dA = exp(dt*A) ----------------
__global__ void dtprep_kernel(const float* __restrict__ zxf, const float* __restrict__ zxb,
                              const float* __restrict__ dbf, const float* __restrict__ alf,
                              const float* __restrict__ dbb, const float* __restrict__ alb,
                              float* __restrict__ dtf, float* __restrict__ dtb,
                              float* __restrict__ dAf, float* __restrict__ dAb){
  int idx = blockIdx.x*256 + threadIdx.x;   // 0 .. 2*ROWS*NHEADS-1
  int dir = idx >> 16;
  int r = idx & 65535;
  int h = r & 15, row = r >> 4;
  const float* zx = dir ? zxb : zxf;
  float raw = zx[(size_t)row*DINPROJ + DINNER + CONVDIM + h];
  float bias = (dir ? dbb : dbf)[h];
  float dtv = softplusf(raw + bias);
  float a = -expf((dir ? alb : alf)[h]);
  float dAv = expf(dtv * a);
  (dir ? dtb : dtf)[r] = dtv;
  (dir ? dAb : dAf)[r] = dAv;
}

// ---------------- parallel sequential scan, deferred reduction ----------------
// 512 wgs = (dir, b, h, pblk); 256 threads; 32-lane group owns one p,
// lane owns 4 n. Per step: private state update + local dot into py[t] (regs).
// Cross-lane reduce batched at chunk end (16 independent shuffle chains).
__global__ __launch_bounds__(256) void scan_kernel(
    const float* __restrict__ cvf, const float* __restrict__ cvb,
    const float* __restrict__ dtf, const float* __restrict__ dtb,
    const float* __restrict__ dAf, const float* __restrict__ dAb,
    const float* __restrict__ Df,  const float* __restrict__ Db,
    float* __restrict__ yf, float* __restrict__ yb){
  int wg = blockIdx.x;
  int pblk = wg & 7;
  int h    = (wg >> 3) & 15;
  int b    = (wg >> 7) & 1;
  int dir  = wg >> 8;
  const float* cv  = dir ? cvb : cvf;
  const float* dtp = dir ? dtb : dtf;
  const float* dAp = dir ? dAb : dAf;
  float* y = dir ? yb : yf;
  float Dh = (dir ? Db : Df)[h];

  int tid = threadIdx.x;
  int nlane = tid & 31;
  int p_in = tid >> 5;          // 0..7
  int n0 = nlane * 4;

  __shared__ __align__(16) float sBC[2][SCAN_T][256];  // B: [0,128), C: [128,256)
  __shared__ float sx [2][SCAN_T][8];
  __shared__ float sdt[2][SCAN_T];
  __shared__ float sdA[2][SCAN_T];
  __shared__ __align__(16) float sy [2][SCAN_T][8];

  size_t rowbase = (size_t)b * L_SEQ;

  float4 pf[4];
  float spf = 0.f;

  auto issue_loads = [&](int c){
    size_t r0 = rowbase + (size_t)c * SCAN_T;
    #pragma unroll
    for (int k = 0; k < 4; k++){
      int f = tid + k*256;           // 0..1023 float4s
      int t = f >> 6, q = f & 63;
      pf[k] = *(const float4*)(cv + (r0 + t)*CONVDIM + DINNER + q*4);
    }
    if (tid < 128){
      int t = tid >> 3, pp = tid & 7;
      spf = cv[(r0 + t)*CONVDIM + h*HEADDIM + pblk*8 + pp];
    } else if (tid < 144){
      spf = dtp[(r0 + (tid-128))*NHEADS + h];
    } else if (tid < 160){
      spf = dAp[(r0 + (tid-144))*NHEADS + h];
    }
  };
  auto write_lds = [&](int bufi){
    #pragma unroll
    for (int k = 0; k < 4; k++){
      int f = tid + k*256;
      int t = f >> 6, q = f & 63;
      *(float4*)&sBC[bufi][t][q*4] = pf[k];
    }
    if (tid < 128)      sx [bufi][tid>>3][tid&7] = spf;
    else if (tid < 144) sdt[bufi][tid-128] = spf;
    else if (tid < 160) sdA[bufi][tid-144] = spf;
  };

  float h0=0.f, h1=0.f, h2=0.f, h3=0.f;
  float py[SCAN_T];

  issue_loads(0);
  write_lds(0);
  __syncthreads();

  for (int c = 0; c < NCHUNK; ++c){
    int buf = c & 1;
    // write out previous chunk's y, coalesced
    if (c > 0 && tid < 32){
      int t = tid >> 1, half = tid & 1;
      size_t row = rowbase + (size_t)(c-1)*SCAN_T + t;
      *(float4*)(y + row*DINNER + h*HEADDIM + pblk*8 + half*4) =
          *(const float4*)&sy[buf^1][t][half*4];
    }
    if (c + 1 < NCHUNK) issue_loads(c+1);
    #pragma unroll
    for (int t = 0; t < SCAN_T; ++t){
      float4 Bv = *(const float4*)&sBC[buf][t][n0];
      float4 Cv = *(const float4*)&sBC[buf][t][128 + n0];
      float xv  = sx[buf][t][p_in];
      float dtv = sdt[buf][t];
      float dAv = sdA[buf][t];
      float dtx = dtv * xv;
      h0 = fmaf(dAv, h0, dtx*Bv.x);
      h1 = fmaf(dAv, h1, dtx*Bv.y);
      h2 = fmaf(dAv, h2, dtx*Bv.z);
      h3 = fmaf(dAv, h3, dtx*Bv.w);
      py[t] = h0*Cv.x + h1*Cv.y + h2*Cv.z + h3*Cv.w;
    }
    // batched cross-lane reduction: 16 independent chains (good ILP)
    #pragma unroll
    for (int t = 0; t < SCAN_T; ++t){
      float a = py[t];
      a += __shfl_xor(a, 1);
      a += __shfl_xor(a, 2);
      a += __shfl_xor(a, 4);
      a += __shfl_xor(a, 8);
      a += __shfl_xor(a, 16);
      if (nlane == 0) sy[buf][t][p_in] = fmaf(Dh, sx[buf][t][p_in], a);
    }
    if (c + 1 < NCHUNK) write_lds(buf ^ 1);
    __syncthreads();
  }
  // final chunk write-out ((NCHUNK-1)&1 == 1)
  if (tid < 32){
    int t = tid >> 1, half = tid & 1;
    size_t row = rowbase + (size_t)(NCHUNK-1)*SCAN_T + t;
    *(float4*)(y + row*DINNER + h*HEADDIM + pblk*8 + half*4) =
        *(const float4*)&sy[1][t][half*4];
  }
}

// ---------------- gate (silu(z)) + rmsnorm; writes bf16 at row stride 2048 over y ----
__global__ void gate_norm_kernel(float* __restrict__ yf, float* __restrict__ yb,
                                 const float* __restrict__ zxf, const float* __restrict__ zxb,
                                 const float* __restrict__ gwf, const float* __restrict__ gwb){
  __shared__ float red[4];
  int row = blockIdx.x; int dir = blockIdx.y;
  float* ybase = dir ? yb : yf;
  const float* yr = ybase + (size_t)row*DINNER;
  unsigned short* yh = (unsigned short*)ybase + (size_t)row*2048;  // overlays same fp32 row
  const float* zx = (dir ? zxb : zxf) + (size_t)row*DINPROJ;
  const float* gw = dir ? gwb : gwf;
  float v[4]; float ss = 0.f;
  #pragma unroll
  for (int k = 0; k < 4; k++){
    int d = threadIdx.x + k*256;
    float val = yr[d] * siluf(zx[d]);
    v[k] = val; ss += val*val;
  }
  ss = blockReduceSum256(ss, red);   // __syncthreads inside: all reads precede writes
  float scale = rsqrtf(ss*(1.f/DINNER) + 1e-5f);
  #pragma unroll
  for (int k = 0; k < 4; k++){
    int d = threadIdx.x + k*256;
    yh[d] = f2bf(v[k]*scale*gw[d]);
  }
}

extern "C" void kernel_launch(void* const* d_in, const int* in_sizes, int n_in,
                              void* d_out, int out_size, void* d_ws, size_t ws_size,
                              hipStream_t stream) {
  const float* x      = (const float*)d_in[0];
  const float* norm_w = (const float*)d_in[1];
  const float* op_w   = (const float*)d_in[2];
  const float* op_b   = (const float*)d_in[3];
  const float* f_in_w    = (const float*)d_in[4];
  const float* f_conv_w  = (const float*)d_in[5];
  const float* f_conv_b  = (const float*)d_in[6];
  const float* f_dt_bias = (const float*)d_in[7];
  const float* f_A_log   = (const float*)d_in[8];
  const float* f_D       = (const float*)d_in[9];
  const float* f_gnorm_w = (const float*)d_in[10];
  const float* f_outp_w  = (const float*)d_in[11];
  const float* b_in_w    = (const float*)d_in[12];
  const float* b_conv_w  = (const float*)d_in[13];
  const float* b_conv_b  = (const float*)d_in[14];
  const float* b_dt_bias = (const float*)d_in[15];
  const float* b_A_log   = (const float*)d_in[16];
  const float* b_D       = (const float*)d_in[17];
  const float* b_gnorm_w = (const float*)d_in[18];
  const float* b_outp_w  = (const float*)d_in[19];
  float* out = (float*)d_out;

  float* ws = (float*)d_ws;
  size_t off = 0;
  unsigned short* u16f = (unsigned short*)(ws + off);
  unsigned short* u16b = u16f + (size_t)ROWS*DHALF;      off += (size_t)ROWS*DHALF; // 2 bf16 arrays
  float* zx_f = ws + off; off += (size_t)ROWS*DINPROJ;
  float* zx_b = ws + off; off += (size_t)ROWS*DINPROJ;
  float* cv_f = ws + off; off += (size_t)ROWS*CONVDIM;
  float* cv_b = ws + off; off += (size_t)ROWS*CONVDIM;
  float* dt_f = ws + off; off += (size_t)ROWS*NHEADS;
  float* dt_b = ws + off; off += (size_t)ROWS*NHEADS;
  float* dA_f = ws + off; off += (size_t)ROWS*NHEADS;
  float* dA_b = ws + off; off += (size_t)ROWS*NHEADS;
  float* y_f  = ws + off; off += (size_t)ROWS*DINNER;
  float* y_b  = ws + off; off += (size_t)ROWS*DINNER;
  unsigned short* w16_fin  = (unsigned short*)(ws + off); off += (size_t)NPADIN*DHALF/2;
  unsigned short* w16_bin  = (unsigned short*)(ws + off); off += (size_t)NPADIN*DHALF/2;
  unsigned short* w16_fout = (unsigned short*)(ws + off); off += (size_t)DHALF*DINNER/2;
  unsigned short* w16_bout = (unsigned short*)(ws + off); off += (size_t)DHALF*DINNER/2;
  unsigned short* w16_op   = (unsigned short*)(ws + off); off += (size_t)DMODEL*DMODEL/2;
  // cat (bf16 [ROWS][1024]) overlays zx_f (dead after gate_norm)
  unsigned short* cat16 = (unsigned short*)zx_f;
  // bf16 gated-y overlays y_f / y_b at row stride 2048
  unsigned short* y16f = (unsigned short*)y_f;
  unsigned short* y16b = (unsigned short*)y_b;

  // 1. rmsnorm + split (bf16, backward pre-flipped)
  rmsnorm_split_kernel<<<ROWS, 256, 0, stream>>>(x, norm_w, u16f, u16b);
  // 2. weight conversions
  wconv_kernel<<<(NPADIN*DHALF+255)/256, 256, 0, stream>>>(f_in_w, w16_fin, DINPROJ, 9, NPADIN*DHALF);
  wconv_kernel<<<(NPADIN*DHALF+255)/256, 256, 0, stream>>>(b_in_w, w16_bin, DINPROJ, 9, NPADIN*DHALF);
  wconv_kernel<<<(DHALF*DINNER+255)/256, 256, 0, stream>>>(f_outp_w, w16_fout, DHALF, 10, DHALF*DINNER);
  wconv_kernel<<<(DHALF*DINNER+255)/256, 256, 0, stream>>>(b_outp_w, w16_bout, DHALF, 10, DHALF*DINNER);
  wconv_kernel<<<(DMODEL*DMODEL+255)/256, 256, 0, stream>>>(op_w, w16_op, DMODEL, 10, DMODEL*DMODEL);
  // 3-4. in-proj GEMMs: [4096x512]@[2320x512]^T -> zx fp32
  gemm_bf16_kernel<<<dim3(NPADIN/128, ROWS/128), 256, 0, stream>>>(
      u16f, DHALF, w16_fin, zx_f, nullptr, ROWS, DINPROJ, DHALF, DINPROJ, 0, 0, nullptr, nullptr);
  gemm_bf16_kernel<<<dim3(NPADIN/128, ROWS/128), 256, 0, stream>>>(
      u16b, DHALF, w16_bin, zx_b, nullptr, ROWS, DINPROJ, DHALF, DINPROJ, 0, 0, nullptr, nullptr);
  // 5. conv + silu
  conv_silu_kernel<<<dim3(ROWS, 2), 256, 0, stream>>>(
      zx_f, zx_b, f_conv_w, f_conv_b, b_conv_w, b_conv_b, cv_f, cv_b);
  // 6. dt / dA
  dtprep_kernel<<<(2*ROWS*NHEADS)/256, 256, 0, stream>>>(
      zx_f, zx_b, f_dt_bias, f_A_log, b_dt_bias, b_A_log, dt_f, dt_b, dA_f, dA_b);
  // 7. scan
  scan_kernel<<<512, 256, 0, stream>>>(cv_f, cv_b, dt_f, dt_b, dA_f, dA_b,
                                       f_D, b_D, y_f, y_b);
  // 8. gate + rmsnorm -> bf16 (stride 2048 overlay)
  gate_norm_kernel<<<dim3(ROWS, 2), 256, 0, stream>>>(
      y_f, y_b, zx_f, zx_b, f_gnorm_w, b_gnorm_w);
  // 9-10. out-proj GEMMs -> cat16 bf16 (backward time-flipped)
  gemm_bf16_kernel<<<dim3(DHALF/128, ROWS/128), 256, 0, stream>>>(
      y16f, 2048, w16_fout, nullptr, cat16, ROWS, DHALF, DINNER, DMODEL, 0, 0, nullptr, nullptr);
  gemm_bf16_kernel<<<dim3(DHALF/128, ROWS/128), 256, 0, stream>>>(
      y16b, 2048, w16_bout, nullptr, cat16, ROWS, DHALF, DINNER, DMODEL, DHALF, 1, nullptr, nullptr);
  // 11. final projection + bias + residual (fp32 out)
  gemm_bf16_kernel<<<dim3(DMODEL/128, ROWS/128), 256, 0, stream>>>(
      cat16, DMODEL, w16_op, out, nullptr, ROWS, DMODEL, DMODEL, DMODEL, 0, 0, op_b, x);
}

// Round 4
// 554.215 us; speedup vs baseline: 3.6987x; 1.5652x over previous
//
#include <hip/hip_runtime.h>
#include <math.h>

#define L_SEQ   2048
#define NBATCH  2
#define DMODEL  1024
#define DHALF   512
#define DINNER  1024
#define DSTATE  128
#define NHEADS  16
#define HEADDIM 64
#define CONVDIM 1280
#define DINPROJ 2320
#define ROWS    4096  /* NBATCH * L_SEQ */
#define NPADIN  2432  /* DINPROJ padded to multiple of 128 */

#define SCAN_T  16
#define NCHUNK  (L_SEQ / SCAN_T)   /* 128 */

typedef __attribute__((ext_vector_type(8))) short bf16x8;
typedef __attribute__((ext_vector_type(4))) float f32x4;

__device__ __forceinline__ float siluf(float v){ return v / (1.f + expf(-v)); }
__device__ __forceinline__ float softplusf(float v){ return v > 20.f ? v : log1pf(expf(v)); }
__device__ __forceinline__ unsigned short f2bf(float f){
  union { float f; unsigned u; } x; x.f = f;
  unsigned r = (x.u + 0x7fffu + ((x.u >> 16) & 1u)) >> 16;
  return (unsigned short)r;
}
__device__ __forceinline__ void gload16(const void* g, void* l){
  __builtin_amdgcn_global_load_lds((const __attribute__((address_space(1))) void*)g,
                                   (__attribute__((address_space(3))) void*)l, 16, 0, 0);
}

// DPP sum over each 32-lane group; result valid in lanes 31 and 63 (VALU pipe, no LDS).
template<int CTRL>
__device__ __forceinline__ float dppadd(float v){
  int s = __builtin_amdgcn_update_dpp(0, __builtin_bit_cast(int, v), CTRL, 0xF, 0xF, true);
  return v + __builtin_bit_cast(float, s);
}
__device__ __forceinline__ float reduce32_dpp(float v){
  v = dppadd<0x111>(v);   // row_shr:1
  v = dppadd<0x112>(v);   // row_shr:2
  v = dppadd<0x114>(v);   // row_shr:4
  v = dppadd<0x118>(v);   // row_shr:8  -> lane15/31/47/63 hold row sums
  v = dppadd<0x142>(v);   // row_bcast15 -> lane31 += lane15, lane63 += lane47
  return v;
}

__device__ __forceinline__ float blockReduceSum256(float v, float* red){
  #pragma unroll
  for (int o = 32; o > 0; o >>= 1) v += __shfl_xor(v, o);
  int wid = threadIdx.x >> 6, lane = threadIdx.x & 63;
  if (lane == 0) red[wid] = v;
  __syncthreads();
  return red[0] + red[1] + red[2] + red[3];
}

// ---------------- rmsnorm + split into bf16 u_f and (pre-flipped) u_b ----------------
__global__ void rmsnorm_split_kernel(const float* __restrict__ x, const float* __restrict__ nw,
                                     unsigned short* __restrict__ uf, unsigned short* __restrict__ ub){
  __shared__ float red[4];
  int row = blockIdx.x;                       // b*L + t
  const float* xr = x + (size_t)row * DMODEL;
  float loc[4]; float ss = 0.f;
  #pragma unroll
  for (int k = 0; k < 4; k++){ float v = xr[threadIdx.x + k*256]; loc[k] = v; ss += v*v; }
  ss = blockReduceSum256(ss, red);
  float scale = rsqrtf(ss * (1.f/DMODEL) + 1e-5f);
  int t = row & (L_SEQ-1);
  int fliprow = (row ^ t) | (L_SEQ-1-t);
  #pragma unroll
  for (int k = 0; k < 4; k++){
    int d = threadIdx.x + k*256;
    float v = loc[k] * scale * nw[d];
    if (d < DHALF) uf[(size_t)row*DHALF + d] = f2bf(v);
    else           ub[(size_t)fliprow*DHALF + (d - DHALF)] = f2bf(v);
  }
}

// ---------------- weight fp32 -> bf16 (+row pad) ----------------
__global__ void wconv_kernel(const float* __restrict__ src, unsigned short* __restrict__ dst,
                             int rows, int kshift, int total){
  int idx = blockIdx.x*256 + threadIdx.x;
  if (idx >= total) return;
  int row = idx >> kshift;
  dst[idx] = (row < rows) ? f2bf(src[idx]) : (unsigned short)0;
}

// ---------------- bf16 MFMA GEMM (m97-style): C[m, coff+n] = sum_k A[m,k]*W[n,k] ----------
__global__ __launch_bounds__(256) void gemm_bf16_kernel(
    const unsigned short* __restrict__ A, int lda,
    const unsigned short* __restrict__ W,
    float* __restrict__ Cf, unsigned short* __restrict__ Ch,
    int M, int Nreal, int K, int ldc, int coff, int flip,
    const float* __restrict__ bias, const float* __restrict__ res){
  __shared__ unsigned short As[128*32];
  __shared__ unsigned short Bs[128*32];
  int bm = blockIdx.y*128, bn = blockIdx.x*128;
  int tid = threadIdx.x;
  int lane = tid & 63;
  int wave = tid >> 6;
  int wm = (wave >> 1) * 64, wn = (wave & 1) * 64;
  int l15 = lane & 15, lhi = lane >> 4;    // lhi 0..3
  f32x4 acc[4][4];
  #pragma unroll
  for (int i = 0; i < 4; i++)
    #pragma unroll
    for (int j = 0; j < 4; j++)
      acc[i][j] = (f32x4){0.f,0.f,0.f,0.f};

  for (int k0 = 0; k0 < K; k0 += 32){
    #pragma unroll
    for (int j = 0; j < 2; j++){
      int f = j*256 + tid;                 // 0..511 16B-chunks (128 rows x 4 chunks)
      int row = f >> 2, c8 = (f & 3) * 8;
      gload16(A + (size_t)(bm+row)*lda + k0 + c8, &As[f*8]);
      gload16(W + (size_t)(bn+row)*K   + k0 + c8, &Bs[f*8]);
    }
    __syncthreads();
    bf16x8 af[4], bfr[4];
    #pragma unroll
    for (int i = 0; i < 4; i++){
      af[i]  = *(const bf16x8*)&As[(wm + i*16 + l15)*32 + lhi*8];
      bfr[i] = *(const bf16x8*)&Bs[(wn + i*16 + l15)*32 + lhi*8];
    }
    #pragma unroll
    for (int i = 0; i < 4; i++)
      #pragma unroll
      for (int j = 0; j < 4; j++)
        acc[i][j] = __builtin_amdgcn_mfma_f32_16x16x32_bf16(af[i], bfr[j], acc[i][j], 0, 0, 0);
    __syncthreads();
  }
  #pragma unroll
  for (int i = 0; i < 4; i++){
    #pragma unroll
    for (int r = 0; r < 4; r++){
      int m = bm + wm + i*16 + lhi*4 + r;
      int mo = m;
      if (flip){ int t = m & (L_SEQ-1); mo = (m ^ t) | (L_SEQ-1-t); }
      #pragma unroll
      for (int j = 0; j < 4; j++){
        int n = bn + wn + j*16 + l15;
        if (n < Nreal){
          float v = acc[i][j][r];
          if (bias) v += bias[n];
          if (res)  v += res[(size_t)mo*ldc + coff + n];
          size_t o = (size_t)mo*ldc + coff + n;
          if (Cf) Cf[o] = v;
          else    Ch[o] = f2bf(v);
        }
      }
    }
  }
}

// ---------------- causal depthwise conv (k=4) + silu over xBC channels ----------------
__global__ void conv_silu_kernel(const float* __restrict__ zxf, const float* __restrict__ zxb,
                                 const float* __restrict__ cwf, const float* __restrict__ cbf,
                                 const float* __restrict__ cwb, const float* __restrict__ cbb,
                                 float* __restrict__ cvf, float* __restrict__ cvb){
  int row = blockIdx.x; int dir = blockIdx.y;
  const float* zx = dir ? zxb : zxf;
  const float* cw = dir ? cwb : cwf;
  const float* cb = dir ? cbb : cbf;
  float* cv = dir ? cvb : cvf;
  int t = row & (L_SEQ-1);
  for (int c = threadIdx.x; c < CONVDIM; c += 256){
    const float* base = zx + (size_t)row*DINPROJ + DINNER + c;
    float v = cb[c];
    if (t >= 1) v += base[-1*(ptrdiff_t)DINPROJ] * cw[c*4+2];
    if (t >= 2) v += base[-2*(ptrdiff_t)DINPROJ] * cw[c*4+1];
    if (t >= 3) v += base[-3*(ptrdiff_t)DINPROJ] * cw[c*4+0];
    v += base[0] * cw[c*4+3];
    cv[(size_t)row*CONVDIM + c] = siluf(v);
  }
}

// ---------------- dt softplus + dA = exp(dt*A) ----------------
__global__ void dtprep_kernel(const float* __restrict__ zxf, const float* __restrict__ zxb,
                              const float* __restrict__ dbf, const float* __restrict__ alf,
                              const float* __restrict__ dbb, const float* __restrict__ alb,
                              float* __restrict__ dtf, float* __restrict__ dtb,
                              float* __restrict__ dAf, float* __restrict__ dAb){
  int idx = blockIdx.x*256 + threadIdx.x;   // 0 .. 2*ROWS*NHEADS-1
  int dir = idx >> 16;
  int r = idx & 65535;
  int h = r & 15, row = r >> 4;
  const float* zx = dir ? zxb : zxf;
  float raw = zx[(size_t)row*DINPROJ + DINNER + CONVDIM + h];
  float bias = (dir ? dbb : dbf)[h];
  float dtv = softplusf(raw + bias);
  float a = -expf((dir ? alb : alf)[h]);
  float dAv = expf(dtv * a);
  (dir ? dtb : dtf)[r] = dtv;
  (dir ? dAb : dAf)[r] = dAv;
}

// ---------------- parallel sequential scan (LDS-pipe optimized) ----------------
// 256 wgs = (dir, b, h, pblk of 16 p); 256 threads; 32-lane group owns a p-pair,
// lane owns 4 n for both p's (8 states). B/C staged via global_load_lds; reduction
// over n via DPP adds (VALU pipe); y buffered in LDS, written coalesced 1 chunk behind.
__global__ __launch_bounds__(256, 1) void scan_kernel(
    const float* __restrict__ cvf, const float* __restrict__ cvb,
    const float* __restrict__ dtf, const float* __restrict__ dtb,
    const float* __restrict__ dAf, const float* __restrict__ dAb,
    const float* __restrict__ Df,  const float* __restrict__ Db,
    float* __restrict__ yf, float* __restrict__ yb){
  int wg = blockIdx.x;
  int pblk = wg & 3;             // 16 p's per wg
  int h    = (wg >> 2) & 15;
  int b    = (wg >> 6) & 1;
  int dir  = wg >> 7;
  const float* cv  = dir ? cvb : cvf;
  const float* dtp = dir ? dtb : dtf;
  const float* dAp = dir ? dAb : dAf;
  float* y = dir ? yb : yf;
  float Dh = (dir ? Db : Df)[h];

  int tid = threadIdx.x;
  int nlane = tid & 31;          // n0 = nlane*4
  int grp = tid >> 5;            // 0..7 -> p-pair (grp*2, grp*2+1) within pblk
  int n0 = nlane * 4;

  __shared__ __align__(16) float sBC [2][SCAN_T][256];  // B: [0,128), C: [128,256)
  __shared__ __align__(16) float sx  [2][SCAN_T][16];
  __shared__ __align__(16) float sdtA[2][SCAN_T][2];    // [0]=dt, [1]=dA
  __shared__ __align__(16) float sy  [2][SCAN_T][16];

  size_t rowbase = (size_t)b * L_SEQ;

  auto issue_bc = [&](int c, int bufi){
    size_t r0 = rowbase + (size_t)c * SCAN_T;
    #pragma unroll
    for (int k = 0; k < 4; k++){
      int f = k*256 + tid;               // 0..1023 16B-chunks, linear in lane order
      int t = f >> 6, q = f & 63;
      gload16(cv + (r0 + t)*CONVDIM + DINNER + q*4, &sBC[bufi][t][q*4]);
    }
  };
  float xreg = 0.f, dreg = 0.f;
  auto issue_xd = [&](int c){
    size_t r0 = rowbase + (size_t)c * SCAN_T;
    { int t = tid >> 4, pp = tid & 15;
      xreg = cv[(r0 + t)*CONVDIM + h*HEADDIM + pblk*16 + pp]; }
    if (tid < 16)       dreg = dtp[(r0 + tid)*NHEADS + h];
    else if (tid < 32)  dreg = dAp[(r0 + (tid-16))*NHEADS + h];
  };
  auto write_xd = [&](int bufi){
    sx[bufi][tid>>4][tid&15] = xreg;
    if (tid < 16)      sdtA[bufi][tid][0] = dreg;
    else if (tid < 32) sdtA[bufi][tid-16][1] = dreg;
  };

  float ha0=0.f,ha1=0.f,ha2=0.f,ha3=0.f;
  float hb0=0.f,hb1=0.f,hb2=0.f,hb3=0.f;
  float2 py[SCAN_T];

  issue_bc(0, 0);
  issue_xd(0);
  write_xd(0);
  __syncthreads();

  for (int c = 0; c < NCHUNK; ++c){
    int buf = c & 1;
    // coalesced write-out of previous chunk's y
    if (c > 0){
      int t = tid >> 4, pp = tid & 15;
      size_t row = rowbase + (size_t)(c-1)*SCAN_T + t;
      y[row*DINNER + h*HEADDIM + pblk*16 + pp] = sy[buf^1][t][pp];
    }
    if (c + 1 < NCHUNK){ issue_bc(c+1, buf^1); issue_xd(c+1); }
    #pragma unroll
    for (int t = 0; t < SCAN_T; ++t){
      float4 Bv = *(const float4*)&sBC[buf][t][n0];
      float4 Cv = *(const float4*)&sBC[buf][t][128 + n0];
      float2 xv = *(const float2*)&sx[buf][t][grp*2];
      float2 dv = *(const float2*)&sdtA[buf][t][0];   // dt, dA
      float dta = dv.x * xv.x;
      float dtb2 = dv.x * xv.y;
      ha0 = fmaf(dv.y, ha0, dta*Bv.x);  hb0 = fmaf(dv.y, hb0, dtb2*Bv.x);
      ha1 = fmaf(dv.y, ha1, dta*Bv.y);  hb1 = fmaf(dv.y, hb1, dtb2*Bv.y);
      ha2 = fmaf(dv.y, ha2, dta*Bv.z);  hb2 = fmaf(dv.y, hb2, dtb2*Bv.z);
      ha3 = fmaf(dv.y, ha3, dta*Bv.w);  hb3 = fmaf(dv.y, hb3, dtb2*Bv.w);
      py[t].x = ha0*Cv.x + ha1*Cv.y + ha2*Cv.z + ha3*Cv.w;
      py[t].y = hb0*Cv.x + hb1*Cv.y + hb2*Cv.z + hb3*Cv.w;
    }
    // cross-lane reduce over n (32 lanes) on VALU pipe; result in lanes 31/63
    #pragma unroll
    for (int t = 0; t < SCAN_T; ++t){
      float ra = reduce32_dpp(py[t].x);
      float rb = reduce32_dpp(py[t].y);
      if (nlane == 31){
        float2 o;
        o.x = fmaf(Dh, sx[buf][t][grp*2],   ra);
        o.y = fmaf(Dh, sx[buf][t][grp*2+1], rb);
        *(float2*)&sy[buf][t][grp*2] = o;
      }
    }
    if (c + 1 < NCHUNK) write_xd(buf ^ 1);
    __syncthreads();
  }
  // final chunk write-out
  {
    int t = tid >> 4, pp = tid & 15;
    size_t row = rowbase + (size_t)(NCHUNK-1)*SCAN_T + t;
    y[row*DINNER + h*HEADDIM + pblk*16 + pp] = sy[(NCHUNK-1)&1][t][pp];
  }
}

// ---------------- gate (silu(z)) + rmsnorm; writes bf16 at row stride 2048 over y ----
__global__ void gate_norm_kernel(float* __restrict__ yf, float* __restrict__ yb,
                                 const float* __restrict__ zxf, const float* __restrict__ zxb,
                                 const float* __restrict__ gwf, const float* __restrict__ gwb){
  __shared__ float red[4];
  int row = blockIdx.x; int dir = blockIdx.y;
  float* ybase = dir ? yb : yf;
  const float* yr = ybase + (size_t)row*DINNER;
  unsigned short* yh = (unsigned short*)ybase + (size_t)row*2048;  // overlays same fp32 row
  const float* zx = (dir ? zxb : zxf) + (size_t)row*DINPROJ;
  const float* gw = dir ? gwb : gwf;
  float v[4]; float ss = 0.f;
  #pragma unroll
  for (int k = 0; k < 4; k++){
    int d = threadIdx.x + k*256;
    float val = yr[d] * siluf(zx[d]);
    v[k] = val; ss += val*val;
  }
  ss = blockReduceSum256(ss, red);   // __syncthreads inside: all reads precede writes
  float scale = rsqrtf(ss*(1.f/DINNER) + 1e-5f);
  #pragma unroll
  for (int k = 0; k < 4; k++){
    int d = threadIdx.x + k*256;
    yh[d] = f2bf(v[k]*scale*gw[d]);
  }
}

extern "C" void kernel_launch(void* const* d_in, const int* in_sizes, int n_in,
                              void* d_out, int out_size, void* d_ws, size_t ws_size,
                              hipStream_t stream) {
  const float* x      = (const float*)d_in[0];
  const float* norm_w = (const float*)d_in[1];
  const float* op_w   = (const float*)d_in[2];
  const float* op_b   = (const float*)d_in[3];
  const float* f_in_w    = (const float*)d_in[4];
  const float* f_conv_w  = (const float*)d_in[5];
  const float* f_conv_b  = (const float*)d_in[6];
  const float* f_dt_bias = (const float*)d_in[7];
  const float* f_A_log   = (const float*)d_in[8];
  const float* f_D       = (const float*)d_in[9];
  const float* f_gnorm_w = (const float*)d_in[10];
  const float* f_outp_w  = (const float*)d_in[11];
  const float* b_in_w    = (const float*)d_in[12];
  const float* b_conv_w  = (const float*)d_in[13];
  const float* b_conv_b  = (const float*)d_in[14];
  const float* b_dt_bias = (const float*)d_in[15];
  const float* b_A_log   = (const float*)d_in[16];
  const float* b_D       = (const float*)d_in[17];
  const float* b_gnorm_w = (const float*)d_in[18];
  const float* b_outp_w  = (const float*)d_in[19];
  float* out = (float*)d_out;

  float* ws = (float*)d_ws;
  size_t off = 0;
  unsigned short* u16f = (unsigned short*)(ws + off);
  unsigned short* u16b = u16f + (size_t)ROWS*DHALF;      off += (size_t)ROWS*DHALF; // 2 bf16 arrays
  float* zx_f = ws + off; off += (size_t)ROWS*DINPROJ;
  float* zx_b = ws + off; off += (size_t)ROWS*DINPROJ;
  float* cv_f = ws + off; off += (size_t)ROWS*CONVDIM;
  float* cv_b = ws + off; off += (size_t)ROWS*CONVDIM;
  float* dt_f = ws + off; off += (size_t)ROWS*NHEADS;
  float* dt_b = ws + off; off += (size_t)ROWS*NHEADS;
  float* dA_f = ws + off; off += (size_t)ROWS*NHEADS;
  float* dA_b = ws + off; off += (size_t)ROWS*NHEADS;
  float* y_f  = ws + off; off += (size_t)ROWS*DINNER;
  float* y_b  = ws + off; off += (size_t)ROWS*DINNER;
  unsigned short* w16_fin  = (unsigned short*)(ws + off); off += (size_t)NPADIN*DHALF/2;
  unsigned short* w16_bin  = (unsigned short*)(ws + off); off += (size_t)NPADIN*DHALF/2;
  unsigned short* w16_fout = (unsigned short*)(ws + off); off += (size_t)DHALF*DINNER/2;
  unsigned short* w16_bout = (unsigned short*)(ws + off); off += (size_t)DHALF*DINNER/2;
  unsigned short* w16_op   = (unsigned short*)(ws + off); off += (size_t)DMODEL*DMODEL/2;
  // cat (bf16 [ROWS][1024]) overlays zx_f (dead after gate_norm)
  unsigned short* cat16 = (unsigned short*)zx_f;
  // bf16 gated-y overlays y_f / y_b at row stride 2048
  unsigned short* y16f = (unsigned short*)y_f;
  unsigned short* y16b = (unsigned short*)y_b;

  // 1. rmsnorm + split (bf16, backward pre-flipped)
  rmsnorm_split_kernel<<<ROWS, 256, 0, stream>>>(x, norm_w, u16f, u16b);
  // 2. weight conversions
  wconv_kernel<<<(NPADIN*DHALF+255)/256, 256, 0, stream>>>(f_in_w, w16_fin, DINPROJ, 9, NPADIN*DHALF);
  wconv_kernel<<<(NPADIN*DHALF+255)/256, 256, 0, stream>>>(b_in_w, w16_bin, DINPROJ, 9, NPADIN*DHALF);
  wconv_kernel<<<(DHALF*DINNER+255)/256, 256, 0, stream>>>(f_outp_w, w16_fout, DHALF, 10, DHALF*DINNER);
  wconv_kernel<<<(DHALF*DINNER+255)/256, 256, 0, stream>>>(b_outp_w, w16_bout, DHALF, 10, DHALF*DINNER);
  wconv_kernel<<<(DMODEL*DMODEL+255)/256, 256, 0, stream>>>(op_w, w16_op, DMODEL, 10, DMODEL*DMODEL);
  // 3-4. in-proj GEMMs: [4096x512]@[2320x512]^T -> zx fp32
  gemm_bf16_kernel<<<dim3(NPADIN/128, ROWS/128), 256, 0, stream>>>(
      u16f, DHALF, w16_fin, zx_f, nullptr, ROWS, DINPROJ, DHALF, DINPROJ, 0, 0, nullptr, nullptr);
  gemm_bf16_kernel<<<dim3(NPADIN/128, ROWS/128), 256, 0, stream>>>(
      u16b, DHALF, w16_bin, zx_b, nullptr, ROWS, DINPROJ, DHALF, DINPROJ, 0, 0, nullptr, nullptr);
  // 5. conv + silu
  conv_silu_kernel<<<dim3(ROWS, 2), 256, 0, stream>>>(
      zx_f, zx_b, f_conv_w, f_conv_b, b_conv_w, b_conv_b, cv_f, cv_b);
  // 6. dt / dA
  dtprep_kernel<<<(2*ROWS*NHEADS)/256, 256, 0, stream>>>(
      zx_f, zx_b, f_dt_bias, f_A_log, b_dt_bias, b_A_log, dt_f, dt_b, dA_f, dA_b);
  // 7. scan (256 wgs, 8 states/thread, DPP reduction)
  scan_kernel<<<256, 256, 0, stream>>>(cv_f, cv_b, dt_f, dt_b, dA_f, dA_b,
                                       f_D, b_D, y_f, y_b);
  // 8. gate + rmsnorm -> bf16 (stride 2048 overlay)
  gate_norm_kernel<<<dim3(ROWS, 2), 256, 0, stream>>>(
      y_f, y_b, zx_f, zx_b, f_gnorm_w, b_gnorm_w);
  // 9-10. out-proj GEMMs -> cat16 bf16 (backward time-flipped)
  gemm_bf16_kernel<<<dim3(DHALF/128, ROWS/128), 256, 0, stream>>>(
      y16f, 2048, w16_fout, nullptr, cat16, ROWS, DHALF, DINNER, DMODEL, 0, 0, nullptr, nullptr);
  gemm_bf16_kernel<<<dim3(DHALF/128, ROWS/128), 256, 0, stream>>>(
      y16b, 2048, w16_bout, nullptr, cat16, ROWS, DHALF, DINNER, DMODEL, DHALF, 1, nullptr, nullptr);
  // 11. final projection + bias + residual (fp32 out)
  gemm_bf16_kernel<<<dim3(DMODEL/128, ROWS/128), 256, 0, stream>>>(
      cat16, DMODEL, w16_op, out, nullptr, ROWS, DMODEL, DMODEL, DMODEL, 0, 0, op_b, x);
}

// Round 5
// 397.125 us; speedup vs baseline: 5.1618x; 1.3956x over previous
//
#include <hip/hip_runtime.h>
#include <math.h>

#define L_SEQ   2048
#define NBATCH  2
#define DMODEL  1024
#define DHALF   512
#define DINNER  1024
#define DSTATE  128
#define NHEADS  16
#define HEADDIM 64
#define CONVDIM 1280
#define DINPROJ 2320
#define XBCDT   1296   /* CONVDIM + NHEADS */
#define ROWS    4096   /* NBATCH * L_SEQ */
#define NPADIN  2432   /* DINPROJ padded to multiple of 128 */

#define QCH     64               /* SSD chunk length */
#define NCH     (L_SEQ / QCH)    /* 32 chunks */

typedef __attribute__((ext_vector_type(8))) short bf16x8;
typedef __attribute__((ext_vector_type(4))) float f32x4;

__device__ __forceinline__ float siluf(float v){ return v / (1.f + expf(-v)); }
__device__ __forceinline__ float softplusf(float v){ return v > 20.f ? v : log1pf(expf(v)); }
__device__ __forceinline__ unsigned short f2bf(float f){
  union { float f; unsigned u; } x; x.f = f;
  unsigned r = (x.u + 0x7fffu + ((x.u >> 16) & 1u)) >> 16;
  return (unsigned short)r;
}
__device__ __forceinline__ float bf2f(unsigned short u){
  union { unsigned u; float f; } x; x.u = ((unsigned)u) << 16; return x.f;
}
__device__ __forceinline__ void gload16(const void* g, void* l){
  __builtin_amdgcn_global_load_lds((const __attribute__((address_space(1))) void*)g,
                                   (__attribute__((address_space(3))) void*)l, 16, 0, 0);
}

__device__ __forceinline__ float blockReduceSum256(float v, float* red){
  #pragma unroll
  for (int o = 32; o > 0; o >>= 1) v += __shfl_xor(v, o);
  int wid = threadIdx.x >> 6, lane = threadIdx.x & 63;
  if (lane == 0) red[wid] = v;
  __syncthreads();
  return red[0] + red[1] + red[2] + red[3];
}

// ---------------- rmsnorm + split into bf16 u_f and (pre-flipped) u_b ----------------
__global__ void rmsnorm_split_kernel(const float* __restrict__ x, const float* __restrict__ nw,
                                     unsigned short* __restrict__ uf, unsigned short* __restrict__ ub){
  __shared__ float red[4];
  int row = blockIdx.x;                       // b*L + t
  const float* xr = x + (size_t)row * DMODEL;
  float loc[4]; float ss = 0.f;
  #pragma unroll
  for (int k = 0; k < 4; k++){ float v = xr[threadIdx.x + k*256]; loc[k] = v; ss += v*v; }
  ss = blockReduceSum256(ss, red);
  float scale = rsqrtf(ss * (1.f/DMODEL) + 1e-5f);
  int t = row & (L_SEQ-1);
  int fliprow = (row ^ t) | (L_SEQ-1-t);
  #pragma unroll
  for (int k = 0; k < 4; k++){
    int d = threadIdx.x + k*256;
    float v = loc[k] * scale * nw[d];
    if (d < DHALF) uf[(size_t)row*DHALF + d] = f2bf(v);
    else           ub[(size_t)fliprow*DHALF + (d - DHALF)] = f2bf(v);
  }
}

// ---------------- weight fp32 -> bf16 (+row pad) ----------------
__global__ void wconv_kernel(const float* __restrict__ src, unsigned short* __restrict__ dst,
                             int rows, int kshift, int total){
  int idx = blockIdx.x*256 + threadIdx.x;
  if (idx >= total) return;
  int row = idx >> kshift;
  dst[idx] = (row < rows) ? f2bf(src[idx]) : (unsigned short)0;
}

// ---------------- bf16 MFMA GEMM: C[m, coff+n] = sum_k A[m,k]*W[n,k] ----------
// Output: n < nsplit -> Cf (fp32) or Ch (bf16) at ldc; n >= nsplit -> Cf2 fp32 at ldc2.
__global__ __launch_bounds__(256) void gemm_bf16_kernel(
    const unsigned short* __restrict__ A, int lda,
    const unsigned short* __restrict__ W,
    float* __restrict__ Cf, unsigned short* __restrict__ Ch,
    float* __restrict__ Cf2, int nsplit, int ldc2,
    int M, int Nreal, int K, int ldc, int coff, int flip,
    const float* __restrict__ bias, const float* __restrict__ res){
  __shared__ unsigned short As[128*32];
  __shared__ unsigned short Bs[128*32];
  int bm = blockIdx.y*128, bn = blockIdx.x*128;
  int tid = threadIdx.x;
  int lane = tid & 63;
  int wave = tid >> 6;
  int wm = (wave >> 1) * 64, wn = (wave & 1) * 64;
  int l15 = lane & 15, lhi = lane >> 4;    // lhi 0..3
  f32x4 acc[4][4];
  #pragma unroll
  for (int i = 0; i < 4; i++)
    #pragma unroll
    for (int j = 0; j < 4; j++)
      acc[i][j] = (f32x4){0.f,0.f,0.f,0.f};

  for (int k0 = 0; k0 < K; k0 += 32){
    #pragma unroll
    for (int j = 0; j < 2; j++){
      int f = j*256 + tid;                 // 0..511 16B-chunks (128 rows x 4 chunks)
      int row = f >> 2, c8 = (f & 3) * 8;
      gload16(A + (size_t)(bm+row)*lda + k0 + c8, &As[f*8]);
      gload16(W + (size_t)(bn+row)*K   + k0 + c8, &Bs[f*8]);
    }
    __syncthreads();
    bf16x8 af[4], bfr[4];
    #pragma unroll
    for (int i = 0; i < 4; i++){
      af[i]  = *(const bf16x8*)&As[(wm + i*16 + l15)*32 + lhi*8];
      bfr[i] = *(const bf16x8*)&Bs[(wn + i*16 + l15)*32 + lhi*8];
    }
    #pragma unroll
    for (int i = 0; i < 4; i++)
      #pragma unroll
      for (int j = 0; j < 4; j++)
        acc[i][j] = __builtin_amdgcn_mfma_f32_16x16x32_bf16(af[i], bfr[j], acc[i][j], 0, 0, 0);
    __syncthreads();
  }
  #pragma unroll
  for (int i = 0; i < 4; i++){
    #pragma unroll
    for (int r = 0; r < 4; r++){
      int m = bm + wm + i*16 + lhi*4 + r;
      int mo = m;
      if (flip){ int t = m & (L_SEQ-1); mo = (m ^ t) | (L_SEQ-1-t); }
      #pragma unroll
      for (int j = 0; j < 4; j++){
        int n = bn + wn + j*16 + l15;
        if (n < Nreal){
          float v = acc[i][j][r];
          if (bias) v += bias[n];
          if (res)  v += res[(size_t)mo*ldc + coff + n];
          if (n < nsplit){
            size_t o = (size_t)mo*ldc + coff + n;
            if (Cf) Cf[o] = v;
            else    Ch[o] = f2bf(v);
          } else {
            Cf2[(size_t)mo*ldc2 + (n - nsplit)] = v;
          }
        }
      }
    }
  }
}

// ---------------- causal depthwise conv (k=4) + silu over xBC channels ----------------
__global__ void conv_silu_kernel(const float* __restrict__ zxf, const float* __restrict__ zxb,
                                 const float* __restrict__ cwf, const float* __restrict__ cbf,
                                 const float* __restrict__ cwb, const float* __restrict__ cbb,
                                 float* __restrict__ cvf, float* __restrict__ cvb){
  int row = blockIdx.x; int dir = blockIdx.y;
  const float* zx = dir ? zxb : zxf;     // [ROWS][XBCDT], xBC at col 0
  const float* cw = dir ? cwb : cwf;
  const float* cb = dir ? cbb : cbf;
  float* cv = dir ? cvb : cvf;
  int t = row & (L_SEQ-1);
  for (int c = threadIdx.x; c < CONVDIM; c += 256){
    const float* base = zx + (size_t)row*XBCDT + c;
    float v = cb[c];
    if (t >= 1) v += base[-1*(ptrdiff_t)XBCDT] * cw[c*4+2];
    if (t >= 2) v += base[-2*(ptrdiff_t)XBCDT] * cw[c*4+1];
    if (t >= 3) v += base[-3*(ptrdiff_t)XBCDT] * cw[c*4+0];
    v += base[0] * cw[c*4+3];
    cv[(size_t)row*CONVDIM + c] = siluf(v);
  }
}

// ---------------- dt softplus + dtA = dt*A ----------------
__global__ void dtprep_kernel(const float* __restrict__ zxf, const float* __restrict__ zxb,
                              const float* __restrict__ dbf, const float* __restrict__ alf,
                              const float* __restrict__ dbb, const float* __restrict__ alb,
                              float* __restrict__ dtf, float* __restrict__ dtb,
                              float* __restrict__ dtAf, float* __restrict__ dtAb){
  int idx = blockIdx.x*256 + threadIdx.x;   // 0 .. 2*ROWS*NHEADS-1
  int dir = idx >> 16;
  int r = idx & 65535;
  int h = r & 15, row = r >> 4;
  const float* zx = dir ? zxb : zxf;
  float raw = zx[(size_t)row*XBCDT + CONVDIM + h];
  float bias = (dir ? dbb : dbf)[h];
  float dtv = softplusf(raw + bias);
  float a = -expf((dir ? alb : alf)[h]);
  (dir ? dtb : dtf)[r] = dtv;
  (dir ? dtAb : dtAf)[r] = dtv * a;
}

// ---------------- K_A: per-chunk inclusive cumsum of dtA ----------------
// acs[dbh*2048 + c*64 + tau]; dbh = (dir*2+b)*16+h. 512 blocks x 256 thr (4 waves).
__global__ void cumsum_kernel(const float* __restrict__ dtAf, const float* __restrict__ dtAb,
                              float* __restrict__ acs){
  int tid = threadIdx.x;
  int wid = blockIdx.x*4 + (tid >> 6);      // 0..2047 = dbh*32 + c
  int tau = tid & 63;
  int c = wid & 31, dbh = wid >> 5;
  int h = dbh & 15, b = (dbh >> 4) & 1, dir = dbh >> 5;
  const float* dtA = dir ? dtAb : dtAf;
  float v = dtA[((size_t)b*L_SEQ + c*QCH + tau)*NHEADS + h];
  #pragma unroll
  for (int off = 1; off < 64; off <<= 1){
    float u = __shfl_up(v, off);
    if (tau >= off) v += u;
  }
  acs[(size_t)dbh*L_SEQ + c*QCH + tau] = v;
}

// ---------------- K_G: G[t][s] = C[t]·B[s], per (dir,b,chunk) ----------------
// grid (32, 4): x=c, y=db. G layout: G[(db*32+c)*4096 + t*64 + s].
__global__ __launch_bounds__(256) void gemm_g_kernel(
    const float* __restrict__ cvf, const float* __restrict__ cvb, float* __restrict__ G){
  int c = blockIdx.x, db = blockIdx.y;
  int b = db & 1, dir = db >> 1;
  const float* cv = dir ? cvb : cvf;
  float* Gp = G + ((size_t)(db*32 + c))*4096;
  int tid = threadIdx.x;
  int tx = tid & 15, ty = tid >> 4;
  __shared__ __align__(16) float Bs[QCH][DSTATE];
  __shared__ __align__(16) float Cs[QCH][DSTATE];
  size_t r0 = (size_t)b*L_SEQ + (size_t)c*QCH;
  #pragma unroll
  for (int k = 0; k < 8; k++){
    int f = k*256 + tid;                 // 0..2047
    int r = f >> 5, q = (f & 31)*4;
    *(float4*)&Bs[r][q] = *(const float4*)&cv[(r0+r)*CONVDIM + DINNER + q];
    *(float4*)&Cs[r][q] = *(const float4*)&cv[(r0+r)*CONVDIM + DINNER + DSTATE + q];
  }
  __syncthreads();
  float acc[4][4] = {};
  for (int n0 = 0; n0 < DSTATE; n0 += 4){
    float4 ca[4], bb[4];
    #pragma unroll
    for (int i = 0; i < 4; i++) ca[i] = *(const float4*)&Cs[ty*4+i][n0];
    #pragma unroll
    for (int j = 0; j < 4; j++) bb[j] = *(const float4*)&Bs[tx*4+j][n0];
    #pragma unroll
    for (int i = 0; i < 4; i++)
      #pragma unroll
      for (int j = 0; j < 4; j++)
        acc[i][j] += ca[i].x*bb[j].x + ca[i].y*bb[j].y + ca[i].z*bb[j].z + ca[i].w*bb[j].w;
  }
  #pragma unroll
  for (int i = 0; i < 4; i++){
    float4 o = {acc[i][0], acc[i][1], acc[i][2], acc[i][3]};
    *(float4*)&Gp[(ty*4+i)*64 + tx*4] = o;
  }
}

// ---------------- K_Y: intra-chunk Y + chunk-state S, per (dir,b,h,chunk) ----------------
// grid (32, 64): x=c, y=dbh. Writes Y_intra -> y, S (bf16) -> S16 per dir.
__global__ __launch_bounds__(256, 2) void intra_kernel(
    const float* __restrict__ cvf, const float* __restrict__ cvb,
    const float* __restrict__ dtf, const float* __restrict__ dtb,
    const float* __restrict__ acs, const float* __restrict__ G,
    float* __restrict__ yf, float* __restrict__ yb,
    unsigned short* __restrict__ S16f, unsigned short* __restrict__ S16b){
  int c = blockIdx.x, dbh = blockIdx.y;
  int h = dbh & 15, b = (dbh >> 4) & 1, dir = dbh >> 5;
  const float* cv  = dir ? cvb : cvf;
  const float* dtp = dir ? dtb : dtf;
  float* y = dir ? yb : yf;
  unsigned short* S16 = dir ? S16b : S16f;
  const float* Gp = G + ((size_t)((dir*2+b)*32 + c))*4096;
  int tid = threadIdx.x;
  int tx = tid & 15, ty = tid >> 4;

  __shared__ __align__(16) float Gs[QCH][QCH];     // raw G then Gh (in place)
  __shared__ __align__(16) float dxs[QCH][HEADDIM];
  __shared__ __align__(16) float Bw[QCH][DSTATE];
  __shared__ float a_sh[QCH], w_sh[QCH], dt_sh[QCH];

  size_t r0 = (size_t)b*L_SEQ + (size_t)c*QCH;

  // phase 1: global loads into regs + small LDS
  float4 gv[4], xv[4], bv[8];
  #pragma unroll
  for (int k = 0; k < 4; k++){
    int f = k*256 + tid; int r = f >> 4, q = (f & 15)*4;
    gv[k] = *(const float4*)&Gp[r*64 + q];
    xv[k] = *(const float4*)&cv[(r0+r)*CONVDIM + h*HEADDIM + q];
  }
  #pragma unroll
  for (int k = 0; k < 8; k++){
    int f = k*256 + tid; int r = f >> 5, q = (f & 31)*4;
    bv[k] = *(const float4*)&cv[(r0+r)*CONVDIM + DINNER + q];
  }
  if (tid < 64){
    dt_sh[tid] = dtp[(r0+tid)*NHEADS + h];
    a_sh[tid]  = acs[(size_t)dbh*L_SEQ + c*QCH + tid];
  }
  __syncthreads();
  // phase 2: Gs raw, dxs = dt*x, w
  #pragma unroll
  for (int k = 0; k < 4; k++){
    int f = k*256 + tid; int r = f >> 4, q = (f & 15)*4;
    *(float4*)&Gs[r][q] = gv[k];
    float d = dt_sh[r];
    float4 o = {d*xv[k].x, d*xv[k].y, d*xv[k].z, d*xv[k].w};
    *(float4*)&dxs[r][q] = o;
  }
  if (tid < 64) w_sh[tid] = expf(a_sh[63] - a_sh[tid]);
  __syncthreads();
  // phase 3: Bw = w*B, Gh in place (mask + decay)
  #pragma unroll
  for (int k = 0; k < 8; k++){
    int f = k*256 + tid; int r = f >> 5, q = (f & 31)*4;
    float w = w_sh[r];
    float4 o = {w*bv[k].x, w*bv[k].y, w*bv[k].z, w*bv[k].w};
    *(float4*)&Bw[r][q] = o;
  }
  #pragma unroll
  for (int i = 0; i < 4; i++){
    int t = ty*4 + i;
    #pragma unroll
    for (int j = 0; j < 4; j++){
      int s = tx*4 + j;
      Gs[t][s] = (s <= t) ? Gs[t][s]*expf(a_sh[t] - a_sh[s]) : 0.f;
    }
  }
  __syncthreads();
  // phase 4a: Y_intra[t,p] = sum_s Gh[t][s]*dxs[s][p]
  {
    float acc[4][4] = {};
    for (int s0 = 0; s0 < QCH; s0 += 4){
      float4 ga[4], dd[4];
      #pragma unroll
      for (int i = 0; i < 4; i++) ga[i] = *(const float4*)&Gs[ty*4+i][s0];
      #pragma unroll
      for (int u = 0; u < 4; u++) dd[u] = *(const float4*)&dxs[s0+u][tx*4];
      #pragma unroll
      for (int i = 0; i < 4; i++){
        #pragma unroll
        for (int j = 0; j < 4; j++){
          float dj0 = (&dd[0].x)[j], dj1 = (&dd[1].x)[j], dj2 = (&dd[2].x)[j], dj3 = (&dd[3].x)[j];
          acc[i][j] += ga[i].x*dj0 + ga[i].y*dj1 + ga[i].z*dj2 + ga[i].w*dj3;
        }
      }
    }
    #pragma unroll
    for (int i = 0; i < 4; i++){
      int t = ty*4 + i;
      float4 o = {acc[i][0], acc[i][1], acc[i][2], acc[i][3]};
      *(float4*)&y[(r0+t)*DINNER + h*HEADDIM + tx*4] = o;
    }
  }
  // phase 4b: S[n,p] = sum_s Bw[s][n]*dxs[s][p]  (n = ty*8..+8, p = tx*4..+4)
  {
    float sacc[8][4] = {};
    for (int s = 0; s < QCH; ++s){
      float4 dv = *(const float4*)&dxs[s][tx*4];
      float4 b0 = *(const float4*)&Bw[s][ty*8];
      float4 b1 = *(const float4*)&Bw[s][ty*8+4];
      #pragma unroll
      for (int j = 0; j < 4; j++){
        float d = (&dv.x)[j];
        sacc[0][j] += b0.x*d; sacc[1][j] += b0.y*d;
        sacc[2][j] += b0.z*d; sacc[3][j] += b0.w*d;
        sacc[4][j] += b1.x*d; sacc[5][j] += b1.y*d;
        sacc[6][j] += b1.z*d; sacc[7][j] += b1.w*d;
      }
    }
    size_t sbase = ((size_t)((b*NHEADS + h)*NCH + c))*8192;
    #pragma unroll
    for (int i = 0; i < 8; i++){
      int n = ty*8 + i;
      unsigned u0 = (unsigned)f2bf(sacc[i][0]) | ((unsigned)f2bf(sacc[i][1]) << 16);
      unsigned u1 = (unsigned)f2bf(sacc[i][2]) | ((unsigned)f2bf(sacc[i][3]) << 16);
      uint2 o = {u0, u1};
      *(uint2*)&S16[sbase + n*64 + tx*4] = o;
    }
  }
}

// ---------------- K_S: inter-chunk state recurrence ----------------
// 1024 blocks x 256 thr; thread owns 2 consecutive states of one dbh.
__global__ void chunkscan_kernel(const unsigned short* __restrict__ S16f,
                                 const unsigned short* __restrict__ S16b,
                                 const float* __restrict__ acs,
                                 unsigned short* __restrict__ hin16){
  __shared__ float sa[NCH];
  int tid = threadIdx.x;
  int dbh = blockIdx.x >> 4;
  int e0 = ((blockIdx.x & 15)*256 + tid)*2;
  int bh = dbh & 31, dir = dbh >> 5;
  const unsigned short* S16 = dir ? S16b : S16f;
  if (tid < NCH) sa[tid] = expf(acs[(size_t)dbh*L_SEQ + tid*QCH + 63]);
  __syncthreads();
  float h0 = 0.f, h1 = 0.f;
  #pragma unroll 8
  for (int c = 0; c < NCH; ++c){
    size_t sidx = ((size_t)(bh*NCH + c))*8192 + e0;
    size_t hidx = ((size_t)(dbh*NCH + c))*8192 + e0;
    unsigned sv = *(const unsigned*)&S16[sidx];
    unsigned hv = (unsigned)f2bf(h0) | ((unsigned)f2bf(h1) << 16);
    *(unsigned*)&hin16[hidx] = hv;
    float ea = sa[c];
    h0 = ea*h0 + bf2f((unsigned short)(sv & 0xffff));
    h1 = ea*h1 + bf2f((unsigned short)(sv >> 16));
  }
}

// ---------------- K_I: Y_inter + D*x, added into y ----------------
// grid (32, 64): x=c, y=dbh.
__global__ __launch_bounds__(256, 2) void inter_kernel(
    const float* __restrict__ cvf, const float* __restrict__ cvb,
    const float* __restrict__ acs, const unsigned short* __restrict__ hin16,
    const float* __restrict__ Df, const float* __restrict__ Db,
    float* __restrict__ yf, float* __restrict__ yb){
  int c = blockIdx.x, dbh = blockIdx.y;
  int h = dbh & 15, b = (dbh >> 4) & 1, dir = dbh >> 5;
  const float* cv = dir ? cvb : cvf;
  float* y = dir ? yb : yf;
  float Dh = (dir ? Db : Df)[h];
  int tid = threadIdx.x;
  int tx = tid & 15, ty = tid >> 4;
  __shared__ __align__(16) float Cs[QCH][DSTATE];
  __shared__ __align__(16) float Hs[DSTATE][HEADDIM];
  __shared__ float e_sh[QCH];
  size_t r0 = (size_t)b*L_SEQ + (size_t)c*QCH;
  #pragma unroll
  for (int k = 0; k < 8; k++){
    int f = k*256 + tid; int r = f >> 5, q = (f & 31)*4;
    *(float4*)&Cs[r][q] = *(const float4*)&cv[(r0+r)*CONVDIM + DINNER + DSTATE + q];
  }
  {
    size_t hbase = ((size_t)(dbh*NCH + c))*8192;
    #pragma unroll
    for (int k = 0; k < 4; k++){
      int f = k*256 + tid;
      int idx = f*8;
      uint4 hv = *(const uint4*)&hin16[hbase + idx];
      int n = idx >> 6, p0 = idx & 63;
      Hs[n][p0+0] = bf2f((unsigned short)(hv.x & 0xffff));
      Hs[n][p0+1] = bf2f((unsigned short)(hv.x >> 16));
      Hs[n][p0+2] = bf2f((unsigned short)(hv.y & 0xffff));
      Hs[n][p0+3] = bf2f((unsigned short)(hv.y >> 16));
      Hs[n][p0+4] = bf2f((unsigned short)(hv.z & 0xffff));
      Hs[n][p0+5] = bf2f((unsigned short)(hv.z >> 16));
      Hs[n][p0+6] = bf2f((unsigned short)(hv.w & 0xffff));
      Hs[n][p0+7] = bf2f((unsigned short)(hv.w >> 16));
    }
  }
  if (tid < 64) e_sh[tid] = expf(acs[(size_t)dbh*L_SEQ + c*QCH + tid]);
  __syncthreads();
  float acc[4][4] = {};
  for (int n0 = 0; n0 < DSTATE; n0 += 4){
    float4 ca[4], hh[4];
    #pragma unroll
    for (int i = 0; i < 4; i++) ca[i] = *(const float4*)&Cs[ty*4+i][n0];
    #pragma unroll
    for (int u = 0; u < 4; u++) hh[u] = *(const float4*)&Hs[n0+u][tx*4];
    #pragma unroll
    for (int i = 0; i < 4; i++){
      #pragma unroll
      for (int j = 0; j < 4; j++){
        float hj0 = (&hh[0].x)[j], hj1 = (&hh[1].x)[j], hj2 = (&hh[2].x)[j], hj3 = (&hh[3].x)[j];
        acc[i][j] += ca[i].x*hj0 + ca[i].y*hj1 + ca[i].z*hj2 + ca[i].w*hj3;
      }
    }
  }
  #pragma unroll
  for (int i = 0; i < 4; i++){
    int t = ty*4 + i;
    size_t row = r0 + t;
    float4 yv = *(const float4*)&y[row*DINNER + h*HEADDIM + tx*4];
    float4 xv = *(const float4*)&cv[row*CONVDIM + h*HEADDIM + tx*4];
    float et = e_sh[t];
    float4 o = {yv.x + et*acc[i][0] + Dh*xv.x,
                yv.y + et*acc[i][1] + Dh*xv.y,
                yv.z + et*acc[i][2] + Dh*xv.z,
                yv.w + et*acc[i][3] + Dh*xv.w};
    *(float4*)&y[row*DINNER + h*HEADDIM + tx*4] = o;
  }
}

// ---------------- gate (silu(z)) + rmsnorm; writes bf16 at row stride 2048 over y ----
__global__ void gate_norm_kernel(float* __restrict__ yf, float* __restrict__ yb,
                                 const float* __restrict__ zf, const float* __restrict__ zb,
                                 const float* __restrict__ gwf, const float* __restrict__ gwb){
  __shared__ float red[4];
  int row = blockIdx.x; int dir = blockIdx.y;
  float* ybase = dir ? yb : yf;
  const float* yr = ybase + (size_t)row*DINNER;
  unsigned short* yh = (unsigned short*)ybase + (size_t)row*2048;  // overlays same fp32 row
  const float* z = (dir ? zb : zf) + (size_t)row*DINNER;
  const float* gw = dir ? gwb : gwf;
  float v[4]; float ss = 0.f;
  #pragma unroll
  for (int k = 0; k < 4; k++){
    int d = threadIdx.x + k*256;
    float val = yr[d] * siluf(z[d]);
    v[k] = val; ss += val*val;
  }
  ss = blockReduceSum256(ss, red);   // __syncthreads inside: all reads precede writes
  float scale = rsqrtf(ss*(1.f/DINNER) + 1e-5f);
  #pragma unroll
  for (int k = 0; k < 4; k++){
    int d = threadIdx.x + k*256;
    yh[d] = f2bf(v[k]*scale*gw[d]);
  }
}

extern "C" void kernel_launch(void* const* d_in, const int* in_sizes, int n_in,
                              void* d_out, int out_size, void* d_ws, size_t ws_size,
                              hipStream_t stream) {
  const float* x      = (const float*)d_in[0];
  const float* norm_w = (const float*)d_in[1];
  const float* op_w   = (const float*)d_in[2];
  const float* op_b   = (const float*)d_in[3];
  const float* f_in_w    = (const float*)d_in[4];
  const float* f_conv_w  = (const float*)d_in[5];
  const float* f_conv_b  = (const float*)d_in[6];
  const float* f_dt_bias = (const float*)d_in[7];
  const float* f_A_log   = (const float*)d_in[8];
  const float* f_D       = (const float*)d_in[9];
  const float* f_gnorm_w = (const float*)d_in[10];
  const float* f_outp_w  = (const float*)d_in[11];
  const float* b_in_w    = (const float*)d_in[12];
  const float* b_conv_w  = (const float*)d_in[13];
  const float* b_conv_b  = (const float*)d_in[14];
  const float* b_dt_bias = (const float*)d_in[15];
  const float* b_A_log   = (const float*)d_in[16];
  const float* b_D       = (const float*)d_in[17];
  const float* b_gnorm_w = (const float*)d_in[18];
  const float* b_outp_w  = (const float*)d_in[19];
  float* out = (float*)d_out;

  float* ws = (float*)d_ws;
  size_t off = 0;
  unsigned short* u16f = (unsigned short*)(ws + off);
  unsigned short* u16b = u16f + (size_t)ROWS*DHALF;      off += (size_t)ROWS*DHALF;
  float* z_f  = ws + off; off += (size_t)ROWS*DINNER;
  float* z_b  = ws + off; off += (size_t)ROWS*DINNER;
  float* zx2_f = ws + off; off += (size_t)ROWS*XBCDT;   // xBC+dt; later overlaid by S16_f
  float* zx2_b = ws + off; off += (size_t)ROWS*XBCDT;
  float* cv_f = ws + off; off += (size_t)ROWS*CONVDIM;
  float* cv_b = ws + off; off += (size_t)ROWS*CONVDIM;
  float* dt_f = ws + off; off += (size_t)ROWS*NHEADS;
  float* dt_b = ws + off; off += (size_t)ROWS*NHEADS;
  float* dtA_f = ws + off; off += (size_t)ROWS*NHEADS;
  float* dtA_b = ws + off; off += (size_t)ROWS*NHEADS;
  float* y_f  = ws + off; off += (size_t)ROWS*DINNER;
  float* y_b  = ws + off; off += (size_t)ROWS*DINNER;
  float* acs  = ws + off; off += (size_t)64*L_SEQ;          // 131K
  float* G    = ws + off; off += (size_t)128*QCH*QCH;       // 524K
  unsigned short* hin16 = (unsigned short*)(ws + off); off += (size_t)64*NCH*8192/2; // 8.4M floats
  unsigned short* w16_fin  = (unsigned short*)(ws + off); off += (size_t)NPADIN*DHALF/2;
  unsigned short* w16_bin  = (unsigned short*)(ws + off); off += (size_t)NPADIN*DHALF/2;
  unsigned short* w16_fout = (unsigned short*)(ws + off); off += (size_t)DHALF*DINNER/2;
  unsigned short* w16_bout = (unsigned short*)(ws + off); off += (size_t)DHALF*DINNER/2;
  unsigned short* w16_op   = (unsigned short*)(ws + off); off += (size_t)DMODEL*DMODEL/2;
  // S16 (bf16, per dir: 2*16*32*8192 = 8.4M shorts) overlays zx2 (dead after conv+dtprep)
  unsigned short* S16f = (unsigned short*)zx2_f;
  unsigned short* S16b = (unsigned short*)zx2_b;
  // cat (bf16 [ROWS][1024]) overlays z_f (dead after gate_norm)
  unsigned short* cat16 = (unsigned short*)z_f;
  // bf16 gated-y overlays y_f / y_b at row stride 2048
  unsigned short* y16f = (unsigned short*)y_f;
  unsigned short* y16b = (unsigned short*)y_b;

  // 1. rmsnorm + split (bf16, backward pre-flipped)
  rmsnorm_split_kernel<<<ROWS, 256, 0, stream>>>(x, norm_w, u16f, u16b);
  // 2. weight conversions
  wconv_kernel<<<(NPADIN*DHALF+255)/256, 256, 0, stream>>>(f_in_w, w16_fin, DINPROJ, 9, NPADIN*DHALF);
  wconv_kernel<<<(NPADIN*DHALF+255)/256, 256, 0, stream>>>(b_in_w, w16_bin, DINPROJ, 9, NPADIN*DHALF);
  wconv_kernel<<<(DHALF*DINNER+255)/256, 256, 0, stream>>>(f_outp_w, w16_fout, DHALF, 10, DHALF*DINNER);
  wconv_kernel<<<(DHALF*DINNER+255)/256, 256, 0, stream>>>(b_outp_w, w16_bout, DHALF, 10, DHALF*DINNER);
  wconv_kernel<<<(DMODEL*DMODEL+255)/256, 256, 0, stream>>>(op_w, w16_op, DMODEL, 10, DMODEL*DMODEL);
  // 3-4. in-proj GEMMs, split output: z (cols<1024) and zx2 (cols>=1024)
  gemm_bf16_kernel<<<dim3(NPADIN/128, ROWS/128), 256, 0, stream>>>(
      u16f, DHALF, w16_fin, z_f, nullptr, zx2_f, DINNER, XBCDT,
      ROWS, DINPROJ, DHALF, DINNER, 0, 0, nullptr, nullptr);
  gemm_bf16_kernel<<<dim3(NPADIN/128, ROWS/128), 256, 0, stream>>>(
      u16b, DHALF, w16_bin, z_b, nullptr, zx2_b, DINNER, XBCDT,
      ROWS, DINPROJ, DHALF, DINNER, 0, 0, nullptr, nullptr);
  // 5. conv + silu
  conv_silu_kernel<<<dim3(ROWS, 2), 256, 0, stream>>>(
      zx2_f, zx2_b, f_conv_w, f_conv_b, b_conv_w, b_conv_b, cv_f, cv_b);
  // 6. dt / dtA
  dtprep_kernel<<<(2*ROWS*NHEADS)/256, 256, 0, stream>>>(
      zx2_f, zx2_b, f_dt_bias, f_A_log, b_dt_bias, b_A_log, dt_f, dt_b, dtA_f, dtA_b);
  // 7. SSD scan replacement
  cumsum_kernel<<<512, 256, 0, stream>>>(dtA_f, dtA_b, acs);
  gemm_g_kernel<<<dim3(32, 4), 256, 0, stream>>>(cv_f, cv_b, G);
  intra_kernel<<<dim3(32, 64), 256, 0, stream>>>(cv_f, cv_b, dt_f, dt_b, acs, G,
                                                 y_f, y_b, S16f, S16b);
  chunkscan_kernel<<<1024, 256, 0, stream>>>(S16f, S16b, acs, hin16);
  inter_kernel<<<dim3(32, 64), 256, 0, stream>>>(cv_f, cv_b, acs, hin16, f_D, b_D, y_f, y_b);
  // 8. gate + rmsnorm -> bf16 (stride 2048 overlay)
  gate_norm_kernel<<<dim3(ROWS, 2), 256, 0, stream>>>(
      y_f, y_b, z_f, z_b, f_gnorm_w, b_gnorm_w);
  // 9-10. out-proj GEMMs -> cat16 bf16 (backward time-flipped)
  gemm_bf16_kernel<<<dim3(DHALF/128, ROWS/128), 256, 0, stream>>>(
      y16f, 2048, w16_fout, nullptr, cat16, nullptr, 1<<30, 0,
      ROWS, DHALF, DINNER, DMODEL, 0, 0, nullptr, nullptr);
  gemm_bf16_kernel<<<dim3(DHALF/128, ROWS/128), 256, 0, stream>>>(
      y16b, 2048, w16_bout, nullptr, cat16, nullptr, 1<<30, 0,
      ROWS, DHALF, DINNER, DMODEL, DHALF, 1, nullptr, nullptr);
  // 11. final projection + bias + residual (fp32 out)
  gemm_bf16_kernel<<<dim3(DMODEL/128, ROWS/128), 256, 0, stream>>>(
      cat16, DMODEL, w16_op, out, nullptr, nullptr, 1<<30, 0,
      ROWS, DMODEL, DMODEL, DMODEL, 0, 0, op_b, x);
}

// Round 6
// 311.302 us; speedup vs baseline: 6.5849x; 1.2757x over previous
//
#include <hip/hip_runtime.h>
#include <math.h>

#define L_SEQ   2048
#define NBATCH  2
#define DMODEL  1024
#define DHALF   512
#define DINNER  1024
#define DSTATE  128
#define NHEADS  16
#define HEADDIM 64
#define CONVDIM 1280
#define DINPROJ 2320
#define XBCDT   1296   /* CONVDIM + NHEADS */
#define ROWS    4096   /* NBATCH * L_SEQ */
#define NPADIN  2432   /* DINPROJ padded to multiple of 128 */

#define QCH     64               /* SSD chunk length */
#define NCH     (L_SEQ / QCH)    /* 32 chunks */

typedef __attribute__((ext_vector_type(8))) short bf16x8;
typedef __attribute__((ext_vector_type(4))) float f32x4;

union US8 { uint4 q; unsigned short s[8]; };

__device__ __forceinline__ float siluf(float v){ return v / (1.f + expf(-v)); }
__device__ __forceinline__ float softplusf(float v){ return v > 20.f ? v : log1pf(expf(v)); }
__device__ __forceinline__ unsigned short f2bf(float f){
  union { float f; unsigned u; } x; x.f = f;
  unsigned r = (x.u + 0x7fffu + ((x.u >> 16) & 1u)) >> 16;
  return (unsigned short)r;
}
__device__ __forceinline__ float bf2f(unsigned short u){
  union { unsigned u; float f; } x; x.u = ((unsigned)u) << 16; return x.f;
}
__device__ __forceinline__ void gload16(const void* g, void* l){
  __builtin_amdgcn_global_load_lds((const __attribute__((address_space(1))) void*)g,
                                   (__attribute__((address_space(3))) void*)l, 16, 0, 0);
}
// XOR swizzle key for LDS tiles: spreads column accesses across banks while
// keeping 8-short (16B) granules intact (b128-read safe).
__device__ __forceinline__ int kx(int row){ return ((row ^ (row >> 3)) & 7) << 3; }

__device__ __forceinline__ float blockReduceSum256(float v, float* red){
  #pragma unroll
  for (int o = 32; o > 0; o >>= 1) v += __shfl_xor(v, o);
  int wid = threadIdx.x >> 6, lane = threadIdx.x & 63;
  if (lane == 0) red[wid] = v;
  __syncthreads();
  return red[0] + red[1] + red[2] + red[3];
}

// ---------------- rmsnorm + split into bf16 u_f and (pre-flipped) u_b ----------------
__global__ void rmsnorm_split_kernel(const float* __restrict__ x, const float* __restrict__ nw,
                                     unsigned short* __restrict__ uf, unsigned short* __restrict__ ub){
  __shared__ float red[4];
  int row = blockIdx.x;                       // b*L + t
  const float* xr = x + (size_t)row * DMODEL;
  float loc[4]; float ss = 0.f;
  #pragma unroll
  for (int k = 0; k < 4; k++){ float v = xr[threadIdx.x + k*256]; loc[k] = v; ss += v*v; }
  ss = blockReduceSum256(ss, red);
  float scale = rsqrtf(ss * (1.f/DMODEL) + 1e-5f);
  int t = row & (L_SEQ-1);
  int fliprow = (row ^ t) | (L_SEQ-1-t);
  #pragma unroll
  for (int k = 0; k < 4; k++){
    int d = threadIdx.x + k*256;
    float v = loc[k] * scale * nw[d];
    if (d < DHALF) uf[(size_t)row*DHALF + d] = f2bf(v);
    else           ub[(size_t)fliprow*DHALF + (d - DHALF)] = f2bf(v);
  }
}

// ---------------- weight fp32 -> bf16 (+row pad) ----------------
__global__ void wconv_kernel(const float* __restrict__ src, unsigned short* __restrict__ dst,
                             int rows, int kshift, int total){
  int idx = blockIdx.x*256 + threadIdx.x;
  if (idx >= total) return;
  int row = idx >> kshift;
  dst[idx] = (row < rows) ? f2bf(src[idx]) : (unsigned short)0;
}

// ---------------- bf16 MFMA GEMM: C[m, coff+n] = sum_k A[m,k]*W[n,k] ----------
// Output: n < nsplit -> Cf (fp32) or Ch (bf16) at ldc; n >= nsplit -> Cf2 fp32 at ldc2.
__global__ __launch_bounds__(256) void gemm_bf16_kernel(
    const unsigned short* __restrict__ A, int lda,
    const unsigned short* __restrict__ W,
    float* __restrict__ Cf, unsigned short* __restrict__ Ch,
    float* __restrict__ Cf2, int nsplit, int ldc2,
    int M, int Nreal, int K, int ldc, int coff, int flip,
    const float* __restrict__ bias, const float* __restrict__ res){
  __shared__ unsigned short As[128*32];
  __shared__ unsigned short Bs[128*32];
  int bm = blockIdx.y*128, bn = blockIdx.x*128;
  int tid = threadIdx.x;
  int lane = tid & 63;
  int wave = tid >> 6;
  int wm = (wave >> 1) * 64, wn = (wave & 1) * 64;
  int l15 = lane & 15, lhi = lane >> 4;    // lhi 0..3
  f32x4 acc[4][4];
  #pragma unroll
  for (int i = 0; i < 4; i++)
    #pragma unroll
    for (int j = 0; j < 4; j++)
      acc[i][j] = (f32x4){0.f,0.f,0.f,0.f};

  for (int k0 = 0; k0 < K; k0 += 32){
    #pragma unroll
    for (int j = 0; j < 2; j++){
      int f = j*256 + tid;                 // 0..511 16B-chunks (128 rows x 4 chunks)
      int row = f >> 2, c8 = (f & 3) * 8;
      gload16(A + (size_t)(bm+row)*lda + k0 + c8, &As[f*8]);
      gload16(W + (size_t)(bn+row)*K   + k0 + c8, &Bs[f*8]);
    }
    __syncthreads();
    bf16x8 af[4], bfr[4];
    #pragma unroll
    for (int i = 0; i < 4; i++){
      af[i]  = *(const bf16x8*)&As[(wm + i*16 + l15)*32 + lhi*8];
      bfr[i] = *(const bf16x8*)&Bs[(wn + i*16 + l15)*32 + lhi*8];
    }
    #pragma unroll
    for (int i = 0; i < 4; i++)
      #pragma unroll
      for (int j = 0; j < 4; j++)
        acc[i][j] = __builtin_amdgcn_mfma_f32_16x16x32_bf16(af[i], bfr[j], acc[i][j], 0, 0, 0);
    __syncthreads();
  }
  #pragma unroll
  for (int i = 0; i < 4; i++){
    #pragma unroll
    for (int r = 0; r < 4; r++){
      int m = bm + wm + i*16 + lhi*4 + r;
      int mo = m;
      if (flip){ int t = m & (L_SEQ-1); mo = (m ^ t) | (L_SEQ-1-t); }
      #pragma unroll
      for (int j = 0; j < 4; j++){
        int n = bn + wn + j*16 + l15;
        if (n < Nreal){
          float v = acc[i][j][r];
          if (bias) v += bias[n];
          if (res)  v += res[(size_t)mo*ldc + coff + n];
          if (n < nsplit){
            size_t o = (size_t)mo*ldc + coff + n;
            if (Cf) Cf[o] = v;
            else    Ch[o] = f2bf(v);
          } else {
            Cf2[(size_t)mo*ldc2 + (n - nsplit)] = v;
          }
        }
      }
    }
  }
}

// ---------------- causal depthwise conv (k=4) + silu -> bf16 cv16 ----------------
__global__ void conv_silu_kernel(const float* __restrict__ zxf, const float* __restrict__ zxb,
                                 const float* __restrict__ cwf, const float* __restrict__ cbf,
                                 const float* __restrict__ cwb, const float* __restrict__ cbb,
                                 unsigned short* __restrict__ cvf, unsigned short* __restrict__ cvb){
  int row = blockIdx.x; int dir = blockIdx.y;
  const float* zx = dir ? zxb : zxf;     // [ROWS][XBCDT], xBC at col 0
  const float* cw = dir ? cwb : cwf;
  const float* cb = dir ? cbb : cbf;
  unsigned short* cv = dir ? cvb : cvf;
  int t = row & (L_SEQ-1);
  for (int c = threadIdx.x; c < CONVDIM; c += 256){
    const float* base = zx + (size_t)row*XBCDT + c;
    float v = cb[c];
    if (t >= 1) v += base[-1*(ptrdiff_t)XBCDT] * cw[c*4+2];
    if (t >= 2) v += base[-2*(ptrdiff_t)XBCDT] * cw[c*4+1];
    if (t >= 3) v += base[-3*(ptrdiff_t)XBCDT] * cw[c*4+0];
    v += base[0] * cw[c*4+3];
    cv[(size_t)row*CONVDIM + c] = f2bf(siluf(v));
  }
}

// ---------------- dt softplus + per-chunk inclusive cumsum of dt*A ----------------
// 512 blocks x 256 thr; each wave = one (dbh, chunk). Writes dt and acs.
__global__ void dtcum_kernel(const float* __restrict__ zxf, const float* __restrict__ zxb,
                             const float* __restrict__ dbf, const float* __restrict__ alf,
                             const float* __restrict__ dbb, const float* __restrict__ alb,
                             float* __restrict__ dtf, float* __restrict__ dtb,
                             float* __restrict__ acs){
  int tid = threadIdx.x;
  int wid = blockIdx.x*4 + (tid >> 6);      // 0..2047 = dbh*32 + c
  int tau = tid & 63;
  int c = wid & 31, dbh = wid >> 5;
  int h = dbh & 15, b = (dbh >> 4) & 1, dir = dbh >> 5;
  const float* zx = dir ? zxb : zxf;
  size_t row = (size_t)b*L_SEQ + c*QCH + tau;
  float raw = zx[row*XBCDT + CONVDIM + h];
  float bias = (dir ? dbb : dbf)[h];
  float dtv = softplusf(raw + bias);
  float a = -expf((dir ? alb : alf)[h]);
  (dir ? dtb : dtf)[row*NHEADS + h] = dtv;
  float v = dtv * a;
  #pragma unroll
  for (int off = 1; off < 64; off <<= 1){
    float u = __shfl_up(v, off);
    if (tau >= off) v += u;
  }
  acs[(size_t)dbh*L_SEQ + c*QCH + tau] = v;
}

// ---------------- K_G (MFMA): G[t][s] = C[t]·B[s], per (dir,b,chunk) ----------------
__global__ __launch_bounds__(256) void gemm_g_kernel(
    const unsigned short* __restrict__ cvf, const unsigned short* __restrict__ cvb,
    float* __restrict__ G){
  int c = blockIdx.x, db = blockIdx.y;
  int b = db & 1, dir = db >> 1;
  const unsigned short* cv = dir ? cvb : cvf;
  float* Gp = G + ((size_t)(db*32 + c))*4096;
  int tid = threadIdx.x, lane = tid & 63, w = tid >> 6;
  int l15 = lane & 15, lhi = lane >> 4;
  __shared__ unsigned short sB[64*128];
  __shared__ unsigned short sC[64*128];
  size_t r0 = (size_t)b*L_SEQ + (size_t)c*QCH;
  #pragma unroll
  for (int k = 0; k < 4; k++){
    int cid = k*256 + tid;
    int row = cid >> 4, slot = cid & 15;
    US8 ub, uc;
    ub.q = *(const uint4*)&cv[(r0+row)*CONVDIM + DINNER + slot*8];
    uc.q = *(const uint4*)&cv[(r0+row)*CONVDIM + DINNER + DSTATE + slot*8];
    *(uint4*)&sB[row*128 + (slot*8 ^ kx(row))] = ub.q;
    *(uint4*)&sC[row*128 + (slot*8 ^ kx(row))] = uc.q;
  }
  __syncthreads();
  int t0 = w*16;
  bf16x8 af[4];
  #pragma unroll
  for (int ks = 0; ks < 4; ks++){
    int r = t0 + l15;
    af[ks] = *(const bf16x8*)&sC[r*128 + ((ks*32 + lhi*8) ^ kx(r))];
  }
  f32x4 acc[4];
  #pragma unroll
  for (int j = 0; j < 4; j++) acc[j] = (f32x4){0.f,0.f,0.f,0.f};
  #pragma unroll
  for (int j = 0; j < 4; j++){
    #pragma unroll
    for (int ks = 0; ks < 4; ks++){
      int r = j*16 + l15;
      bf16x8 wf = *(const bf16x8*)&sB[r*128 + ((ks*32 + lhi*8) ^ kx(r))];
      acc[j] = __builtin_amdgcn_mfma_f32_16x16x32_bf16(af[ks], wf, acc[j], 0, 0, 0);
    }
  }
  #pragma unroll
  for (int j = 0; j < 4; j++)
    #pragma unroll
    for (int r = 0; r < 4; r++)
      Gp[(t0 + lhi*4 + r)*64 + j*16 + l15] = acc[j][r];
}

// ---------------- K_Y (MFMA): intra-chunk Y + chunk-state S^T, per (dir,b,h,chunk) ----
__global__ __launch_bounds__(256) void intra_kernel(
    const unsigned short* __restrict__ cvf, const unsigned short* __restrict__ cvb,
    const float* __restrict__ dtf, const float* __restrict__ dtb,
    const float* __restrict__ acs, const float* __restrict__ G,
    float* __restrict__ yf, float* __restrict__ yb,
    unsigned short* __restrict__ S16f, unsigned short* __restrict__ S16b){
  int c = blockIdx.x, dbh = blockIdx.y;
  int h = dbh & 15, b = (dbh >> 4) & 1, dir = dbh >> 5;
  const unsigned short* cv = dir ? cvb : cvf;
  const float* dtp = dir ? dtb : dtf;
  float* y = dir ? yb : yf;
  unsigned short* S16 = dir ? S16b : S16f;
  const float* Gp = G + ((size_t)((dir*2+b)*32 + c))*4096;
  int tid = threadIdx.x, lane = tid & 63, w = tid >> 6;
  int l15 = lane & 15, lhi = lane >> 4;

  __shared__ unsigned short sGh [64*64];   // Gh[t][s]  (A for Y)
  __shared__ unsigned short sDxT[64*64];   // dxT[p][s] (W for Y, A for S^T)
  __shared__ unsigned short sBwT[128*64];  // BwT[n][s] (W for S^T)
  __shared__ float a_sh[QCH], dt_sh[QCH];

  size_t r0 = (size_t)b*L_SEQ + (size_t)c*QCH;
  if (tid < 64){
    a_sh[tid]  = acs[(size_t)dbh*L_SEQ + c*QCH + tid];
    dt_sh[tid] = dtp[(r0 + tid)*NHEADS + h];
  }
  __syncthreads();
  float a63 = a_sh[63];
  // dxT[p][s] = dt[s]*x[s][p], transposed scalar writes (swizzled)
  #pragma unroll
  for (int k = 0; k < 2; k++){
    int cid = k*256 + tid;
    int s = cid >> 3, p0 = (cid & 7)*8;
    US8 u; u.q = *(const uint4*)&cv[(r0+s)*CONVDIM + h*HEADDIM + p0];
    float d = dt_sh[s];
    #pragma unroll
    for (int j = 0; j < 8; j++){
      int p = p0 + j;
      sDxT[p*64 + (s ^ kx(p))] = f2bf(bf2f(u.s[j]) * d);
    }
  }
  // BwT[n][s] = exp(a63-a[s])*B[s][n]
  #pragma unroll
  for (int k = 0; k < 4; k++){
    int cid = k*256 + tid;
    int s = cid >> 4, n0 = (cid & 15)*8;
    US8 u; u.q = *(const uint4*)&cv[(r0+s)*CONVDIM + DINNER + n0];
    float wv = expf(a63 - a_sh[s]);
    #pragma unroll
    for (int j = 0; j < 8; j++){
      int n = n0 + j;
      sBwT[n*64 + (s ^ kx(n))] = f2bf(bf2f(u.s[j]) * wv);
    }
  }
  // Gh[t][s] = (s<=t) ? G[t][s]*exp(a[t]-a[s]) : 0, bf16
  #pragma unroll
  for (int k = 0; k < 4; k++){
    int f = k*256 + tid;
    int t = f >> 4, s0 = (f & 15)*4;
    float4 g = *(const float4*)&Gp[t*64 + s0];
    float at = a_sh[t];
    float v0 = (s0+0 <= t) ? g.x*expf(at - a_sh[s0+0]) : 0.f;
    float v1 = (s0+1 <= t) ? g.y*expf(at - a_sh[s0+1]) : 0.f;
    float v2 = (s0+2 <= t) ? g.z*expf(at - a_sh[s0+2]) : 0.f;
    float v3 = (s0+3 <= t) ? g.w*expf(at - a_sh[s0+3]) : 0.f;
    int addr = t*64 + (s0 ^ kx(t));
    *(unsigned*)&sGh[addr]     = (unsigned)f2bf(v0) | ((unsigned)f2bf(v1) << 16);
    *(unsigned*)&sGh[addr + 2] = (unsigned)f2bf(v2) | ((unsigned)f2bf(v3) << 16);
  }
  __syncthreads();

  int t0 = w*16;                     // Y t-tile; also S^T p-tile
  bf16x8 aY[2], aS[2];
  #pragma unroll
  for (int ks = 0; ks < 2; ks++){
    int rg = t0 + l15;
    aY[ks] = *(const bf16x8*)&sGh [rg*64 + ((ks*32 + lhi*8) ^ kx(rg))];
    aS[ks] = *(const bf16x8*)&sDxT[rg*64 + ((ks*32 + lhi*8) ^ kx(rg))];
  }
  // Y[t][p] = sum_s Gh[t][s] * dxT[p][s]
  f32x4 accY[4];
  #pragma unroll
  for (int j = 0; j < 4; j++) accY[j] = (f32x4){0.f,0.f,0.f,0.f};
  #pragma unroll
  for (int j = 0; j < 4; j++){
    #pragma unroll
    for (int ks = 0; ks < 2; ks++){
      int rp = j*16 + l15;
      bf16x8 wf = *(const bf16x8*)&sDxT[rp*64 + ((ks*32 + lhi*8) ^ kx(rp))];
      accY[j] = __builtin_amdgcn_mfma_f32_16x16x32_bf16(aY[ks], wf, accY[j], 0, 0, 0);
    }
  }
  // S^T[p][n] = sum_s dxT[p][s] * BwT[n][s]
  f32x4 accS[8];
  #pragma unroll
  for (int j = 0; j < 8; j++) accS[j] = (f32x4){0.f,0.f,0.f,0.f};
  #pragma unroll
  for (int j = 0; j < 8; j++){
    #pragma unroll
    for (int ks = 0; ks < 2; ks++){
      int rn = j*16 + l15;
      bf16x8 wf = *(const bf16x8*)&sBwT[rn*64 + ((ks*32 + lhi*8) ^ kx(rn))];
      accS[j] = __builtin_amdgcn_mfma_f32_16x16x32_bf16(aS[ks], wf, accS[j], 0, 0, 0);
    }
  }
  // epilogues
  #pragma unroll
  for (int j = 0; j < 4; j++){
    #pragma unroll
    for (int r = 0; r < 4; r++){
      int t = t0 + lhi*4 + r, p = j*16 + l15;
      y[(r0 + t)*DINNER + h*HEADDIM + p] = accY[j][r];
    }
  }
  size_t sbase = ((size_t)((b*NHEADS + h)*NCH + c))*8192;
  #pragma unroll
  for (int j = 0; j < 8; j++){
    #pragma unroll
    for (int r = 0; r < 4; r++){
      int p = t0 + lhi*4 + r, n = j*16 + l15;
      S16[sbase + p*128 + n] = f2bf(accS[j][r]);
    }
  }
}

// ---------------- K_S: inter-chunk state recurrence (elementwise over [p][n]) --------
__global__ void chunkscan_kernel(const unsigned short* __restrict__ S16f,
                                 const unsigned short* __restrict__ S16b,
                                 const float* __restrict__ acs,
                                 unsigned short* __restrict__ hin16){
  __shared__ float sa[NCH];
  int tid = threadIdx.x;
  int dbh = blockIdx.x >> 4;
  int e0 = ((blockIdx.x & 15)*256 + tid)*2;
  int bh = dbh & 31, dir = dbh >> 5;
  const unsigned short* S16 = dir ? S16b : S16f;
  if (tid < NCH) sa[tid] = expf(acs[(size_t)dbh*L_SEQ + tid*QCH + 63]);
  __syncthreads();
  float h0 = 0.f, h1 = 0.f;
  #pragma unroll 8
  for (int c = 0; c < NCH; ++c){
    size_t sidx = ((size_t)(bh*NCH + c))*8192 + e0;
    size_t hidx = ((size_t)(dbh*NCH + c))*8192 + e0;
    unsigned sv = *(const unsigned*)&S16[sidx];
    unsigned hv = (unsigned)f2bf(h0) | ((unsigned)f2bf(h1) << 16);
    *(unsigned*)&hin16[hidx] = hv;
    float ea = sa[c];
    h0 = ea*h0 + bf2f((unsigned short)(sv & 0xffff));
    h1 = ea*h1 + bf2f((unsigned short)(sv >> 16));
  }
}

// ---------------- K_I (MFMA): Y_inter = e[t]*C·h_in + D*x, added into y -------------
__global__ __launch_bounds__(256) void inter_kernel(
    const unsigned short* __restrict__ cvf, const unsigned short* __restrict__ cvb,
    const float* __restrict__ acs, const unsigned short* __restrict__ hin16,
    const float* __restrict__ Df, const float* __restrict__ Db,
    float* __restrict__ yf, float* __restrict__ yb){
  int c = blockIdx.x, dbh = blockIdx.y;
  int h = dbh & 15, b = (dbh >> 4) & 1, dir = dbh >> 5;
  const unsigned short* cv = dir ? cvb : cvf;
  float* y = dir ? yb : yf;
  float Dh = (dir ? Db : Df)[h];
  int tid = threadIdx.x, lane = tid & 63, w = tid >> 6;
  int l15 = lane & 15, lhi = lane >> 4;
  __shared__ unsigned short sC [64*128];   // C[t][n]  (A)
  __shared__ unsigned short sHT[64*128];   // hT[p][n] (W)
  __shared__ float e_sh[QCH];
  size_t r0 = (size_t)b*L_SEQ + (size_t)c*QCH;
  size_t hbase = ((size_t)(dbh*NCH + c))*8192;
  if (tid < 64) e_sh[tid] = expf(acs[(size_t)dbh*L_SEQ + c*QCH + tid]);
  #pragma unroll
  for (int k = 0; k < 4; k++){
    int cid = k*256 + tid;
    int row = cid >> 4, slot = cid & 15;
    US8 uc, uh;
    uc.q = *(const uint4*)&cv[(r0+row)*CONVDIM + DINNER + DSTATE + slot*8];
    uh.q = *(const uint4*)&hin16[hbase + cid*8];
    *(uint4*)&sC [row*128 + (slot*8 ^ kx(row))] = uc.q;
    *(uint4*)&sHT[row*128 + (slot*8 ^ kx(row))] = uh.q;
  }
  __syncthreads();
  int t0 = w*16;
  bf16x8 af[4];
  #pragma unroll
  for (int ks = 0; ks < 4; ks++){
    int r = t0 + l15;
    af[ks] = *(const bf16x8*)&sC[r*128 + ((ks*32 + lhi*8) ^ kx(r))];
  }
  f32x4 acc[4];
  #pragma unroll
  for (int j = 0; j < 4; j++) acc[j] = (f32x4){0.f,0.f,0.f,0.f};
  #pragma unroll
  for (int j = 0; j < 4; j++){
    #pragma unroll
    for (int ks = 0; ks < 4; ks++){
      int r = j*16 + l15;
      bf16x8 wf = *(const bf16x8*)&sHT[r*128 + ((ks*32 + lhi*8) ^ kx(r))];
      acc[j] = __builtin_amdgcn_mfma_f32_16x16x32_bf16(af[ks], wf, acc[j], 0, 0, 0);
    }
  }
  #pragma unroll
  for (int j = 0; j < 4; j++){
    #pragma unroll
    for (int r = 0; r < 4; r++){
      int t = t0 + lhi*4 + r, p = j*16 + l15;
      size_t row = r0 + t;
      float xv = bf2f(cv[row*CONVDIM + h*HEADDIM + p]);
      float* yp = &y[row*DINNER + h*HEADDIM + p];
      *yp = *yp + e_sh[t]*acc[j][r] + Dh*xv;
    }
  }
}

// ---------------- gate (silu(z)) + rmsnorm; writes bf16 at row stride 2048 over y ----
__global__ void gate_norm_kernel(float* __restrict__ yf, float* __restrict__ yb,
                                 const float* __restrict__ zf, const float* __restrict__ zb,
                                 const float* __restrict__ gwf, const float* __restrict__ gwb){
  __shared__ float red[4];
  int row = blockIdx.x; int dir = blockIdx.y;
  float* ybase = dir ? yb : yf;
  const float* yr = ybase + (size_t)row*DINNER;
  unsigned short* yh = (unsigned short*)ybase + (size_t)row*2048;  // overlays same fp32 row
  const float* z = (dir ? zb : zf) + (size_t)row*DINNER;
  const float* gw = dir ? gwb : gwf;
  float v[4]; float ss = 0.f;
  #pragma unroll
  for (int k = 0; k < 4; k++){
    int d = threadIdx.x + k*256;
    float val = yr[d] * siluf(z[d]);
    v[k] = val; ss += val*val;
  }
  ss = blockReduceSum256(ss, red);   // __syncthreads inside: all reads precede writes
  float scale = rsqrtf(ss*(1.f/DINNER) + 1e-5f);
  #pragma unroll
  for (int k = 0; k < 4; k++){
    int d = threadIdx.x + k*256;
    yh[d] = f2bf(v[k]*scale*gw[d]);
  }
}

extern "C" void kernel_launch(void* const* d_in, const int* in_sizes, int n_in,
                              void* d_out, int out_size, void* d_ws, size_t ws_size,
                              hipStream_t stream) {
  const float* x      = (const float*)d_in[0];
  const float* norm_w = (const float*)d_in[1];
  const float* op_w   = (const float*)d_in[2];
  const float* op_b   = (const float*)d_in[3];
  const float* f_in_w    = (const float*)d_in[4];
  const float* f_conv_w  = (const float*)d_in[5];
  const float* f_conv_b  = (const float*)d_in[6];
  const float* f_dt_bias = (const float*)d_in[7];
  const float* f_A_log   = (const float*)d_in[8];
  const float* f_D       = (const float*)d_in[9];
  const float* f_gnorm_w = (const float*)d_in[10];
  const float* f_outp_w  = (const float*)d_in[11];
  const float* b_in_w    = (const float*)d_in[12];
  const float* b_conv_w  = (const float*)d_in[13];
  const float* b_conv_b  = (const float*)d_in[14];
  const float* b_dt_bias = (const float*)d_in[15];
  const float* b_A_log   = (const float*)d_in[16];
  const float* b_D       = (const float*)d_in[17];
  const float* b_gnorm_w = (const float*)d_in[18];
  const float* b_outp_w  = (const float*)d_in[19];
  float* out = (float*)d_out;

  float* ws = (float*)d_ws;
  size_t off = 0;
  unsigned short* u16f = (unsigned short*)(ws + off);
  unsigned short* u16b = u16f + (size_t)ROWS*DHALF;      off += (size_t)ROWS*DHALF;
  float* z_f  = ws + off; off += (size_t)ROWS*DINNER;
  float* z_b  = ws + off; off += (size_t)ROWS*DINNER;
  float* zx2_f = ws + off; off += (size_t)ROWS*XBCDT;   // xBC+dt; later overlaid by S16_f
  float* zx2_b = ws + off; off += (size_t)ROWS*XBCDT;
  unsigned short* cv16f = (unsigned short*)(ws + off); off += (size_t)ROWS*CONVDIM/2;
  unsigned short* cv16b = (unsigned short*)(ws + off); off += (size_t)ROWS*CONVDIM/2;
  float* dt_f = ws + off; off += (size_t)ROWS*NHEADS;
  float* dt_b = ws + off; off += (size_t)ROWS*NHEADS;
  float* y_f  = ws + off; off += (size_t)ROWS*DINNER;
  float* y_b  = ws + off; off += (size_t)ROWS*DINNER;
  float* acs  = ws + off; off += (size_t)64*L_SEQ;          // 131K
  float* G    = ws + off; off += (size_t)128*QCH*QCH;       // 524K
  unsigned short* hin16 = (unsigned short*)(ws + off); off += (size_t)64*NCH*8192/2;
  unsigned short* w16_fin  = (unsigned short*)(ws + off); off += (size_t)NPADIN*DHALF/2;
  unsigned short* w16_bin  = (unsigned short*)(ws + off); off += (size_t)NPADIN*DHALF/2;
  unsigned short* w16_fout = (unsigned short*)(ws + off); off += (size_t)DHALF*DINNER/2;
  unsigned short* w16_bout = (unsigned short*)(ws + off); off += (size_t)DHALF*DINNER/2;
  unsigned short* w16_op   = (unsigned short*)(ws + off); off += (size_t)DMODEL*DMODEL/2;
  // S16 (bf16) overlays zx2 (dead after conv+dtcum)
  unsigned short* S16f = (unsigned short*)zx2_f;
  unsigned short* S16b = (unsigned short*)zx2_b;
  // cat (bf16 [ROWS][1024]) overlays z_f (dead after gate_norm)
  unsigned short* cat16 = (unsigned short*)z_f;
  // bf16 gated-y overlays y_f / y_b at row stride 2048
  unsigned short* y16f = (unsigned short*)y_f;
  unsigned short* y16b = (unsigned short*)y_b;

  // 1. rmsnorm + split (bf16, backward pre-flipped)
  rmsnorm_split_kernel<<<ROWS, 256, 0, stream>>>(x, norm_w, u16f, u16b);
  // 2. weight conversions
  wconv_kernel<<<(NPADIN*DHALF+255)/256, 256, 0, stream>>>(f_in_w, w16_fin, DINPROJ, 9, NPADIN*DHALF);
  wconv_kernel<<<(NPADIN*DHALF+255)/256, 256, 0, stream>>>(b_in_w, w16_bin, DINPROJ, 9, NPADIN*DHALF);
  wconv_kernel<<<(DHALF*DINNER+255)/256, 256, 0, stream>>>(f_outp_w, w16_fout, DHALF, 10, DHALF*DINNER);
  wconv_kernel<<<(DHALF*DINNER+255)/256, 256, 0, stream>>>(b_outp_w, w16_bout, DHALF, 10, DHALF*DINNER);
  wconv_kernel<<<(DMODEL*DMODEL+255)/256, 256, 0, stream>>>(op_w, w16_op, DMODEL, 10, DMODEL*DMODEL);
  // 3-4. in-proj GEMMs, split output: z (cols<1024) and zx2 (cols>=1024)
  gemm_bf16_kernel<<<dim3(NPADIN/128, ROWS/128), 256, 0, stream>>>(
      u16f, DHALF, w16_fin, z_f, nullptr, zx2_f, DINNER, XBCDT,
      ROWS, DINPROJ, DHALF, DINNER, 0, 0, nullptr, nullptr);
  gemm_bf16_kernel<<<dim3(NPADIN/128, ROWS/128), 256, 0, stream>>>(
      u16b, DHALF, w16_bin, z_b, nullptr, zx2_b, DINNER, XBCDT,
      ROWS, DINPROJ, DHALF, DINNER, 0, 0, nullptr, nullptr);
  // 5. conv + silu -> bf16
  conv_silu_kernel<<<dim3(ROWS, 2), 256, 0, stream>>>(
      zx2_f, zx2_b, f_conv_w, f_conv_b, b_conv_w, b_conv_b, cv16f, cv16b);
  // 6. dt softplus + chunked cumsum
  dtcum_kernel<<<512, 256, 0, stream>>>(
      zx2_f, zx2_b, f_dt_bias, f_A_log, b_dt_bias, b_A_log, dt_f, dt_b, acs);
  // 7. SSD: G, intra(Y+S), chunk recurrence, inter
  gemm_g_kernel<<<dim3(32, 4), 256, 0, stream>>>(cv16f, cv16b, G);
  intra_kernel<<<dim3(32, 64), 256, 0, stream>>>(cv16f, cv16b, dt_f, dt_b, acs, G,
                                                 y_f, y_b, S16f, S16b);
  chunkscan_kernel<<<1024, 256, 0, stream>>>(S16f, S16b, acs, hin16);
  inter_kernel<<<dim3(32, 64), 256, 0, stream>>>(cv16f, cv16b, acs, hin16, f_D, b_D, y_f, y_b);
  // 8. gate + rmsnorm -> bf16 (stride 2048 overlay)
  gate_norm_kernel<<<dim3(ROWS, 2), 256, 0, stream>>>(
      y_f, y_b, z_f, z_b, f_gnorm_w, b_gnorm_w);
  // 9-10. out-proj GEMMs -> cat16 bf16 (backward time-flipped)
  gemm_bf16_kernel<<<dim3(DHALF/128, ROWS/128), 256, 0, stream>>>(
      y16f, 2048, w16_fout, nullptr, cat16, nullptr, 1<<30, 0,
      ROWS, DHALF, DINNER, DMODEL, 0, 0, nullptr, nullptr);
  gemm_bf16_kernel<<<dim3(DHALF/128, ROWS/128), 256, 0, stream>>>(
      y16b, 2048, w16_bout, nullptr, cat16, nullptr, 1<<30, 0,
      ROWS, DHALF, DINNER, DMODEL, DHALF, 1, nullptr, nullptr);
  // 11. final projection + bias + residual (fp32 out)
  gemm_bf16_kernel<<<dim3(DMODEL/128, ROWS/128), 256, 0, stream>>>(
      cat16, DMODEL, w16_op, out, nullptr, nullptr, 1<<30, 0,
      ROWS, DMODEL, DMODEL, DMODEL, 0, 0, op_b, x);
}

// Round 7
// 286.777 us; speedup vs baseline: 7.1480x; 1.0855x over previous
//
#include <hip/hip_runtime.h>
#include <math.h>

#define L_SEQ   2048
#define NBATCH  2
#define DMODEL  1024
#define DHALF   512
#define DINNER  1024
#define DSTATE  128
#define NHEADS  16
#define HEADDIM 64
#define CONVDIM 1280
#define DINPROJ 2320
#define ROWS    4096   /* NBATCH * L_SEQ */
#define NPADIN  2432   /* DINPROJ padded to multiple of 128 */

#define QCH     64               /* SSD chunk length */
#define NCH     (L_SEQ / QCH)    /* 32 chunks */

typedef __attribute__((ext_vector_type(8))) short bf16x8;
typedef __attribute__((ext_vector_type(4))) float f32x4;

union US8 { uint4 q; unsigned short s[8]; };
union US4 { uint2 q; unsigned short s[4]; };

__device__ __forceinline__ float siluf(float v){ return v / (1.f + expf(-v)); }
__device__ __forceinline__ float softplusf(float v){ return v > 20.f ? v : log1pf(expf(v)); }
__device__ __forceinline__ unsigned short f2bf(float f){
  union { float f; unsigned u; } x; x.f = f;
  unsigned r = (x.u + 0x7fffu + ((x.u >> 16) & 1u)) >> 16;
  return (unsigned short)r;
}
__device__ __forceinline__ float bf2f(unsigned short u){
  union { unsigned u; float f; } x; x.u = ((unsigned)u) << 16; return x.f;
}
__device__ __forceinline__ void gload16(const void* g, void* l){
  __builtin_amdgcn_global_load_lds((const __attribute__((address_space(1))) void*)g,
                                   (__attribute__((address_space(3))) void*)l, 16, 0, 0);
}
__device__ __forceinline__ int kx(int row){ return ((row ^ (row >> 3)) & 7) << 3; }

__device__ __forceinline__ float blockReduceSum256(float v, float* red){
  #pragma unroll
  for (int o = 32; o > 0; o >>= 1) v += __shfl_xor(v, o);
  int wid = threadIdx.x >> 6, lane = threadIdx.x & 63;
  if (lane == 0) red[wid] = v;
  __syncthreads();
  return red[0] + red[1] + red[2] + red[3];
}

// ---------------- rmsnorm + split into bf16 u_f and (pre-flipped) u_b ----------------
__global__ void rmsnorm_split_kernel(const float* __restrict__ x, const float* __restrict__ nw,
                                     unsigned short* __restrict__ uf, unsigned short* __restrict__ ub){
  __shared__ float red[4];
  int row = blockIdx.x;                       // b*L + t
  int tid = threadIdx.x;
  float4 v4 = *(const float4*)(x + (size_t)row*DMODEL + tid*4);
  float ss = v4.x*v4.x + v4.y*v4.y + v4.z*v4.z + v4.w*v4.w;
  ss = blockReduceSum256(ss, red);
  float scale = rsqrtf(ss * (1.f/DMODEL) + 1e-5f);
  int t = row & (L_SEQ-1);
  int fliprow = (row ^ t) | (L_SEQ-1-t);
  float4 w4 = *(const float4*)(nw + tid*4);
  US4 o;
  o.s[0] = f2bf(v4.x*scale*w4.x);
  o.s[1] = f2bf(v4.y*scale*w4.y);
  o.s[2] = f2bf(v4.z*scale*w4.z);
  o.s[3] = f2bf(v4.w*scale*w4.w);
  int d = tid*4;
  if (d < DHALF) *(uint2*)&uf[(size_t)row*DHALF + d] = o.q;
  else           *(uint2*)&ub[(size_t)fliprow*DHALF + (d - DHALF)] = o.q;
}

// ---------------- all weight fp32 -> bf16 (+row pad), one launch ----------------
__global__ void wconv_all_kernel(const float* __restrict__ s0, const float* __restrict__ s1,
                                 const float* __restrict__ s2, const float* __restrict__ s3,
                                 const float* __restrict__ s4,
                                 unsigned short* __restrict__ d0, unsigned short* __restrict__ d1,
                                 unsigned short* __restrict__ d2, unsigned short* __restrict__ d3,
                                 unsigned short* __restrict__ d4){
  const int S01 = NPADIN*DHALF;          // 1245184, kshift 9, rows DINPROJ
  const int S23 = DHALF*DINNER;          // 524288, kshift 10, rows DHALF (full)
  const int S4  = DMODEL*DMODEL;         // 1048576
  int idx = blockIdx.x*256 + threadIdx.x;
  if (idx < S01){
    int row = idx >> 9;
    d0[idx] = (row < DINPROJ) ? f2bf(s0[idx]) : (unsigned short)0;
    return;
  }
  idx -= S01;
  if (idx < S01){
    int row = idx >> 9;
    d1[idx] = (row < DINPROJ) ? f2bf(s1[idx]) : (unsigned short)0;
    return;
  }
  idx -= S01;
  if (idx < S23){ d2[idx] = f2bf(s2[idx]); return; }
  idx -= S23;
  if (idx < S23){ d3[idx] = f2bf(s3[idx]); return; }
  idx -= S23;
  if (idx < S4){ d4[idx] = f2bf(s4[idx]); }
}

// ---------------- bf16 MFMA GEMM with XCD swizzle + flexible epilogue ----------
// n ranges: Cf!=null -> all fp32 at ldc(+coff,flip,bias,res).
// else: n<n1 -> O0 bf16 ld0(+coff,flip); n1<=n<n2 -> O1 bf16 ld1; else O2 fp32 ld2.
__global__ __launch_bounds__(256) void gemm_bf16_kernel(
    const unsigned short* __restrict__ A, int lda,
    const unsigned short* __restrict__ W,
    float* __restrict__ Cf, int ldc, int coff, int flip,
    const float* __restrict__ bias, const float* __restrict__ res,
    unsigned short* __restrict__ O0, int ld0,
    unsigned short* __restrict__ O1, int n1, int ld1,
    float* __restrict__ O2, int n2, int ld2,
    int M, int Nreal, int K){
  __shared__ unsigned short As[128*32];
  __shared__ unsigned short Bs[128*32];
  // XCD-aware swizzle: contiguous logical chunk per XCD
  int bid = blockIdx.y*gridDim.x + blockIdx.x;
  int nwg = gridDim.x*gridDim.y;
  int bx = blockIdx.x, by = blockIdx.y;
  if ((nwg & 7) == 0){
    int cpx = nwg >> 3;
    int s = (bid & 7)*cpx + (bid >> 3);
    bx = s % gridDim.x; by = s / gridDim.x;
  }
  int bm = by*128, bn = bx*128;
  int tid = threadIdx.x;
  int lane = tid & 63;
  int wave = tid >> 6;
  int wm = (wave >> 1) * 64, wn = (wave & 1) * 64;
  int l15 = lane & 15, lhi = lane >> 4;    // lhi 0..3
  f32x4 acc[4][4];
  #pragma unroll
  for (int i = 0; i < 4; i++)
    #pragma unroll
    for (int j = 0; j < 4; j++)
      acc[i][j] = (f32x4){0.f,0.f,0.f,0.f};

  for (int k0 = 0; k0 < K; k0 += 32){
    #pragma unroll
    for (int j = 0; j < 2; j++){
      int f = j*256 + tid;                 // 0..511 16B-chunks (128 rows x 4 chunks)
      int row = f >> 2, c8 = (f & 3) * 8;
      gload16(A + (size_t)(bm+row)*lda + k0 + c8, &As[f*8]);
      gload16(W + (size_t)(bn+row)*K   + k0 + c8, &Bs[f*8]);
    }
    __syncthreads();
    bf16x8 af[4], bfr[4];
    #pragma unroll
    for (int i = 0; i < 4; i++){
      af[i]  = *(const bf16x8*)&As[(wm + i*16 + l15)*32 + lhi*8];
      bfr[i] = *(const bf16x8*)&Bs[(wn + i*16 + l15)*32 + lhi*8];
    }
    #pragma unroll
    for (int i = 0; i < 4; i++)
      #pragma unroll
      for (int j = 0; j < 4; j++)
        acc[i][j] = __builtin_amdgcn_mfma_f32_16x16x32_bf16(af[i], bfr[j], acc[i][j], 0, 0, 0);
    __syncthreads();
  }
  #pragma unroll
  for (int i = 0; i < 4; i++){
    #pragma unroll
    for (int r = 0; r < 4; r++){
      int m = bm + wm + i*16 + lhi*4 + r;
      int mo = m;
      if (flip){ int t = m & (L_SEQ-1); mo = (m ^ t) | (L_SEQ-1-t); }
      #pragma unroll
      for (int j = 0; j < 4; j++){
        int n = bn + wn + j*16 + l15;
        if (n < Nreal){
          float v = acc[i][j][r];
          if (bias) v += bias[n];
          if (res)  v += res[(size_t)mo*ldc + coff + n];
          if (Cf)            Cf[(size_t)mo*ldc + coff + n] = v;
          else if (n < n1)   O0[(size_t)mo*ld0 + coff + n] = f2bf(v);
          else if (n < n2)   O1[(size_t)mo*ld1 + (n - n1)] = f2bf(v);
          else               O2[(size_t)mo*ld2 + (n - n2)] = v;
        }
      }
    }
  }
}

// ---------------- causal depthwise conv (k=4) + silu, bf16 in/out ----------------
__global__ void conv_silu_kernel(const unsigned short* __restrict__ xbcf, const unsigned short* __restrict__ xbcb,
                                 const float* __restrict__ cwf, const float* __restrict__ cbf,
                                 const float* __restrict__ cwb, const float* __restrict__ cbb,
                                 unsigned short* __restrict__ cvf, unsigned short* __restrict__ cvb){
  int row = blockIdx.x; int dir = blockIdx.y;
  int tid = threadIdx.x;
  if (tid >= 160) return;
  const unsigned short* xbc = dir ? xbcb : xbcf;
  const float* cw = dir ? cwb : cwf;
  const float* cb = dir ? cbb : cbf;
  unsigned short* cv = dir ? cvb : cvf;
  int t = row & (L_SEQ-1);
  int c0 = tid*8;
  const unsigned short* base = xbc + (size_t)row*CONVDIM + c0;
  US8 u3, u2, u1, u0;
  u3.q = *(const uint4*)base;
  u2.q = (t >= 1) ? *(const uint4*)(base - CONVDIM)   : (uint4){0,0,0,0};
  u1.q = (t >= 2) ? *(const uint4*)(base - 2*CONVDIM) : (uint4){0,0,0,0};
  u0.q = (t >= 3) ? *(const uint4*)(base - 3*CONVDIM) : (uint4){0,0,0,0};
  US8 o;
  #pragma unroll
  for (int j = 0; j < 8; j++){
    float4 w = *(const float4*)&cw[(c0+j)*4];
    float v = cb[c0+j];
    v += bf2f(u3.s[j])*w.w + bf2f(u2.s[j])*w.z + bf2f(u1.s[j])*w.y + bf2f(u0.s[j])*w.x;
    o.s[j] = f2bf(siluf(v));
  }
  *(uint4*)&cv[(size_t)row*CONVDIM + c0] = o.q;
}

// ---------------- dt softplus + per-chunk inclusive cumsum of dt*A ----------------
__global__ void dtcum_kernel(const float* __restrict__ drf, const float* __restrict__ drb,
                             const float* __restrict__ dbf, const float* __restrict__ alf,
                             const float* __restrict__ dbb, const float* __restrict__ alb,
                             float* __restrict__ dtf, float* __restrict__ dtb,
                             float* __restrict__ acs){
  int tid = threadIdx.x;
  int wid = blockIdx.x*4 + (tid >> 6);      // 0..2047 = dbh*32 + c
  int tau = tid & 63;
  int c = wid & 31, dbh = wid >> 5;
  int h = dbh & 15, b = (dbh >> 4) & 1, dir = dbh >> 5;
  const float* dr = dir ? drb : drf;
  size_t row = (size_t)b*L_SEQ + c*QCH + tau;
  float raw = dr[row*NHEADS + h];
  float bias = (dir ? dbb : dbf)[h];
  float dtv = softplusf(raw + bias);
  float a = -expf((dir ? alb : alf)[h]);
  (dir ? dtb : dtf)[row*NHEADS + h] = dtv;
  float v = dtv * a;
  #pragma unroll
  for (int off = 1; off < 64; off <<= 1){
    float u = __shfl_up(v, off);
    if (tau >= off) v += u;
  }
  acs[(size_t)dbh*L_SEQ + c*QCH + tau] = v;
}

// ---------------- K_G (MFMA): G[t][s] = C[t]·B[s], per (dir,b,chunk) ----------------
__global__ __launch_bounds__(256) void gemm_g_kernel(
    const unsigned short* __restrict__ cvf, const unsigned short* __restrict__ cvb,
    float* __restrict__ G){
  int c = blockIdx.x, db = blockIdx.y;
  int b = db & 1, dir = db >> 1;
  const unsigned short* cv = dir ? cvb : cvf;
  float* Gp = G + ((size_t)(db*32 + c))*4096;
  int tid = threadIdx.x, lane = tid & 63, w = tid >> 6;
  int l15 = lane & 15, lhi = lane >> 4;
  __shared__ unsigned short sB[64*128];
  __shared__ unsigned short sC[64*128];
  size_t r0 = (size_t)b*L_SEQ + (size_t)c*QCH;
  #pragma unroll
  for (int k = 0; k < 4; k++){
    int cid = k*256 + tid;
    int row = cid >> 4, slot = cid & 15;
    US8 ub, uc;
    ub.q = *(const uint4*)&cv[(r0+row)*CONVDIM + DINNER + slot*8];
    uc.q = *(const uint4*)&cv[(r0+row)*CONVDIM + DINNER + DSTATE + slot*8];
    *(uint4*)&sB[row*128 + (slot*8 ^ kx(row))] = ub.q;
    *(uint4*)&sC[row*128 + (slot*8 ^ kx(row))] = uc.q;
  }
  __syncthreads();
  int t0 = w*16;
  bf16x8 af[4];
  #pragma unroll
  for (int ks = 0; ks < 4; ks++){
    int r = t0 + l15;
    af[ks] = *(const bf16x8*)&sC[r*128 + ((ks*32 + lhi*8) ^ kx(r))];
  }
  f32x4 acc[4];
  #pragma unroll
  for (int j = 0; j < 4; j++) acc[j] = (f32x4){0.f,0.f,0.f,0.f};
  #pragma unroll
  for (int j = 0; j < 4; j++){
    #pragma unroll
    for (int ks = 0; ks < 4; ks++){
      int r = j*16 + l15;
      bf16x8 wf = *(const bf16x8*)&sB[r*128 + ((ks*32 + lhi*8) ^ kx(r))];
      acc[j] = __builtin_amdgcn_mfma_f32_16x16x32_bf16(af[ks], wf, acc[j], 0, 0, 0);
    }
  }
  #pragma unroll
  for (int j = 0; j < 4; j++)
    #pragma unroll
    for (int r = 0; r < 4; r++)
      Gp[(t0 + lhi*4 + r)*64 + j*16 + l15] = acc[j][r];
}

// ---------------- K_Y (MFMA): intra-chunk Y + chunk-state S^T, per (dir,b,h,chunk) ----
__global__ __launch_bounds__(256) void intra_kernel(
    const unsigned short* __restrict__ cvf, const unsigned short* __restrict__ cvb,
    const float* __restrict__ dtf, const float* __restrict__ dtb,
    const float* __restrict__ acs, const float* __restrict__ G,
    float* __restrict__ yf, float* __restrict__ yb,
    unsigned short* __restrict__ S16f, unsigned short* __restrict__ S16b){
  int c = blockIdx.x, dbh = blockIdx.y;
  int h = dbh & 15, b = (dbh >> 4) & 1, dir = dbh >> 5;
  const unsigned short* cv = dir ? cvb : cvf;
  const float* dtp = dir ? dtb : dtf;
  float* y = dir ? yb : yf;
  unsigned short* S16 = dir ? S16b : S16f;
  const float* Gp = G + ((size_t)((dir*2+b)*32 + c))*4096;
  int tid = threadIdx.x, lane = tid & 63, w = tid >> 6;
  int l15 = lane & 15, lhi = lane >> 4;

  __shared__ unsigned short sGh [64*64];   // Gh[t][s]  (A for Y)
  __shared__ unsigned short sDxT[64*64];   // dxT[p][s] (W for Y, A for S^T)
  __shared__ unsigned short sBwT[128*64];  // BwT[n][s] (W for S^T)
  __shared__ float a_sh[QCH], dt_sh[QCH];

  size_t r0 = (size_t)b*L_SEQ + (size_t)c*QCH;
  if (tid < 64){
    a_sh[tid]  = acs[(size_t)dbh*L_SEQ + c*QCH + tid];
    dt_sh[tid] = dtp[(r0 + tid)*NHEADS + h];
  }
  __syncthreads();
  float a63 = a_sh[63];
  // dxT[p][s] = dt[s]*x[s][p], transposed scalar writes (swizzled)
  #pragma unroll
  for (int k = 0; k < 2; k++){
    int cid = k*256 + tid;
    int s = cid >> 3, p0 = (cid & 7)*8;
    US8 u; u.q = *(const uint4*)&cv[(r0+s)*CONVDIM + h*HEADDIM + p0];
    float d = dt_sh[s];
    #pragma unroll
    for (int j = 0; j < 8; j++){
      int p = p0 + j;
      sDxT[p*64 + (s ^ kx(p))] = f2bf(bf2f(u.s[j]) * d);
    }
  }
  // BwT[n][s] = exp(a63-a[s])*B[s][n]
  #pragma unroll
  for (int k = 0; k < 4; k++){
    int cid = k*256 + tid;
    int s = cid >> 4, n0 = (cid & 15)*8;
    US8 u; u.q = *(const uint4*)&cv[(r0+s)*CONVDIM + DINNER + n0];
    float wv = expf(a63 - a_sh[s]);
    #pragma unroll
    for (int j = 0; j < 8; j++){
      int n = n0 + j;
      sBwT[n*64 + (s ^ kx(n))] = f2bf(bf2f(u.s[j]) * wv);
    }
  }
  // Gh[t][s] = (s<=t) ? G[t][s]*exp(a[t]-a[s]) : 0, bf16
  #pragma unroll
  for (int k = 0; k < 4; k++){
    int f = k*256 + tid;
    int t = f >> 4, s0 = (f & 15)*4;
    float4 g = *(const float4*)&Gp[t*64 + s0];
    float at = a_sh[t];
    float v0 = (s0+0 <= t) ? g.x*expf(at - a_sh[s0+0]) : 0.f;
    float v1 = (s0+1 <= t) ? g.y*expf(at - a_sh[s0+1]) : 0.f;
    float v2 = (s0+2 <= t) ? g.z*expf(at - a_sh[s0+2]) : 0.f;
    float v3 = (s0+3 <= t) ? g.w*expf(at - a_sh[s0+3]) : 0.f;
    int addr = t*64 + (s0 ^ kx(t));
    *(unsigned*)&sGh[addr]     = (unsigned)f2bf(v0) | ((unsigned)f2bf(v1) << 16);
    *(unsigned*)&sGh[addr + 2] = (unsigned)f2bf(v2) | ((unsigned)f2bf(v3) << 16);
  }
  __syncthreads();

  int t0 = w*16;                     // Y t-tile; also S^T p-tile
  bf16x8 aY[2], aS[2];
  #pragma unroll
  for (int ks = 0; ks < 2; ks++){
    int rg = t0 + l15;
    aY[ks] = *(const bf16x8*)&sGh [rg*64 + ((ks*32 + lhi*8) ^ kx(rg))];
    aS[ks] = *(const bf16x8*)&sDxT[rg*64 + ((ks*32 + lhi*8) ^ kx(rg))];
  }
  // Y[t][p] = sum_s Gh[t][s] * dxT[p][s]
  f32x4 accY[4];
  #pragma unroll
  for (int j = 0; j < 4; j++) accY[j] = (f32x4){0.f,0.f,0.f,0.f};
  #pragma unroll
  for (int j = 0; j < 4; j++){
    #pragma unroll
    for (int ks = 0; ks < 2; ks++){
      int rp = j*16 + l15;
      bf16x8 wf = *(const bf16x8*)&sDxT[rp*64 + ((ks*32 + lhi*8) ^ kx(rp))];
      accY[j] = __builtin_amdgcn_mfma_f32_16x16x32_bf16(aY[ks], wf, accY[j], 0, 0, 0);
    }
  }
  // S^T[p][n] = sum_s dxT[p][s] * BwT[n][s]
  f32x4 accS[8];
  #pragma unroll
  for (int j = 0; j < 8; j++) accS[j] = (f32x4){0.f,0.f,0.f,0.f};
  #pragma unroll
  for (int j = 0; j < 8; j++){
    #pragma unroll
    for (int ks = 0; ks < 2; ks++){
      int rn = j*16 + l15;
      bf16x8 wf = *(const bf16x8*)&sBwT[rn*64 + ((ks*32 + lhi*8) ^ kx(rn))];
      accS[j] = __builtin_amdgcn_mfma_f32_16x16x32_bf16(aS[ks], wf, accS[j], 0, 0, 0);
    }
  }
  // epilogues
  #pragma unroll
  for (int j = 0; j < 4; j++){
    #pragma unroll
    for (int r = 0; r < 4; r++){
      int t = t0 + lhi*4 + r, p = j*16 + l15;
      y[(r0 + t)*DINNER + h*HEADDIM + p] = accY[j][r];
    }
  }
  size_t sbase = ((size_t)((b*NHEADS + h)*NCH + c))*8192;
  #pragma unroll
  for (int j = 0; j < 8; j++){
    #pragma unroll
    for (int r = 0; r < 4; r++){
      int p = t0 + lhi*4 + r, n = j*16 + l15;
      S16[sbase + p*128 + n] = f2bf(accS[j][r]);
    }
  }
}

// ---------------- K_S: inter-chunk state recurrence (elementwise over [p][n]) --------
__global__ void chunkscan_kernel(const unsigned short* __restrict__ S16f,
                                 const unsigned short* __restrict__ S16b,
                                 const float* __restrict__ acs,
                                 unsigned short* __restrict__ hin16){
  __shared__ float sa[NCH];
  int tid = threadIdx.x;
  int dbh = blockIdx.x >> 4;
  int e0 = ((blockIdx.x & 15)*256 + tid)*2;
  int bh = dbh & 31, dir = dbh >> 5;
  const unsigned short* S16 = dir ? S16b : S16f;
  if (tid < NCH) sa[tid] = expf(acs[(size_t)dbh*L_SEQ + tid*QCH + 63]);
  __syncthreads();
  float h0 = 0.f, h1 = 0.f;
  #pragma unroll 8
  for (int c = 0; c < NCH; ++c){
    size_t sidx = ((size_t)(bh*NCH + c))*8192 + e0;
    size_t hidx = ((size_t)(dbh*NCH + c))*8192 + e0;
    unsigned sv = *(const unsigned*)&S16[sidx];
    unsigned hv = (unsigned)f2bf(h0) | ((unsigned)f2bf(h1) << 16);
    *(unsigned*)&hin16[hidx] = hv;
    float ea = sa[c];
    h0 = ea*h0 + bf2f((unsigned short)(sv & 0xffff));
    h1 = ea*h1 + bf2f((unsigned short)(sv >> 16));
  }
}

// ---------------- K_I (MFMA): Y = y_intra + e[t]*C·h_in + D*x -> bf16 yg -------------
__global__ __launch_bounds__(256) void inter_kernel(
    const unsigned short* __restrict__ cvf, const unsigned short* __restrict__ cvb,
    const float* __restrict__ acs, const unsigned short* __restrict__ hin16,
    const float* __restrict__ Df, const float* __restrict__ Db,
    const float* __restrict__ yf, const float* __restrict__ yb,
    unsigned short* __restrict__ ygf, unsigned short* __restrict__ ygb){
  int c = blockIdx.x, dbh = blockIdx.y;
  int h = dbh & 15, b = (dbh >> 4) & 1, dir = dbh >> 5;
  const unsigned short* cv = dir ? cvb : cvf;
  const float* y = dir ? yb : yf;
  unsigned short* yg = dir ? ygb : ygf;
  float Dh = (dir ? Db : Df)[h];
  int tid = threadIdx.x, lane = tid & 63, w = tid >> 6;
  int l15 = lane & 15, lhi = lane >> 4;
  __shared__ unsigned short sC [64*128];   // C[t][n]  (A)
  __shared__ unsigned short sHT[64*128];   // hT[p][n] (W)
  __shared__ float e_sh[QCH];
  size_t r0 = (size_t)b*L_SEQ + (size_t)c*QCH;
  size_t hbase = ((size_t)(dbh*NCH + c))*8192;
  if (tid < 64) e_sh[tid] = expf(acs[(size_t)dbh*L_SEQ + c*QCH + tid]);
  #pragma unroll
  for (int k = 0; k < 4; k++){
    int cid = k*256 + tid;
    int row = cid >> 4, slot = cid & 15;
    US8 uc, uh;
    uc.q = *(const uint4*)&cv[(r0+row)*CONVDIM + DINNER + DSTATE + slot*8];
    uh.q = *(const uint4*)&hin16[hbase + cid*8];
    *(uint4*)&sC [row*128 + (slot*8 ^ kx(row))] = uc.q;
    *(uint4*)&sHT[row*128 + (slot*8 ^ kx(row))] = uh.q;
  }
  __syncthreads();
  int t0 = w*16;
  bf16x8 af[4];
  #pragma unroll
  for (int ks = 0; ks < 4; ks++){
    int r = t0 + l15;
    af[ks] = *(const bf16x8*)&sC[r*128 + ((ks*32 + lhi*8) ^ kx(r))];
  }
  f32x4 acc[4];
  #pragma unroll
  for (int j = 0; j < 4; j++) acc[j] = (f32x4){0.f,0.f,0.f,0.f};
  #pragma unroll
  for (int j = 0; j < 4; j++){
    #pragma unroll
    for (int ks = 0; ks < 4; ks++){
      int r = j*16 + l15;
      bf16x8 wf = *(const bf16x8*)&sHT[r*128 + ((ks*32 + lhi*8) ^ kx(r))];
      acc[j] = __builtin_amdgcn_mfma_f32_16x16x32_bf16(af[ks], wf, acc[j], 0, 0, 0);
    }
  }
  #pragma unroll
  for (int j = 0; j < 4; j++){
    #pragma unroll
    for (int r = 0; r < 4; r++){
      int t = t0 + lhi*4 + r, p = j*16 + l15;
      size_t row = r0 + t;
      float xv = bf2f(cv[row*CONVDIM + h*HEADDIM + p]);
      float v = y[row*DINNER + h*HEADDIM + p] + e_sh[t]*acc[j][r] + Dh*xv;
      yg[row*DINNER + h*HEADDIM + p] = f2bf(v);
    }
  }
}

// ---------------- gate (silu(z)) + rmsnorm, all bf16, in place on yg ----------------
__global__ void gate_norm_kernel(unsigned short* __restrict__ ygf, unsigned short* __restrict__ ygb,
                                 const unsigned short* __restrict__ z16f, const unsigned short* __restrict__ z16b,
                                 const float* __restrict__ gwf, const float* __restrict__ gwb){
  __shared__ float red[4];
  int row = blockIdx.x; int dir = blockIdx.y;
  int tid = threadIdx.x;
  unsigned short* yg = (dir ? ygb : ygf) + (size_t)row*DINNER;
  const unsigned short* z = (dir ? z16b : z16f) + (size_t)row*DINNER;
  const float* gw = dir ? gwb : gwf;
  int d = tid*4;
  US4 uy, uz;
  uy.q = *(const uint2*)&yg[d];
  uz.q = *(const uint2*)&z[d];
  float v[4]; float ss = 0.f;
  #pragma unroll
  for (int k = 0; k < 4; k++){
    float val = bf2f(uy.s[k]) * siluf(bf2f(uz.s[k]));
    v[k] = val; ss += val*val;
  }
  ss = blockReduceSum256(ss, red);   // __syncthreads inside: reads precede writes
  float scale = rsqrtf(ss*(1.f/DINNER) + 1e-5f);
  float4 w4 = *(const float4*)&gw[d];
  US4 o;
  o.s[0] = f2bf(v[0]*scale*w4.x);
  o.s[1] = f2bf(v[1]*scale*w4.y);
  o.s[2] = f2bf(v[2]*scale*w4.z);
  o.s[3] = f2bf(v[3]*scale*w4.w);
  *(uint2*)&yg[d] = o.q;
}

extern "C" void kernel_launch(void* const* d_in, const int* in_sizes, int n_in,
                              void* d_out, int out_size, void* d_ws, size_t ws_size,
                              hipStream_t stream) {
  const float* x      = (const float*)d_in[0];
  const float* norm_w = (const float*)d_in[1];
  const float* op_w   = (const float*)d_in[2];
  const float* op_b   = (const float*)d_in[3];
  const float* f_in_w    = (const float*)d_in[4];
  const float* f_conv_w  = (const float*)d_in[5];
  const float* f_conv_b  = (const float*)d_in[6];
  const float* f_dt_bias = (const float*)d_in[7];
  const float* f_A_log   = (const float*)d_in[8];
  const float* f_D       = (const float*)d_in[9];
  const float* f_gnorm_w = (const float*)d_in[10];
  const float* f_outp_w  = (const float*)d_in[11];
  const float* b_in_w    = (const float*)d_in[12];
  const float* b_conv_w  = (const float*)d_in[13];
  const float* b_conv_b  = (const float*)d_in[14];
  const float* b_dt_bias = (const float*)d_in[15];
  const float* b_A_log   = (const float*)d_in[16];
  const float* b_D       = (const float*)d_in[17];
  const float* b_gnorm_w = (const float*)d_in[18];
  const float* b_outp_w  = (const float*)d_in[19];
  float* out = (float*)d_out;

  float* ws = (float*)d_ws;
  size_t off = 0;
  unsigned short* u16f = (unsigned short*)(ws + off);
  unsigned short* u16b = u16f + (size_t)ROWS*DHALF;      off += (size_t)ROWS*DHALF;
  unsigned short* z16f = (unsigned short*)(ws + off);    off += (size_t)ROWS*DINNER/2;
  unsigned short* z16b = (unsigned short*)(ws + off);    off += (size_t)ROWS*DINNER/2;
  unsigned short* xbc16f = (unsigned short*)(ws + off);  off += (size_t)ROWS*CONVDIM/2;
  unsigned short* xbc16b = (unsigned short*)(ws + off);  off += (size_t)ROWS*CONVDIM/2;
  float* draw_f = ws + off; off += (size_t)ROWS*NHEADS;
  float* draw_b = ws + off; off += (size_t)ROWS*NHEADS;
  unsigned short* cv16f = (unsigned short*)(ws + off); off += (size_t)ROWS*CONVDIM/2;
  unsigned short* cv16b = (unsigned short*)(ws + off); off += (size_t)ROWS*CONVDIM/2;
  float* dt_f = ws + off; off += (size_t)ROWS*NHEADS;
  float* dt_b = ws + off; off += (size_t)ROWS*NHEADS;
  float* y_f  = ws + off; off += (size_t)ROWS*DINNER;
  float* y_b  = ws + off; off += (size_t)ROWS*DINNER;
  unsigned short* yg16f = (unsigned short*)(ws + off); off += (size_t)ROWS*DINNER/2;
  unsigned short* yg16b = (unsigned short*)(ws + off); off += (size_t)ROWS*DINNER/2;
  float* acs  = ws + off; off += (size_t)64*L_SEQ;
  float* G    = ws + off; off += (size_t)128*QCH*QCH;
  unsigned short* S16f = (unsigned short*)(ws + off); off += (size_t)32*NCH*8192/2;
  unsigned short* S16b = (unsigned short*)(ws + off); off += (size_t)32*NCH*8192/2;
  unsigned short* hin16 = (unsigned short*)(ws + off); off += (size_t)64*NCH*8192/2;
  unsigned short* w16_fin  = (unsigned short*)(ws + off); off += (size_t)NPADIN*DHALF/2;
  unsigned short* w16_bin  = (unsigned short*)(ws + off); off += (size_t)NPADIN*DHALF/2;
  unsigned short* w16_fout = (unsigned short*)(ws + off); off += (size_t)DHALF*DINNER/2;
  unsigned short* w16_bout = (unsigned short*)(ws + off); off += (size_t)DHALF*DINNER/2;
  unsigned short* w16_op   = (unsigned short*)(ws + off); off += (size_t)DMODEL*DMODEL/2;
  // cat (bf16 [ROWS][1024]) overlays z16f+z16b region (dead after gate_norm)
  unsigned short* cat16 = z16f;

  // 1. rmsnorm + split (bf16, backward pre-flipped)
  rmsnorm_split_kernel<<<ROWS, 256, 0, stream>>>(x, norm_w, u16f, u16b);
  // 2. weight conversions (single launch)
  {
    const int TOT = 2*NPADIN*DHALF + 2*DHALF*DINNER + DMODEL*DMODEL;
    wconv_all_kernel<<<(TOT+255)/256, 256, 0, stream>>>(
        f_in_w, b_in_w, f_outp_w, b_outp_w, op_w,
        w16_fin, w16_bin, w16_fout, w16_bout, w16_op);
  }
  // 3-4. in-proj GEMMs, 3-way split: z16 bf16 | xbc16 bf16 | draw fp32
  gemm_bf16_kernel<<<dim3(NPADIN/128, ROWS/128), 256, 0, stream>>>(
      u16f, DHALF, w16_fin, nullptr, 0, 0, 0, nullptr, nullptr,
      z16f, DINNER, xbc16f, DINNER, CONVDIM, draw_f, DINNER+CONVDIM, NHEADS,
      ROWS, DINPROJ, DHALF);
  gemm_bf16_kernel<<<dim3(NPADIN/128, ROWS/128), 256, 0, stream>>>(
      u16b, DHALF, w16_bin, nullptr, 0, 0, 0, nullptr, nullptr,
      z16b, DINNER, xbc16b, DINNER, CONVDIM, draw_b, DINNER+CONVDIM, NHEADS,
      ROWS, DINPROJ, DHALF);
  // 5. conv + silu (bf16 in/out)
  conv_silu_kernel<<<dim3(ROWS, 2), 256, 0, stream>>>(
      xbc16f, xbc16b, f_conv_w, f_conv_b, b_conv_w, b_conv_b, cv16f, cv16b);
  // 6. dt softplus + chunked cumsum
  dtcum_kernel<<<512, 256, 0, stream>>>(
      draw_f, draw_b, f_dt_bias, f_A_log, b_dt_bias, b_A_log, dt_f, dt_b, acs);
  // 7. SSD: G, intra(Y+S), chunk recurrence, inter (-> bf16 yg)
  gemm_g_kernel<<<dim3(32, 4), 256, 0, stream>>>(cv16f, cv16b, G);
  intra_kernel<<<dim3(32, 64), 256, 0, stream>>>(cv16f, cv16b, dt_f, dt_b, acs, G,
                                                 y_f, y_b, S16f, S16b);
  chunkscan_kernel<<<1024, 256, 0, stream>>>(S16f, S16b, acs, hin16);
  inter_kernel<<<dim3(32, 64), 256, 0, stream>>>(cv16f, cv16b, acs, hin16, f_D, b_D,
                                                 y_f, y_b, yg16f, yg16b);
  // 8. gate + rmsnorm (all bf16, in place on yg)
  gate_norm_kernel<<<dim3(ROWS, 2), 256, 0, stream>>>(
      yg16f, yg16b, z16f, z16b, f_gnorm_w, b_gnorm_w);
  // 9-10. out-proj GEMMs -> cat16 bf16 (backward time-flipped)
  gemm_bf16_kernel<<<dim3(DHALF/128, ROWS/128), 256, 0, stream>>>(
      yg16f, DINNER, w16_fout, nullptr, 0, 0, 0, nullptr, nullptr,
      cat16, DMODEL, nullptr, 1<<30, 0, nullptr, 1<<30, 0,
      ROWS, DHALF, DINNER);
  gemm_bf16_kernel<<<dim3(DHALF/128, ROWS/128), 256, 0, stream>>>(
      yg16b, DINNER, w16_bout, nullptr, 0, DHALF, 1, nullptr, nullptr,
      cat16, DMODEL, nullptr, 1<<30, 0, nullptr, 1<<30, 0,
      ROWS, DHALF, DINNER);
  // 11. final projection + bias + residual (fp32 out)
  gemm_bf16_kernel<<<dim3(DMODEL/128, ROWS/128), 256, 0, stream>>>(
      cat16, DMODEL, w16_op, out, DMODEL, 0, 0, op_b, x,
      nullptr, 0, nullptr, 1<<30, 0, nullptr, 1<<30, 0,
      ROWS, DMODEL, DMODEL);
}

// Round 8
// 240.944 us; speedup vs baseline: 8.5078x; 1.1902x over previous
//
#include <hip/hip_runtime.h>
#include <math.h>

#define L_SEQ   2048
#define NBATCH  2
#define DMODEL  1024
#define DHALF   512
#define DINNER  1024
#define DSTATE  128
#define NHEADS  16
#define HEADDIM 64
#define CONVDIM 1280
#define DINPROJ 2320
#define ROWS    4096   /* NBATCH * L_SEQ */
#define NPADIN  2432   /* DINPROJ padded to multiple of 128 */

#define QCH     64               /* SSD chunk length */
#define NCH     (L_SEQ / QCH)    /* 32 chunks */

typedef __attribute__((ext_vector_type(8))) short bf16x8;
typedef __attribute__((ext_vector_type(4))) float f32x4;

union US8 { uint4 q; unsigned short s[8]; };
union US4 { uint2 q; unsigned short s[4]; };

__device__ __forceinline__ float siluf(float v){ return v / (1.f + expf(-v)); }
__device__ __forceinline__ float softplusf(float v){ return v > 20.f ? v : log1pf(expf(v)); }
__device__ __forceinline__ unsigned short f2bf(float f){
  union { float f; unsigned u; } x; x.f = f;
  unsigned r = (x.u + 0x7fffu + ((x.u >> 16) & 1u)) >> 16;
  return (unsigned short)r;
}
__device__ __forceinline__ float bf2f(unsigned short u){
  union { unsigned u; float f; } x; x.u = ((unsigned)u) << 16; return x.f;
}
__device__ __forceinline__ void gload16(const void* g, void* l){
  __builtin_amdgcn_global_load_lds((const __attribute__((address_space(1))) void*)g,
                                   (__attribute__((address_space(3))) void*)l, 16, 0, 0);
}
__device__ __forceinline__ int kx(int row){ return ((row ^ (row >> 3)) & 7) << 3; }

__device__ __forceinline__ float blockReduceSum256(float v, float* red){
  #pragma unroll
  for (int o = 32; o > 0; o >>= 1) v += __shfl_xor(v, o);
  int wid = threadIdx.x >> 6, lane = threadIdx.x & 63;
  if (lane == 0) red[wid] = v;
  __syncthreads();
  return red[0] + red[1] + red[2] + red[3];
}

// ---------------- rmsnorm + split into bf16 u_f and (pre-flipped) u_b ----------------
__global__ void rmsnorm_split_kernel(const float* __restrict__ x, const float* __restrict__ nw,
                                     unsigned short* __restrict__ uf, unsigned short* __restrict__ ub){
  __shared__ float red[4];
  int row = blockIdx.x;                       // b*L + t
  int tid = threadIdx.x;
  float4 v4 = *(const float4*)(x + (size_t)row*DMODEL + tid*4);
  float ss = v4.x*v4.x + v4.y*v4.y + v4.z*v4.z + v4.w*v4.w;
  ss = blockReduceSum256(ss, red);
  float scale = rsqrtf(ss * (1.f/DMODEL) + 1e-5f);
  int t = row & (L_SEQ-1);
  int fliprow = (row ^ t) | (L_SEQ-1-t);
  float4 w4 = *(const float4*)(nw + tid*4);
  US4 o;
  o.s[0] = f2bf(v4.x*scale*w4.x);
  o.s[1] = f2bf(v4.y*scale*w4.y);
  o.s[2] = f2bf(v4.z*scale*w4.z);
  o.s[3] = f2bf(v4.w*scale*w4.w);
  int d = tid*4;
  if (d < DHALF) *(uint2*)&uf[(size_t)row*DHALF + d] = o.q;
  else           *(uint2*)&ub[(size_t)fliprow*DHALF + (d - DHALF)] = o.q;
}

// ---------------- all weight fp32 -> bf16 (+row pad), one launch ----------------
__global__ void wconv_all_kernel(const float* __restrict__ s0, const float* __restrict__ s1,
                                 const float* __restrict__ s2, const float* __restrict__ s3,
                                 const float* __restrict__ s4,
                                 unsigned short* __restrict__ d0, unsigned short* __restrict__ d1,
                                 unsigned short* __restrict__ d2, unsigned short* __restrict__ d3,
                                 unsigned short* __restrict__ d4){
  const int S01 = NPADIN*DHALF;          // kshift 9, rows DINPROJ
  const int S23 = DHALF*DINNER;
  const int S4  = DMODEL*DMODEL;
  int idx = blockIdx.x*256 + threadIdx.x;
  if (idx < S01){
    int row = idx >> 9;
    d0[idx] = (row < DINPROJ) ? f2bf(s0[idx]) : (unsigned short)0;
    return;
  }
  idx -= S01;
  if (idx < S01){
    int row = idx >> 9;
    d1[idx] = (row < DINPROJ) ? f2bf(s1[idx]) : (unsigned short)0;
    return;
  }
  idx -= S01;
  if (idx < S23){ d2[idx] = f2bf(s2[idx]); return; }
  idx -= S23;
  if (idx < S23){ d3[idx] = f2bf(s3[idx]); return; }
  idx -= S23;
  if (idx < S4){ d4[idx] = f2bf(s4[idx]); }
}

// ---------------- bf16 MFMA GEMM: dual-direction (blockIdx.z), 2-phase pipelined ------
// dir d: A = (d?A1:A0), W = (d?W1:W0), outputs per-dir. coff/flip apply to dir1 only
// (dir0 uses coff=0,flip=0 unless Cf path). Epilogue ranges:
//   Cf != null -> all fp32 at ldc (+bias/res).
//   else n<n1 -> O0 bf16 ld0 (+coff,flip); n1<=n<n2 -> O1 bf16 ld1; else O2 fp32 ld2.
__global__ __launch_bounds__(256) void gemm_bf16_kernel(
    const unsigned short* __restrict__ A0, const unsigned short* __restrict__ A1, int lda,
    const unsigned short* __restrict__ W0, const unsigned short* __restrict__ W1,
    float* __restrict__ Cf, int ldc,
    const float* __restrict__ bias, const float* __restrict__ res,
    unsigned short* __restrict__ O0a, unsigned short* __restrict__ O0b, int ld0,
    unsigned short* __restrict__ O1a, unsigned short* __restrict__ O1b, int n1, int ld1,
    float* __restrict__ O2a, float* __restrict__ O2b, int n2, int ld2,
    int coff1, int flip1,
    int M, int Nreal, int K){
  __shared__ unsigned short As[2][128*32];
  __shared__ unsigned short Bs[2][128*32];
  // XCD-aware swizzle over flattened (z,y,x) grid
  int bid = (blockIdx.z*gridDim.y + blockIdx.y)*gridDim.x + blockIdx.x;
  int nwg = gridDim.x*gridDim.y*gridDim.z;
  int s = bid;
  if ((nwg & 7) == 0){
    int cpx = nwg >> 3;
    s = (bid & 7)*cpx + (bid >> 3);
  }
  int bx = s % gridDim.x;
  int tmp = s / gridDim.x;
  int by = tmp % gridDim.y;
  int dir = tmp / gridDim.y;

  const unsigned short* A = dir ? A1 : A0;
  const unsigned short* W = dir ? W1 : W0;
  unsigned short* O0 = dir ? O0b : O0a;
  unsigned short* O1 = dir ? O1b : O1a;
  float* O2 = dir ? O2b : O2a;
  int coff = dir ? coff1 : 0;
  int flip = dir ? flip1 : 0;

  int bm = by*128, bn = bx*128;
  int tid = threadIdx.x;
  int lane = tid & 63;
  int wave = tid >> 6;
  int wm = (wave >> 1) * 64, wn = (wave & 1) * 64;
  int l15 = lane & 15, lhi = lane >> 4;    // lhi 0..3
  f32x4 acc[4][4];
  #pragma unroll
  for (int i = 0; i < 4; i++)
    #pragma unroll
    for (int j = 0; j < 4; j++)
      acc[i][j] = (f32x4){0.f,0.f,0.f,0.f};

  auto stage = [&](int bufi, int k0){
    #pragma unroll
    for (int j = 0; j < 2; j++){
      int f = j*256 + tid;                 // 0..511 16B-chunks (128 rows x 4 chunks)
      int row = f >> 2, c8 = (f & 3) * 8;
      gload16(A + (size_t)(bm+row)*lda + k0 + c8, &As[bufi][f*8]);
      gload16(W + (size_t)(bn+row)*K   + k0 + c8, &Bs[bufi][f*8]);
    }
  };

  stage(0, 0);
  __syncthreads();                         // drains prologue loads
  int cur = 0;
  for (int k0 = 0; k0 < K; k0 += 32){
    if (k0 + 32 < K) stage(cur ^ 1, k0 + 32);   // issue next tile FIRST (overlap)
    bf16x8 af[4], bfr[4];
    #pragma unroll
    for (int i = 0; i < 4; i++){
      af[i]  = *(const bf16x8*)&As[cur][(wm + i*16 + l15)*32 + lhi*8];
      bfr[i] = *(const bf16x8*)&Bs[cur][(wn + i*16 + l15)*32 + lhi*8];
    }
    #pragma unroll
    for (int i = 0; i < 4; i++)
      #pragma unroll
      for (int j = 0; j < 4; j++)
        acc[i][j] = __builtin_amdgcn_mfma_f32_16x16x32_bf16(af[i], bfr[j], acc[i][j], 0, 0, 0);
    __syncthreads();                       // one vmcnt(0)+barrier per tile
    cur ^= 1;
  }
  #pragma unroll
  for (int i = 0; i < 4; i++){
    #pragma unroll
    for (int r = 0; r < 4; r++){
      int m = bm + wm + i*16 + lhi*4 + r;
      int mo = m;
      if (flip){ int t = m & (L_SEQ-1); mo = (m ^ t) | (L_SEQ-1-t); }
      #pragma unroll
      for (int j = 0; j < 4; j++){
        int n = bn + wn + j*16 + l15;
        if (n < Nreal){
          float v = acc[i][j][r];
          if (bias) v += bias[n];
          if (res)  v += res[(size_t)mo*ldc + coff + n];
          if (Cf)            Cf[(size_t)mo*ldc + coff + n] = v;
          else if (n < n1)   O0[(size_t)mo*ld0 + coff + n] = f2bf(v);
          else if (n < n2)   O1[(size_t)mo*ld1 + (n - n1)] = f2bf(v);
          else               O2[(size_t)mo*ld2 + (n - n2)] = v;
        }
      }
    }
  }
}

// ---------------- causal depthwise conv (k=4) + silu, bf16 in/out ----------------
__global__ void conv_silu_kernel(const unsigned short* __restrict__ xbcf, const unsigned short* __restrict__ xbcb,
                                 const float* __restrict__ cwf, const float* __restrict__ cbf,
                                 const float* __restrict__ cwb, const float* __restrict__ cbb,
                                 unsigned short* __restrict__ cvf, unsigned short* __restrict__ cvb){
  int row = blockIdx.x; int dir = blockIdx.y;
  int tid = threadIdx.x;
  if (tid >= 160) return;
  const unsigned short* xbc = dir ? xbcb : xbcf;
  const float* cw = dir ? cwb : cwf;
  const float* cb = dir ? cbb : cbf;
  unsigned short* cv = dir ? cvb : cvf;
  int t = row & (L_SEQ-1);
  int c0 = tid*8;
  const unsigned short* base = xbc + (size_t)row*CONVDIM + c0;
  US8 u3, u2, u1, u0;
  u3.q = *(const uint4*)base;
  u2.q = (t >= 1) ? *(const uint4*)(base - CONVDIM)   : (uint4){0,0,0,0};
  u1.q = (t >= 2) ? *(const uint4*)(base - 2*CONVDIM) : (uint4){0,0,0,0};
  u0.q = (t >= 3) ? *(const uint4*)(base - 3*CONVDIM) : (uint4){0,0,0,0};
  US8 o;
  #pragma unroll
  for (int j = 0; j < 8; j++){
    float4 w = *(const float4*)&cw[(c0+j)*4];
    float v = cb[c0+j];
    v += bf2f(u3.s[j])*w.w + bf2f(u2.s[j])*w.z + bf2f(u1.s[j])*w.y + bf2f(u0.s[j])*w.x;
    o.s[j] = f2bf(siluf(v));
  }
  *(uint4*)&cv[(size_t)row*CONVDIM + c0] = o.q;
}

// ---------------- dt softplus + per-chunk inclusive cumsum of dt*A ----------------
__global__ void dtcum_kernel(const float* __restrict__ drf, const float* __restrict__ drb,
                             const float* __restrict__ dbf, const float* __restrict__ alf,
                             const float* __restrict__ dbb, const float* __restrict__ alb,
                             float* __restrict__ dtf, float* __restrict__ dtb,
                             float* __restrict__ acs){
  int tid = threadIdx.x;
  int wid = blockIdx.x*4 + (tid >> 6);      // 0..2047 = dbh*32 + c
  int tau = tid & 63;
  int c = wid & 31, dbh = wid >> 5;
  int h = dbh & 15, b = (dbh >> 4) & 1, dir = dbh >> 5;
  const float* dr = dir ? drb : drf;
  size_t row = (size_t)b*L_SEQ + c*QCH + tau;
  float raw = dr[row*NHEADS + h];
  float bias = (dir ? dbb : dbf)[h];
  float dtv = softplusf(raw + bias);
  float a = -expf((dir ? alb : alf)[h]);
  (dir ? dtb : dtf)[row*NHEADS + h] = dtv;
  float v = dtv * a;
  #pragma unroll
  for (int off = 1; off < 64; off <<= 1){
    float u = __shfl_up(v, off);
    if (tau >= off) v += u;
  }
  acs[(size_t)dbh*L_SEQ + c*QCH + tau] = v;
}

// ---------------- K_G (MFMA): G[t][s] = C[t]·B[s], per (dir,b,chunk) ----------------
__global__ __launch_bounds__(256) void gemm_g_kernel(
    const unsigned short* __restrict__ cvf, const unsigned short* __restrict__ cvb,
    float* __restrict__ G){
  int c = blockIdx.x, db = blockIdx.y;
  int b = db & 1, dir = db >> 1;
  const unsigned short* cv = dir ? cvb : cvf;
  float* Gp = G + ((size_t)(db*32 + c))*4096;
  int tid = threadIdx.x, lane = tid & 63, w = tid >> 6;
  int l15 = lane & 15, lhi = lane >> 4;
  __shared__ unsigned short sB[64*128];
  __shared__ unsigned short sC[64*128];
  size_t r0 = (size_t)b*L_SEQ + (size_t)c*QCH;
  #pragma unroll
  for (int k = 0; k < 4; k++){
    int cid = k*256 + tid;
    int row = cid >> 4, slot = cid & 15;
    US8 ub, uc;
    ub.q = *(const uint4*)&cv[(r0+row)*CONVDIM + DINNER + slot*8];
    uc.q = *(const uint4*)&cv[(r0+row)*CONVDIM + DINNER + DSTATE + slot*8];
    *(uint4*)&sB[row*128 + (slot*8 ^ kx(row))] = ub.q;
    *(uint4*)&sC[row*128 + (slot*8 ^ kx(row))] = uc.q;
  }
  __syncthreads();
  int t0 = w*16;
  bf16x8 af[4];
  #pragma unroll
  for (int ks = 0; ks < 4; ks++){
    int r = t0 + l15;
    af[ks] = *(const bf16x8*)&sC[r*128 + ((ks*32 + lhi*8) ^ kx(r))];
  }
  f32x4 acc[4];
  #pragma unroll
  for (int j = 0; j < 4; j++) acc[j] = (f32x4){0.f,0.f,0.f,0.f};
  #pragma unroll
  for (int j = 0; j < 4; j++){
    #pragma unroll
    for (int ks = 0; ks < 4; ks++){
      int r = j*16 + l15;
      bf16x8 wf = *(const bf16x8*)&sB[r*128 + ((ks*32 + lhi*8) ^ kx(r))];
      acc[j] = __builtin_amdgcn_mfma_f32_16x16x32_bf16(af[ks], wf, acc[j], 0, 0, 0);
    }
  }
  #pragma unroll
  for (int j = 0; j < 4; j++)
    #pragma unroll
    for (int r = 0; r < 4; r++)
      Gp[(t0 + lhi*4 + r)*64 + j*16 + l15] = acc[j][r];
}

// ---------------- K_Y (MFMA): intra-chunk Y + chunk-state S^T, per (dir,b,h,chunk) ----
__global__ __launch_bounds__(256) void intra_kernel(
    const unsigned short* __restrict__ cvf, const unsigned short* __restrict__ cvb,
    const float* __restrict__ dtf, const float* __restrict__ dtb,
    const float* __restrict__ acs, const float* __restrict__ G,
    float* __restrict__ yf, float* __restrict__ yb,
    unsigned short* __restrict__ S16f, unsigned short* __restrict__ S16b){
  int c = blockIdx.x, dbh = blockIdx.y;
  int h = dbh & 15, b = (dbh >> 4) & 1, dir = dbh >> 5;
  const unsigned short* cv = dir ? cvb : cvf;
  const float* dtp = dir ? dtb : dtf;
  float* y = dir ? yb : yf;
  unsigned short* S16 = dir ? S16b : S16f;
  const float* Gp = G + ((size_t)((dir*2+b)*32 + c))*4096;
  int tid = threadIdx.x, lane = tid & 63, w = tid >> 6;
  int l15 = lane & 15, lhi = lane >> 4;

  __shared__ unsigned short sGh [64*64];   // Gh[t][s]  (A for Y)
  __shared__ unsigned short sDxT[64*64];   // dxT[p][s] (W for Y, A for S^T)
  __shared__ unsigned short sBwT[128*64];  // BwT[n][s] (W for S^T)
  __shared__ float a_sh[QCH], dt_sh[QCH];

  size_t r0 = (size_t)b*L_SEQ + (size_t)c*QCH;
  if (tid < 64){
    a_sh[tid]  = acs[(size_t)dbh*L_SEQ + c*QCH + tid];
    dt_sh[tid] = dtp[(r0 + tid)*NHEADS + h];
  }
  __syncthreads();
  float a63 = a_sh[63];
  // dxT[p][s] = dt[s]*x[s][p], transposed scalar writes (swizzled)
  #pragma unroll
  for (int k = 0; k < 2; k++){
    int cid = k*256 + tid;
    int s = cid >> 3, p0 = (cid & 7)*8;
    US8 u; u.q = *(const uint4*)&cv[(r0+s)*CONVDIM + h*HEADDIM + p0];
    float d = dt_sh[s];
    #pragma unroll
    for (int j = 0; j < 8; j++){
      int p = p0 + j;
      sDxT[p*64 + (s ^ kx(p))] = f2bf(bf2f(u.s[j]) * d);
    }
  }
  // BwT[n][s] = exp(a63-a[s])*B[s][n]
  #pragma unroll
  for (int k = 0; k < 4; k++){
    int cid = k*256 + tid;
    int s = cid >> 4, n0 = (cid & 15)*8;
    US8 u; u.q = *(const uint4*)&cv[(r0+s)*CONVDIM + DINNER + n0];
    float wv = expf(a63 - a_sh[s]);
    #pragma unroll
    for (int j = 0; j < 8; j++){
      int n = n0 + j;
      sBwT[n*64 + (s ^ kx(n))] = f2bf(bf2f(u.s[j]) * wv);
    }
  }
  // Gh[t][s] = (s<=t) ? G[t][s]*exp(a[t]-a[s]) : 0, bf16
  #pragma unroll
  for (int k = 0; k < 4; k++){
    int f = k*256 + tid;
    int t = f >> 4, s0 = (f & 15)*4;
    float4 g = *(const float4*)&Gp[t*64 + s0];
    float at = a_sh[t];
    float v0 = (s0+0 <= t) ? g.x*expf(at - a_sh[s0+0]) : 0.f;
    float v1 = (s0+1 <= t) ? g.y*expf(at - a_sh[s0+1]) : 0.f;
    float v2 = (s0+2 <= t) ? g.z*expf(at - a_sh[s0+2]) : 0.f;
    float v3 = (s0+3 <= t) ? g.w*expf(at - a_sh[s0+3]) : 0.f;
    int addr = t*64 + (s0 ^ kx(t));
    *(unsigned*)&sGh[addr]     = (unsigned)f2bf(v0) | ((unsigned)f2bf(v1) << 16);
    *(unsigned*)&sGh[addr + 2] = (unsigned)f2bf(v2) | ((unsigned)f2bf(v3) << 16);
  }
  __syncthreads();

  int t0 = w*16;                     // Y t-tile; also S^T p-tile
  bf16x8 aY[2], aS[2];
  #pragma unroll
  for (int ks = 0; ks < 2; ks++){
    int rg = t0 + l15;
    aY[ks] = *(const bf16x8*)&sGh [rg*64 + ((ks*32 + lhi*8) ^ kx(rg))];
    aS[ks] = *(const bf16x8*)&sDxT[rg*64 + ((ks*32 + lhi*8) ^ kx(rg))];
  }
  // Y[t][p] = sum_s Gh[t][s] * dxT[p][s]
  f32x4 accY[4];
  #pragma unroll
  for (int j = 0; j < 4; j++) accY[j] = (f32x4){0.f,0.f,0.f,0.f};
  #pragma unroll
  for (int j = 0; j < 4; j++){
    #pragma unroll
    for (int ks = 0; ks < 2; ks++){
      int rp = j*16 + l15;
      bf16x8 wf = *(const bf16x8*)&sDxT[rp*64 + ((ks*32 + lhi*8) ^ kx(rp))];
      accY[j] = __builtin_amdgcn_mfma_f32_16x16x32_bf16(aY[ks], wf, accY[j], 0, 0, 0);
    }
  }
  // S^T[p][n] = sum_s dxT[p][s] * BwT[n][s]
  f32x4 accS[8];
  #pragma unroll
  for (int j = 0; j < 8; j++) accS[j] = (f32x4){0.f,0.f,0.f,0.f};
  #pragma unroll
  for (int j = 0; j < 8; j++){
    #pragma unroll
    for (int ks = 0; ks < 2; ks++){
      int rn = j*16 + l15;
      bf16x8 wf = *(const bf16x8*)&sBwT[rn*64 + ((ks*32 + lhi*8) ^ kx(rn))];
      accS[j] = __builtin_amdgcn_mfma_f32_16x16x32_bf16(aS[ks], wf, accS[j], 0, 0, 0);
    }
  }
  // epilogues
  #pragma unroll
  for (int j = 0; j < 4; j++){
    #pragma unroll
    for (int r = 0; r < 4; r++){
      int t = t0 + lhi*4 + r, p = j*16 + l15;
      y[(r0 + t)*DINNER + h*HEADDIM + p] = accY[j][r];
    }
  }
  size_t sbase = ((size_t)((b*NHEADS + h)*NCH + c))*8192;
  #pragma unroll
  for (int j = 0; j < 8; j++){
    #pragma unroll
    for (int r = 0; r < 4; r++){
      int p = t0 + lhi*4 + r, n = j*16 + l15;
      S16[sbase + p*128 + n] = f2bf(accS[j][r]);
    }
  }
}

// ---------------- K_S: inter-chunk state recurrence (elementwise over [p][n]) --------
__global__ void chunkscan_kernel(const unsigned short* __restrict__ S16f,
                                 const unsigned short* __restrict__ S16b,
                                 const float* __restrict__ acs,
                                 unsigned short* __restrict__ hin16){
  __shared__ float sa[NCH];
  int tid = threadIdx.x;
  int dbh = blockIdx.x >> 4;
  int e0 = ((blockIdx.x & 15)*256 + tid)*2;
  int bh = dbh & 31, dir = dbh >> 5;
  const unsigned short* S16 = dir ? S16b : S16f;
  if (tid < NCH) sa[tid] = expf(acs[(size_t)dbh*L_SEQ + tid*QCH + 63]);
  __syncthreads();
  float h0 = 0.f, h1 = 0.f;
  #pragma unroll 8
  for (int c = 0; c < NCH; ++c){
    size_t sidx = ((size_t)(bh*NCH + c))*8192 + e0;
    size_t hidx = ((size_t)(dbh*NCH + c))*8192 + e0;
    unsigned sv = *(const unsigned*)&S16[sidx];
    unsigned hv = (unsigned)f2bf(h0) | ((unsigned)f2bf(h1) << 16);
    *(unsigned*)&hin16[hidx] = hv;
    float ea = sa[c];
    h0 = ea*h0 + bf2f((unsigned short)(sv & 0xffff));
    h1 = ea*h1 + bf2f((unsigned short)(sv >> 16));
  }
}

// ---------------- K_I (MFMA): Y = y_intra + e[t]*C·h_in + D*x -> bf16 yg -------------
__global__ __launch_bounds__(256) void inter_kernel(
    const unsigned short* __restrict__ cvf, const unsigned short* __restrict__ cvb,
    const float* __restrict__ acs, const unsigned short* __restrict__ hin16,
    const float* __restrict__ Df, const float* __restrict__ Db,
    const float* __restrict__ yf, const float* __restrict__ yb,
    unsigned short* __restrict__ ygf, unsigned short* __restrict__ ygb){
  int c = blockIdx.x, dbh = blockIdx.y;
  int h = dbh & 15, b = (dbh >> 4) & 1, dir = dbh >> 5;
  const unsigned short* cv = dir ? cvb : cvf;
  const float* y = dir ? yb : yf;
  unsigned short* yg = dir ? ygb : ygf;
  float Dh = (dir ? Db : Df)[h];
  int tid = threadIdx.x, lane = tid & 63, w = tid >> 6;
  int l15 = lane & 15, lhi = lane >> 4;
  __shared__ unsigned short sC [64*128];   // C[t][n]  (A)
  __shared__ unsigned short sHT[64*128];   // hT[p][n] (W)
  __shared__ float e_sh[QCH];
  size_t r0 = (size_t)b*L_SEQ + (size_t)c*QCH;
  size_t hbase = ((size_t)(dbh*NCH + c))*8192;
  if (tid < 64) e_sh[tid] = expf(acs[(size_t)dbh*L_SEQ + c*QCH + tid]);
  #pragma unroll
  for (int k = 0; k < 4; k++){
    int cid = k*256 + tid;
    int row = cid >> 4, slot = cid & 15;
    US8 uc, uh;
    uc.q = *(const uint4*)&cv[(r0+row)*CONVDIM + DINNER + DSTATE + slot*8];
    uh.q = *(const uint4*)&hin16[hbase + cid*8];
    *(uint4*)&sC [row*128 + (slot*8 ^ kx(row))] = uc.q;
    *(uint4*)&sHT[row*128 + (slot*8 ^ kx(row))] = uh.q;
  }
  __syncthreads();
  int t0 = w*16;
  bf16x8 af[4];
  #pragma unroll
  for (int ks = 0; ks < 4; ks++){
    int r = t0 + l15;
    af[ks] = *(const bf16x8*)&sC[r*128 + ((ks*32 + lhi*8) ^ kx(r))];
  }
  f32x4 acc[4];
  #pragma unroll
  for (int j = 0; j < 4; j++) acc[j] = (f32x4){0.f,0.f,0.f,0.f};
  #pragma unroll
  for (int j = 0; j < 4; j++){
    #pragma unroll
    for (int ks = 0; ks < 4; ks++){
      int r = j*16 + l15;
      bf16x8 wf = *(const bf16x8*)&sHT[r*128 + ((ks*32 + lhi*8) ^ kx(r))];
      acc[j] = __builtin_amdgcn_mfma_f32_16x16x32_bf16(af[ks], wf, acc[j], 0, 0, 0);
    }
  }
  #pragma unroll
  for (int j = 0; j < 4; j++){
    #pragma unroll
    for (int r = 0; r < 4; r++){
      int t = t0 + lhi*4 + r, p = j*16 + l15;
      size_t row = r0 + t;
      float xv = bf2f(cv[row*CONVDIM + h*HEADDIM + p]);
      float v = y[row*DINNER + h*HEADDIM + p] + e_sh[t]*acc[j][r] + Dh*xv;
      yg[row*DINNER + h*HEADDIM + p] = f2bf(v);
    }
  }
}

// ---------------- gate (silu(z)) + rmsnorm, all bf16, in place on yg ----------------
__global__ void gate_norm_kernel(unsigned short* __restrict__ ygf, unsigned short* __restrict__ ygb,
                                 const unsigned short* __restrict__ z16f, const unsigned short* __restrict__ z16b,
                                 const float* __restrict__ gwf, const float* __restrict__ gwb){
  __shared__ float red[4];
  int row = blockIdx.x; int dir = blockIdx.y;
  int tid = threadIdx.x;
  unsigned short* yg = (dir ? ygb : ygf) + (size_t)row*DINNER;
  const unsigned short* z = (dir ? z16b : z16f) + (size_t)row*DINNER;
  const float* gw = dir ? gwb : gwf;
  int d = tid*4;
  US4 uy, uz;
  uy.q = *(const uint2*)&yg[d];
  uz.q = *(const uint2*)&z[d];
  float v[4]; float ss = 0.f;
  #pragma unroll
  for (int k = 0; k < 4; k++){
    float val = bf2f(uy.s[k]) * siluf(bf2f(uz.s[k]));
    v[k] = val; ss += val*val;
  }
  ss = blockReduceSum256(ss, red);   // __syncthreads inside: reads precede writes
  float scale = rsqrtf(ss*(1.f/DINNER) + 1e-5f);
  float4 w4 = *(const float4*)&gw[d];
  US4 o;
  o.s[0] = f2bf(v[0]*scale*w4.x);
  o.s[1] = f2bf(v[1]*scale*w4.y);
  o.s[2] = f2bf(v[2]*scale*w4.z);
  o.s[3] = f2bf(v[3]*scale*w4.w);
  *(uint2*)&yg[d] = o.q;
}

extern "C" void kernel_launch(void* const* d_in, const int* in_sizes, int n_in,
                              void* d_out, int out_size, void* d_ws, size_t ws_size,
                              hipStream_t stream) {
  const float* x      = (const float*)d_in[0];
  const float* norm_w = (const float*)d_in[1];
  const float* op_w   = (const float*)d_in[2];
  const float* op_b   = (const float*)d_in[3];
  const float* f_in_w    = (const float*)d_in[4];
  const float* f_conv_w  = (const float*)d_in[5];
  const float* f_conv_b  = (const float*)d_in[6];
  const float* f_dt_bias = (const float*)d_in[7];
  const float* f_A_log   = (const float*)d_in[8];
  const float* f_D       = (const float*)d_in[9];
  const float* f_gnorm_w = (const float*)d_in[10];
  const float* f_outp_w  = (const float*)d_in[11];
  const float* b_in_w    = (const float*)d_in[12];
  const float* b_conv_w  = (const float*)d_in[13];
  const float* b_conv_b  = (const float*)d_in[14];
  const float* b_dt_bias = (const float*)d_in[15];
  const float* b_A_log   = (const float*)d_in[16];
  const float* b_D       = (const float*)d_in[17];
  const float* b_gnorm_w = (const float*)d_in[18];
  const float* b_outp_w  = (const float*)d_in[19];
  float* out = (float*)d_out;

  float* ws = (float*)d_ws;
  size_t off = 0;
  unsigned short* u16f = (unsigned short*)(ws + off);
  unsigned short* u16b = u16f + (size_t)ROWS*DHALF;      off += (size_t)ROWS*DHALF;
  unsigned short* z16f = (unsigned short*)(ws + off);    off += (size_t)ROWS*DINNER/2;
  unsigned short* z16b = (unsigned short*)(ws + off);    off += (size_t)ROWS*DINNER/2;
  unsigned short* xbc16f = (unsigned short*)(ws + off);  off += (size_t)ROWS*CONVDIM/2;
  unsigned short* xbc16b = (unsigned short*)(ws + off);  off += (size_t)ROWS*CONVDIM/2;
  float* draw_f = ws + off; off += (size_t)ROWS*NHEADS;
  float* draw_b = ws + off; off += (size_t)ROWS*NHEADS;
  unsigned short* cv16f = (unsigned short*)(ws + off); off += (size_t)ROWS*CONVDIM/2;
  unsigned short* cv16b = (unsigned short*)(ws + off); off += (size_t)ROWS*CONVDIM/2;
  float* dt_f = ws + off; off += (size_t)ROWS*NHEADS;
  float* dt_b = ws + off; off += (size_t)ROWS*NHEADS;
  float* y_f  = ws + off; off += (size_t)ROWS*DINNER;
  float* y_b  = ws + off; off += (size_t)ROWS*DINNER;
  unsigned short* yg16f = (unsigned short*)(ws + off); off += (size_t)ROWS*DINNER/2;
  unsigned short* yg16b = (unsigned short*)(ws + off); off += (size_t)ROWS*DINNER/2;
  float* acs  = ws + off; off += (size_t)64*L_SEQ;
  float* G    = ws + off; off += (size_t)128*QCH*QCH;
  unsigned short* S16f = (unsigned short*)(ws + off); off += (size_t)32*NCH*8192/2;
  unsigned short* S16b = (unsigned short*)(ws + off); off += (size_t)32*NCH*8192/2;
  unsigned short* hin16 = (unsigned short*)(ws + off); off += (size_t)64*NCH*8192/2;
  unsigned short* w16_fin  = (unsigned short*)(ws + off); off += (size_t)NPADIN*DHALF/2;
  unsigned short* w16_bin  = (unsigned short*)(ws + off); off += (size_t)NPADIN*DHALF/2;
  unsigned short* w16_fout = (unsigned short*)(ws + off); off += (size_t)DHALF*DINNER/2;
  unsigned short* w16_bout = (unsigned short*)(ws + off); off += (size_t)DHALF*DINNER/2;
  unsigned short* w16_op   = (unsigned short*)(ws + off); off += (size_t)DMODEL*DMODEL/2;
  // cat (bf16 [ROWS][1024]) overlays z16f+z16b region (dead after gate_norm)
  unsigned short* cat16 = z16f;

  // 1. rmsnorm + split (bf16, backward pre-flipped)
  rmsnorm_split_kernel<<<ROWS, 256, 0, stream>>>(x, norm_w, u16f, u16b);
  // 2. weight conversions (single launch)
  {
    const int TOT = 2*NPADIN*DHALF + 2*DHALF*DINNER + DMODEL*DMODEL;
    wconv_all_kernel<<<(TOT+255)/256, 256, 0, stream>>>(
        f_in_w, b_in_w, f_outp_w, b_outp_w, op_w,
        w16_fin, w16_bin, w16_fout, w16_bout, w16_op);
  }
  // 3. in-proj GEMM, both dirs in one launch; 3-way split epilogue
  gemm_bf16_kernel<<<dim3(NPADIN/128, ROWS/128, 2), 256, 0, stream>>>(
      u16f, u16b, DHALF, w16_fin, w16_bin,
      nullptr, 0, nullptr, nullptr,
      z16f, z16b, DINNER,
      xbc16f, xbc16b, DINNER, CONVDIM,
      draw_f, draw_b, DINNER+CONVDIM, NHEADS,
      0, 0,
      ROWS, DINPROJ, DHALF);
  // 4. conv + silu (bf16 in/out)
  conv_silu_kernel<<<dim3(ROWS, 2), 256, 0, stream>>>(
      xbc16f, xbc16b, f_conv_w, f_conv_b, b_conv_w, b_conv_b, cv16f, cv16b);
  // 5. dt softplus + chunked cumsum
  dtcum_kernel<<<512, 256, 0, stream>>>(
      draw_f, draw_b, f_dt_bias, f_A_log, b_dt_bias, b_A_log, dt_f, dt_b, acs);
  // 6. SSD: G, intra(Y+S), chunk recurrence, inter (-> bf16 yg)
  gemm_g_kernel<<<dim3(32, 4), 256, 0, stream>>>(cv16f, cv16b, G);
  intra_kernel<<<dim3(32, 64), 256, 0, stream>>>(cv16f, cv16b, dt_f, dt_b, acs, G,
                                                 y_f, y_b, S16f, S16b);
  chunkscan_kernel<<<1024, 256, 0, stream>>>(S16f, S16b, acs, hin16);
  inter_kernel<<<dim3(32, 64), 256, 0, stream>>>(cv16f, cv16b, acs, hin16, f_D, b_D,
                                                 y_f, y_b, yg16f, yg16b);
  // 7. gate + rmsnorm (all bf16, in place on yg)
  gate_norm_kernel<<<dim3(ROWS, 2), 256, 0, stream>>>(
      yg16f, yg16b, z16f, z16b, f_gnorm_w, b_gnorm_w);
  // 8. out-proj GEMM, both dirs in one launch -> cat16 (dir1 time-flipped, coff=512)
  gemm_bf16_kernel<<<dim3(DHALF/128, ROWS/128, 2), 256, 0, stream>>>(
      yg16f, yg16b, DINNER, w16_fout, w16_bout,
      nullptr, 0, nullptr, nullptr,
      cat16, cat16, DMODEL,
      nullptr, nullptr, 1<<30, 0,
      nullptr, nullptr, 1<<30, 0,
      DHALF, 1,
      ROWS, DHALF, DINNER);
  // 9. final projection + bias + residual (fp32 out)
  gemm_bf16_kernel<<<dim3(DMODEL/128, ROWS/128, 1), 256, 0, stream>>>(
      cat16, nullptr, DMODEL, w16_op, nullptr,
      out, DMODEL, op_b, x,
      nullptr, nullptr, 0,
      nullptr, nullptr, 1<<30, 0,
      nullptr, nullptr, 1<<30, 0,
      0, 0,
      ROWS, DMODEL, DMODEL);
}

// Round 9
// 222.844 us; speedup vs baseline: 9.1988x; 1.0812x over previous
//
#include <hip/hip_runtime.h>
#include <math.h>

#define L_SEQ   2048
#define NBATCH  2
#define DMODEL  1024
#define DHALF   512
#define DINNER  1024
#define DSTATE  128
#define NHEADS  16
#define HEADDIM 64
#define CONVDIM 1280
#define DINPROJ 2320
#define ROWS    4096   /* NBATCH * L_SEQ */
#define NPADIN  2432   /* DINPROJ padded to multiple of 128 */

#define QCH     64               /* SSD chunk length */
#define NCH     (L_SEQ / QCH)    /* 32 chunks */

typedef __attribute__((ext_vector_type(8))) short bf16x8;
typedef __attribute__((ext_vector_type(4))) float f32x4;

union US8 { uint4 q; unsigned short s[8]; };
union US4 { uint2 q; unsigned short s[4]; };

__device__ __forceinline__ float siluf(float v){ return v / (1.f + expf(-v)); }
__device__ __forceinline__ float softplusf(float v){ return v > 20.f ? v : log1pf(expf(v)); }
__device__ __forceinline__ unsigned short f2bf(float f){
  union { float f; unsigned u; } x; x.f = f;
  unsigned r = (x.u + 0x7fffu + ((x.u >> 16) & 1u)) >> 16;
  return (unsigned short)r;
}
__device__ __forceinline__ float bf2f(unsigned short u){
  union { unsigned u; float f; } x; x.u = ((unsigned)u) << 16; return x.f;
}
__device__ __forceinline__ void gload16(const void* g, void* l){
  __builtin_amdgcn_global_load_lds((const __attribute__((address_space(1))) void*)g,
                                   (__attribute__((address_space(3))) void*)l, 16, 0, 0);
}
__device__ __forceinline__ int kx(int row){ return ((row ^ (row >> 3)) & 7) << 3; }

__device__ __forceinline__ float blockReduceSum256(float v, float* red){
  #pragma unroll
  for (int o = 32; o > 0; o >>= 1) v += __shfl_xor(v, o);
  int wid = threadIdx.x >> 6, lane = threadIdx.x & 63;
  if (lane == 0) red[wid] = v;
  __syncthreads();
  return red[0] + red[1] + red[2] + red[3];
}

// ---------------- rmsnorm + split into bf16 u_f and (pre-flipped) u_b ----------------
__global__ void rmsnorm_split_kernel(const float* __restrict__ x, const float* __restrict__ nw,
                                     unsigned short* __restrict__ uf, unsigned short* __restrict__ ub){
  __shared__ float red[4];
  int row = blockIdx.x;                       // b*L + t
  int tid = threadIdx.x;
  float4 v4 = *(const float4*)(x + (size_t)row*DMODEL + tid*4);
  float ss = v4.x*v4.x + v4.y*v4.y + v4.z*v4.z + v4.w*v4.w;
  ss = blockReduceSum256(ss, red);
  float scale = rsqrtf(ss * (1.f/DMODEL) + 1e-5f);
  int t = row & (L_SEQ-1);
  int fliprow = (row ^ t) | (L_SEQ-1-t);
  float4 w4 = *(const float4*)(nw + tid*4);
  US4 o;
  o.s[0] = f2bf(v4.x*scale*w4.x);
  o.s[1] = f2bf(v4.y*scale*w4.y);
  o.s[2] = f2bf(v4.z*scale*w4.z);
  o.s[3] = f2bf(v4.w*scale*w4.w);
  int d = tid*4;
  if (d < DHALF) *(uint2*)&uf[(size_t)row*DHALF + d] = o.q;
  else           *(uint2*)&ub[(size_t)fliprow*DHALF + (d - DHALF)] = o.q;
}

// ---------------- all weight fp32 -> bf16 (+row pad), one launch, x4 vectorized ------
__global__ void wconv_all_kernel(const float* __restrict__ s0, const float* __restrict__ s1,
                                 const float* __restrict__ s2, const float* __restrict__ s3,
                                 const float* __restrict__ s4,
                                 unsigned short* __restrict__ d0, unsigned short* __restrict__ d1,
                                 unsigned short* __restrict__ d2, unsigned short* __restrict__ d3,
                                 unsigned short* __restrict__ d4){
  const int S01 = NPADIN*DHALF;          // kshift 9, rows DINPROJ
  const int S23 = DHALF*DINNER;
  const int S4  = DMODEL*DMODEL;
  int idx = (blockIdx.x*256 + threadIdx.x)*4;
  const float* s; unsigned short* d; int pad_rows = 0;
  if (idx < S01){ s = s0; d = d0; pad_rows = DINPROJ; }
  else if ((idx -= S01) < S01){ s = s1; d = d1; pad_rows = DINPROJ; }
  else if ((idx -= S01) < S23){ s = s2; d = d2; }
  else if ((idx -= S23) < S23){ s = s3; d = d3; }
  else if ((idx -= S23) < S4){ s = s4; d = d4; }
  else return;
  US4 o;
  if (pad_rows && (idx >> 9) >= pad_rows){
    o.s[0] = o.s[1] = o.s[2] = o.s[3] = 0;
  } else {
    float4 v = *(const float4*)&s[idx];
    o.s[0] = f2bf(v.x); o.s[1] = f2bf(v.y); o.s[2] = f2bf(v.z); o.s[3] = f2bf(v.w);
  }
  *(uint2*)&d[idx] = o.q;
}

// ---------------- bf16 MFMA GEMM: dual-direction, 2-phase pipelined, TM-templated ----
// dir d: A = (d?A1:A0), W = (d?W1:W0), outputs per-dir. coff/flip apply to dir1 only.
// Epilogue: Cf != null -> all fp32 at ldc (+bias/res).
//   else n<n1 -> O0 bf16 ld0 (+coff,flip); n1<=n<n2 -> O1 bf16 ld1; else O2 fp32 ld2.
template<int TM>
__global__ __launch_bounds__(256) void gemm_bf16_t(
    const unsigned short* __restrict__ A0, const unsigned short* __restrict__ A1, int lda,
    const unsigned short* __restrict__ W0, const unsigned short* __restrict__ W1,
    float* __restrict__ Cf, int ldc,
    const float* __restrict__ bias, const float* __restrict__ res,
    unsigned short* __restrict__ O0a, unsigned short* __restrict__ O0b, int ld0,
    unsigned short* __restrict__ O1a, unsigned short* __restrict__ O1b, int n1, int ld1,
    float* __restrict__ O2a, float* __restrict__ O2b, int n2, int ld2,
    int coff1, int flip1,
    int M, int Nreal, int K){
  constexpr int MI = TM/32;                // m-fragments per wave
  __shared__ unsigned short As[2][TM*32];
  __shared__ unsigned short Bs[2][128*32];
  // XCD-aware swizzle over flattened (z,y,x) grid
  int bid = (blockIdx.z*gridDim.y + blockIdx.y)*gridDim.x + blockIdx.x;
  int nwg = gridDim.x*gridDim.y*gridDim.z;
  int s = bid;
  if ((nwg & 7) == 0){
    int cpx = nwg >> 3;
    s = (bid & 7)*cpx + (bid >> 3);
  }
  int bx = s % gridDim.x;
  int tmp = s / gridDim.x;
  int by = tmp % gridDim.y;
  int dir = tmp / gridDim.y;

  const unsigned short* A = dir ? A1 : A0;
  const unsigned short* W = dir ? W1 : W0;
  unsigned short* O0 = dir ? O0b : O0a;
  unsigned short* O1 = dir ? O1b : O1a;
  float* O2 = dir ? O2b : O2a;
  int coff = dir ? coff1 : 0;
  int flip = dir ? flip1 : 0;

  int bm = by*TM, bn = bx*128;
  int tid = threadIdx.x;
  int lane = tid & 63;
  int wave = tid >> 6;
  int wm = (wave >> 1) * (TM/2), wn = (wave & 1) * 64;
  int l15 = lane & 15, lhi = lane >> 4;    // lhi 0..3
  f32x4 acc[MI][4];
  #pragma unroll
  for (int i = 0; i < MI; i++)
    #pragma unroll
    for (int j = 0; j < 4; j++)
      acc[i][j] = (f32x4){0.f,0.f,0.f,0.f};

  auto stage = [&](int bufi, int k0){
    #pragma unroll
    for (int f = tid; f < TM*4; f += 256){
      int row = f >> 2, c8 = (f & 3) * 8;
      gload16(A + (size_t)(bm+row)*lda + k0 + c8, &As[bufi][f*8]);
    }
    #pragma unroll
    for (int f = tid; f < 512; f += 256){
      int row = f >> 2, c8 = (f & 3) * 8;
      gload16(W + (size_t)(bn+row)*K + k0 + c8, &Bs[bufi][f*8]);
    }
  };

  stage(0, 0);
  __syncthreads();                         // drains prologue loads
  int cur = 0;
  for (int k0 = 0; k0 < K; k0 += 32){
    if (k0 + 32 < K) stage(cur ^ 1, k0 + 32);   // issue next tile FIRST (overlap)
    bf16x8 af[MI], bfr[4];
    #pragma unroll
    for (int i = 0; i < MI; i++)
      af[i] = *(const bf16x8*)&As[cur][(wm + i*16 + l15)*32 + lhi*8];
    #pragma unroll
    for (int j = 0; j < 4; j++)
      bfr[j] = *(const bf16x8*)&Bs[cur][(wn + j*16 + l15)*32 + lhi*8];
    #pragma unroll
    for (int i = 0; i < MI; i++)
      #pragma unroll
      for (int j = 0; j < 4; j++)
        acc[i][j] = __builtin_amdgcn_mfma_f32_16x16x32_bf16(af[i], bfr[j], acc[i][j], 0, 0, 0);
    __syncthreads();                       // one vmcnt(0)+barrier per tile
    cur ^= 1;
  }
  #pragma unroll
  for (int i = 0; i < MI; i++){
    #pragma unroll
    for (int r = 0; r < 4; r++){
      int m = bm + wm + i*16 + lhi*4 + r;
      int mo = m;
      if (flip){ int t = m & (L_SEQ-1); mo = (m ^ t) | (L_SEQ-1-t); }
      #pragma unroll
      for (int j = 0; j < 4; j++){
        int n = bn + wn + j*16 + l15;
        if (n < Nreal){
          float v = acc[i][j][r];
          if (bias) v += bias[n];
          if (res)  v += res[(size_t)mo*ldc + coff + n];
          if (Cf)            Cf[(size_t)mo*ldc + coff + n] = v;
          else if (n < n1)   O0[(size_t)mo*ld0 + coff + n] = f2bf(v);
          else if (n < n2)   O1[(size_t)mo*ld1 + (n - n1)] = f2bf(v);
          else               O2[(size_t)mo*ld2 + (n - n2)] = v;
        }
      }
    }
  }
}

// ---------------- causal depthwise conv (k=4) + silu, bf16 in/out, both dirs/block ---
__global__ void conv_silu_kernel(const unsigned short* __restrict__ xbcf, const unsigned short* __restrict__ xbcb,
                                 const float* __restrict__ cwf, const float* __restrict__ cbf,
                                 const float* __restrict__ cwb, const float* __restrict__ cbb,
                                 unsigned short* __restrict__ cvf, unsigned short* __restrict__ cvb){
  int row = blockIdx.x;
  int tid = threadIdx.x;              // 0..319: dir = tid>=160
  int dir = tid >= 160;
  int slot = tid - dir*160;
  const unsigned short* xbc = dir ? xbcb : xbcf;
  const float* cw = dir ? cwb : cwf;
  const float* cb = dir ? cbb : cbf;
  unsigned short* cv = dir ? cvb : cvf;
  int t = row & (L_SEQ-1);
  int c0 = slot*8;
  const unsigned short* base = xbc + (size_t)row*CONVDIM + c0;
  US8 u3, u2, u1, u0;
  u3.q = *(const uint4*)base;
  u2.q = (t >= 1) ? *(const uint4*)(base - CONVDIM)   : (uint4){0,0,0,0};
  u1.q = (t >= 2) ? *(const uint4*)(base - 2*CONVDIM) : (uint4){0,0,0,0};
  u0.q = (t >= 3) ? *(const uint4*)(base - 3*CONVDIM) : (uint4){0,0,0,0};
  US8 o;
  #pragma unroll
  for (int j = 0; j < 8; j++){
    float4 w = *(const float4*)&cw[(c0+j)*4];
    float v = cb[c0+j];
    v += bf2f(u3.s[j])*w.w + bf2f(u2.s[j])*w.z + bf2f(u1.s[j])*w.y + bf2f(u0.s[j])*w.x;
    o.s[j] = f2bf(siluf(v));
  }
  *(uint4*)&cv[(size_t)row*CONVDIM + c0] = o.q;
}

// ---------------- dt softplus + per-chunk inclusive cumsum of dt*A ----------------
__global__ void dtcum_kernel(const float* __restrict__ drf, const float* __restrict__ drb,
                             const float* __restrict__ dbf, const float* __restrict__ alf,
                             const float* __restrict__ dbb, const float* __restrict__ alb,
                             float* __restrict__ dtf, float* __restrict__ dtb,
                             float* __restrict__ acs){
  int tid = threadIdx.x;
  int wid = blockIdx.x*4 + (tid >> 6);      // 0..2047 = dbh*32 + c
  int tau = tid & 63;
  int c = wid & 31, dbh = wid >> 5;
  int h = dbh & 15, b = (dbh >> 4) & 1, dir = dbh >> 5;
  const float* dr = dir ? drb : drf;
  size_t row = (size_t)b*L_SEQ + c*QCH + tau;
  float raw = dr[row*NHEADS + h];
  float bias = (dir ? dbb : dbf)[h];
  float dtv = softplusf(raw + bias);
  float a = -expf((dir ? alb : alf)[h]);
  (dir ? dtb : dtf)[row*NHEADS + h] = dtv;
  float v = dtv * a;
  #pragma unroll
  for (int off = 1; off < 64; off <<= 1){
    float u = __shfl_up(v, off);
    if (tau >= off) v += u;
  }
  acs[(size_t)dbh*L_SEQ + c*QCH + tau] = v;
}

// ---------------- K_G (MFMA): G[t][s] = C[t]·B[s], per (dir,b,chunk) ----------------
__global__ __launch_bounds__(256) void gemm_g_kernel(
    const unsigned short* __restrict__ cvf, const unsigned short* __restrict__ cvb,
    float* __restrict__ G){
  int c = blockIdx.x, db = blockIdx.y;
  int b = db & 1, dir = db >> 1;
  const unsigned short* cv = dir ? cvb : cvf;
  float* Gp = G + ((size_t)(db*32 + c))*4096;
  int tid = threadIdx.x, lane = tid & 63, w = tid >> 6;
  int l15 = lane & 15, lhi = lane >> 4;
  __shared__ unsigned short sB[64*128];
  __shared__ unsigned short sC[64*128];
  size_t r0 = (size_t)b*L_SEQ + (size_t)c*QCH;
  #pragma unroll
  for (int k = 0; k < 4; k++){
    int cid = k*256 + tid;
    int row = cid >> 4, slot = cid & 15;
    US8 ub, uc;
    ub.q = *(const uint4*)&cv[(r0+row)*CONVDIM + DINNER + slot*8];
    uc.q = *(const uint4*)&cv[(r0+row)*CONVDIM + DINNER + DSTATE + slot*8];
    *(uint4*)&sB[row*128 + (slot*8 ^ kx(row))] = ub.q;
    *(uint4*)&sC[row*128 + (slot*8 ^ kx(row))] = uc.q;
  }
  __syncthreads();
  int t0 = w*16;
  bf16x8 af[4];
  #pragma unroll
  for (int ks = 0; ks < 4; ks++){
    int r = t0 + l15;
    af[ks] = *(const bf16x8*)&sC[r*128 + ((ks*32 + lhi*8) ^ kx(r))];
  }
  f32x4 acc[4];
  #pragma unroll
  for (int j = 0; j < 4; j++) acc[j] = (f32x4){0.f,0.f,0.f,0.f};
  #pragma unroll
  for (int j = 0; j < 4; j++){
    #pragma unroll
    for (int ks = 0; ks < 4; ks++){
      int r = j*16 + l15;
      bf16x8 wf = *(const bf16x8*)&sB[r*128 + ((ks*32 + lhi*8) ^ kx(r))];
      acc[j] = __builtin_amdgcn_mfma_f32_16x16x32_bf16(af[ks], wf, acc[j], 0, 0, 0);
    }
  }
  #pragma unroll
  for (int j = 0; j < 4; j++)
    #pragma unroll
    for (int r = 0; r < 4; r++)
      Gp[(t0 + lhi*4 + r)*64 + j*16 + l15] = acc[j][r];
}

// ---------------- K_Y (MFMA): intra-chunk Y + chunk-state S^T, per (dir,b,h,chunk) ----
__global__ __launch_bounds__(256) void intra_kernel(
    const unsigned short* __restrict__ cvf, const unsigned short* __restrict__ cvb,
    const float* __restrict__ dtf, const float* __restrict__ dtb,
    const float* __restrict__ acs, const float* __restrict__ G,
    float* __restrict__ yf, float* __restrict__ yb,
    unsigned short* __restrict__ S16f, unsigned short* __restrict__ S16b){
  int c = blockIdx.x, dbh = blockIdx.y;
  int h = dbh & 15, b = (dbh >> 4) & 1, dir = dbh >> 5;
  const unsigned short* cv = dir ? cvb : cvf;
  const float* dtp = dir ? dtb : dtf;
  float* y = dir ? yb : yf;
  unsigned short* S16 = dir ? S16b : S16f;
  const float* Gp = G + ((size_t)((dir*2+b)*32 + c))*4096;
  int tid = threadIdx.x, lane = tid & 63, w = tid >> 6;
  int l15 = lane & 15, lhi = lane >> 4;

  __shared__ unsigned short sGh [64*64];   // Gh[t][s]  (A for Y)
  __shared__ unsigned short sDxT[64*64];   // dxT[p][s] (W for Y, A for S^T)
  __shared__ unsigned short sBwT[128*64];  // BwT[n][s] (W for S^T)
  __shared__ float a_sh[QCH], dt_sh[QCH];

  size_t r0 = (size_t)b*L_SEQ + (size_t)c*QCH;
  if (tid < 64){
    a_sh[tid]  = acs[(size_t)dbh*L_SEQ + c*QCH + tid];
    dt_sh[tid] = dtp[(r0 + tid)*NHEADS + h];
  }
  __syncthreads();
  float a63 = a_sh[63];
  // dxT[p][s] = dt[s]*x[s][p], transposed scalar writes (swizzled)
  #pragma unroll
  for (int k = 0; k < 2; k++){
    int cid = k*256 + tid;
    int s = cid >> 3, p0 = (cid & 7)*8;
    US8 u; u.q = *(const uint4*)&cv[(r0+s)*CONVDIM + h*HEADDIM + p0];
    float d = dt_sh[s];
    #pragma unroll
    for (int j = 0; j < 8; j++){
      int p = p0 + j;
      sDxT[p*64 + (s ^ kx(p))] = f2bf(bf2f(u.s[j]) * d);
    }
  }
  // BwT[n][s] = exp(a63-a[s])*B[s][n]
  #pragma unroll
  for (int k = 0; k < 4; k++){
    int cid = k*256 + tid;
    int s = cid >> 4, n0 = (cid & 15)*8;
    US8 u; u.q = *(const uint4*)&cv[(r0+s)*CONVDIM + DINNER + n0];
    float wv = expf(a63 - a_sh[s]);
    #pragma unroll
    for (int j = 0; j < 8; j++){
      int n = n0 + j;
      sBwT[n*64 + (s ^ kx(n))] = f2bf(bf2f(u.s[j]) * wv);
    }
  }
  // Gh[t][s] = (s<=t) ? G[t][s]*exp(a[t]-a[s]) : 0, bf16
  #pragma unroll
  for (int k = 0; k < 4; k++){
    int f = k*256 + tid;
    int t = f >> 4, s0 = (f & 15)*4;
    float4 g = *(const float4*)&Gp[t*64 + s0];
    float at = a_sh[t];
    float v0 = (s0+0 <= t) ? g.x*expf(at - a_sh[s0+0]) : 0.f;
    float v1 = (s0+1 <= t) ? g.y*expf(at - a_sh[s0+1]) : 0.f;
    float v2 = (s0+2 <= t) ? g.z*expf(at - a_sh[s0+2]) : 0.f;
    float v3 = (s0+3 <= t) ? g.w*expf(at - a_sh[s0+3]) : 0.f;
    int addr = t*64 + (s0 ^ kx(t));
    *(unsigned*)&sGh[addr]     = (unsigned)f2bf(v0) | ((unsigned)f2bf(v1) << 16);
    *(unsigned*)&sGh[addr + 2] = (unsigned)f2bf(v2) | ((unsigned)f2bf(v3) << 16);
  }
  __syncthreads();

  int t0 = w*16;                     // Y t-tile; also S^T p-tile
  bf16x8 aY[2], aS[2];
  #pragma unroll
  for (int ks = 0; ks < 2; ks++){
    int rg = t0 + l15;
    aY[ks] = *(const bf16x8*)&sGh [rg*64 + ((ks*32 + lhi*8) ^ kx(rg))];
    aS[ks] = *(const bf16x8*)&sDxT[rg*64 + ((ks*32 + lhi*8) ^ kx(rg))];
  }
  // Y[t][p] = sum_s Gh[t][s] * dxT[p][s]
  f32x4 accY[4];
  #pragma unroll
  for (int j = 0; j < 4; j++) accY[j] = (f32x4){0.f,0.f,0.f,0.f};
  #pragma unroll
  for (int j = 0; j < 4; j++){
    #pragma unroll
    for (int ks = 0; ks < 2; ks++){
      int rp = j*16 + l15;
      bf16x8 wf = *(const bf16x8*)&sDxT[rp*64 + ((ks*32 + lhi*8) ^ kx(rp))];
      accY[j] = __builtin_amdgcn_mfma_f32_16x16x32_bf16(aY[ks], wf, accY[j], 0, 0, 0);
    }
  }
  // S^T[p][n] = sum_s dxT[p][s] * BwT[n][s]
  f32x4 accS[8];
  #pragma unroll
  for (int j = 0; j < 8; j++) accS[j] = (f32x4){0.f,0.f,0.f,0.f};
  #pragma unroll
  for (int j = 0; j < 8; j++){
    #pragma unroll
    for (int ks = 0; ks < 2; ks++){
      int rn = j*16 + l15;
      bf16x8 wf = *(const bf16x8*)&sBwT[rn*64 + ((ks*32 + lhi*8) ^ kx(rn))];
      accS[j] = __builtin_amdgcn_mfma_f32_16x16x32_bf16(aS[ks], wf, accS[j], 0, 0, 0);
    }
  }
  // epilogues
  #pragma unroll
  for (int j = 0; j < 4; j++){
    #pragma unroll
    for (int r = 0; r < 4; r++){
      int t = t0 + lhi*4 + r, p = j*16 + l15;
      y[(r0 + t)*DINNER + h*HEADDIM + p] = accY[j][r];
    }
  }
  size_t sbase = ((size_t)((b*NHEADS + h)*NCH + c))*8192;
  #pragma unroll
  for (int j = 0; j < 8; j++){
    #pragma unroll
    for (int r = 0; r < 4; r++){
      int p = t0 + lhi*4 + r, n = j*16 + l15;
      S16[sbase + p*128 + n] = f2bf(accS[j][r]);
    }
  }
}

// ---------------- K_S: inter-chunk state recurrence (elementwise over [p][n]) --------
__global__ void chunkscan_kernel(const unsigned short* __restrict__ S16f,
                                 const unsigned short* __restrict__ S16b,
                                 const float* __restrict__ acs,
                                 unsigned short* __restrict__ hin16){
  __shared__ float sa[NCH];
  int tid = threadIdx.x;
  int dbh = blockIdx.x >> 4;
  int e0 = ((blockIdx.x & 15)*256 + tid)*2;
  int bh = dbh & 31, dir = dbh >> 5;
  const unsigned short* S16 = dir ? S16b : S16f;
  if (tid < NCH) sa[tid] = expf(acs[(size_t)dbh*L_SEQ + tid*QCH + 63]);
  __syncthreads();
  float h0 = 0.f, h1 = 0.f;
  #pragma unroll 8
  for (int c = 0; c < NCH; ++c){
    size_t sidx = ((size_t)(bh*NCH + c))*8192 + e0;
    size_t hidx = ((size_t)(dbh*NCH + c))*8192 + e0;
    unsigned sv = *(const unsigned*)&S16[sidx];
    unsigned hv = (unsigned)f2bf(h0) | ((unsigned)f2bf(h1) << 16);
    *(unsigned*)&hin16[hidx] = hv;
    float ea = sa[c];
    h0 = ea*h0 + bf2f((unsigned short)(sv & 0xffff));
    h1 = ea*h1 + bf2f((unsigned short)(sv >> 16));
  }
}

// ---------------- K_I (MFMA): Y = y_intra + e[t]*C·h_in + D*x -> bf16 yg -------------
__global__ __launch_bounds__(256) void inter_kernel(
    const unsigned short* __restrict__ cvf, const unsigned short* __restrict__ cvb,
    const float* __restrict__ acs, const unsigned short* __restrict__ hin16,
    const float* __restrict__ Df, const float* __restrict__ Db,
    const float* __restrict__ yf, const float* __restrict__ yb,
    unsigned short* __restrict__ ygf, unsigned short* __restrict__ ygb){
  int c = blockIdx.x, dbh = blockIdx.y;
  int h = dbh & 15, b = (dbh >> 4) & 1, dir = dbh >> 5;
  const unsigned short* cv = dir ? cvb : cvf;
  const float* y = dir ? yb : yf;
  unsigned short* yg = dir ? ygb : ygf;
  float Dh = (dir ? Db : Df)[h];
  int tid = threadIdx.x, lane = tid & 63, w = tid >> 6;
  int l15 = lane & 15, lhi = lane >> 4;
  __shared__ unsigned short sC [64*128];   // C[t][n]  (A)
  __shared__ unsigned short sHT[64*128];   // hT[p][n] (W)
  __shared__ float e_sh[QCH];
  size_t r0 = (size_t)b*L_SEQ + (size_t)c*QCH;
  size_t hbase = ((size_t)(dbh*NCH + c))*8192;
  if (tid < 64) e_sh[tid] = expf(acs[(size_t)dbh*L_SEQ + c*QCH + tid]);
  #pragma unroll
  for (int k = 0; k < 4; k++){
    int cid = k*256 + tid;
    int row = cid >> 4, slot = cid & 15;
    US8 uc, uh;
    uc.q = *(const uint4*)&cv[(r0+row)*CONVDIM + DINNER + DSTATE + slot*8];
    uh.q = *(const uint4*)&hin16[hbase + cid*8];
    *(uint4*)&sC [row*128 + (slot*8 ^ kx(row))] = uc.q;
    *(uint4*)&sHT[row*128 + (slot*8 ^ kx(row))] = uh.q;
  }
  __syncthreads();
  int t0 = w*16;
  bf16x8 af[4];
  #pragma unroll
  for (int ks = 0; ks < 4; ks++){
    int r = t0 + l15;
    af[ks] = *(const bf16x8*)&sC[r*128 + ((ks*32 + lhi*8) ^ kx(r))];
  }
  f32x4 acc[4];
  #pragma unroll
  for (int j = 0; j < 4; j++) acc[j] = (f32x4){0.f,0.f,0.f,0.f};
  #pragma unroll
  for (int j = 0; j < 4; j++){
    #pragma unroll
    for (int ks = 0; ks < 4; ks++){
      int r = j*16 + l15;
      bf16x8 wf = *(const bf16x8*)&sHT[r*128 + ((ks*32 + lhi*8) ^ kx(r))];
      acc[j] = __builtin_amdgcn_mfma_f32_16x16x32_bf16(af[ks], wf, acc[j], 0, 0, 0);
    }
  }
  #pragma unroll
  for (int j = 0; j < 4; j++){
    #pragma unroll
    for (int r = 0; r < 4; r++){
      int t = t0 + lhi*4 + r, p = j*16 + l15;
      size_t row = r0 + t;
      float xv = bf2f(cv[row*CONVDIM + h*HEADDIM + p]);
      float v = y[row*DINNER + h*HEADDIM + p] + e_sh[t]*acc[j][r] + Dh*xv;
      yg[row*DINNER + h*HEADDIM + p] = f2bf(v);
    }
  }
}

// ---------------- gate (silu(z)) + rmsnorm, all bf16, in place on yg ----------------
__global__ void gate_norm_kernel(unsigned short* __restrict__ ygf, unsigned short* __restrict__ ygb,
                                 const unsigned short* __restrict__ z16f, const unsigned short* __restrict__ z16b,
                                 const float* __restrict__ gwf, const float* __restrict__ gwb){
  __shared__ float red[4];
  int row = blockIdx.x; int dir = blockIdx.y;
  int tid = threadIdx.x;
  unsigned short* yg = (dir ? ygb : ygf) + (size_t)row*DINNER;
  const unsigned short* z = (dir ? z16b : z16f) + (size_t)row*DINNER;
  const float* gw = dir ? gwb : gwf;
  int d = tid*4;
  US4 uy, uz;
  uy.q = *(const uint2*)&yg[d];
  uz.q = *(const uint2*)&z[d];
  float v[4]; float ss = 0.f;
  #pragma unroll
  for (int k = 0; k < 4; k++){
    float val = bf2f(uy.s[k]) * siluf(bf2f(uz.s[k]));
    v[k] = val; ss += val*val;
  }
  ss = blockReduceSum256(ss, red);   // __syncthreads inside: reads precede writes
  float scale = rsqrtf(ss*(1.f/DINNER) + 1e-5f);
  float4 w4 = *(const float4*)&gw[d];
  US4 o;
  o.s[0] = f2bf(v[0]*scale*w4.x);
  o.s[1] = f2bf(v[1]*scale*w4.y);
  o.s[2] = f2bf(v[2]*scale*w4.z);
  o.s[3] = f2bf(v[3]*scale*w4.w);
  *(uint2*)&yg[d] = o.q;
}

extern "C" void kernel_launch(void* const* d_in, const int* in_sizes, int n_in,
                              void* d_out, int out_size, void* d_ws, size_t ws_size,
                              hipStream_t stream) {
  const float* x      = (const float*)d_in[0];
  const float* norm_w = (const float*)d_in[1];
  const float* op_w   = (const float*)d_in[2];
  const float* op_b   = (const float*)d_in[3];
  const float* f_in_w    = (const float*)d_in[4];
  const float* f_conv_w  = (const float*)d_in[5];
  const float* f_conv_b  = (const float*)d_in[6];
  const float* f_dt_bias = (const float*)d_in[7];
  const float* f_A_log   = (const float*)d_in[8];
  const float* f_D       = (const float*)d_in[9];
  const float* f_gnorm_w = (const float*)d_in[10];
  const float* f_outp_w  = (const float*)d_in[11];
  const float* b_in_w    = (const float*)d_in[12];
  const float* b_conv_w  = (const float*)d_in[13];
  const float* b_conv_b  = (const float*)d_in[14];
  const float* b_dt_bias = (const float*)d_in[15];
  const float* b_A_log   = (const float*)d_in[16];
  const float* b_D       = (const float*)d_in[17];
  const float* b_gnorm_w = (const float*)d_in[18];
  const float* b_outp_w  = (const float*)d_in[19];
  float* out = (float*)d_out;

  float* ws = (float*)d_ws;
  size_t off = 0;
  unsigned short* u16f = (unsigned short*)(ws + off);
  unsigned short* u16b = u16f + (size_t)ROWS*DHALF;      off += (size_t)ROWS*DHALF;
  unsigned short* z16f = (unsigned short*)(ws + off);    off += (size_t)ROWS*DINNER/2;
  unsigned short* z16b = (unsigned short*)(ws + off);    off += (size_t)ROWS*DINNER/2;
  unsigned short* xbc16f = (unsigned short*)(ws + off);  off += (size_t)ROWS*CONVDIM/2;
  unsigned short* xbc16b = (unsigned short*)(ws + off);  off += (size_t)ROWS*CONVDIM/2;
  float* draw_f = ws + off; off += (size_t)ROWS*NHEADS;
  float* draw_b = ws + off; off += (size_t)ROWS*NHEADS;
  unsigned short* cv16f = (unsigned short*)(ws + off); off += (size_t)ROWS*CONVDIM/2;
  unsigned short* cv16b = (unsigned short*)(ws + off); off += (size_t)ROWS*CONVDIM/2;
  float* dt_f = ws + off; off += (size_t)ROWS*NHEADS;
  float* dt_b = ws + off; off += (size_t)ROWS*NHEADS;
  float* y_f  = ws + off; off += (size_t)ROWS*DINNER;
  float* y_b  = ws + off; off += (size_t)ROWS*DINNER;
  unsigned short* yg16f = (unsigned short*)(ws + off); off += (size_t)ROWS*DINNER/2;
  unsigned short* yg16b = (unsigned short*)(ws + off); off += (size_t)ROWS*DINNER/2;
  float* acs  = ws + off; off += (size_t)64*L_SEQ;
  float* G    = ws + off; off += (size_t)128*QCH*QCH;
  unsigned short* S16f = (unsigned short*)(ws + off); off += (size_t)32*NCH*8192/2;
  unsigned short* S16b = (unsigned short*)(ws + off); off += (size_t)32*NCH*8192/2;
  unsigned short* hin16 = (unsigned short*)(ws + off); off += (size_t)64*NCH*8192/2;
  unsigned short* w16_fin  = (unsigned short*)(ws + off); off += (size_t)NPADIN*DHALF/2;
  unsigned short* w16_bin  = (unsigned short*)(ws + off); off += (size_t)NPADIN*DHALF/2;
  unsigned short* w16_fout = (unsigned short*)(ws + off); off += (size_t)DHALF*DINNER/2;
  unsigned short* w16_bout = (unsigned short*)(ws + off); off += (size_t)DHALF*DINNER/2;
  unsigned short* w16_op   = (unsigned short*)(ws + off); off += (size_t)DMODEL*DMODEL/2;
  // cat (bf16 [ROWS][1024]) overlays z16f+z16b region (dead after gate_norm)
  unsigned short* cat16 = z16f;

  // 1. rmsnorm + split (bf16, backward pre-flipped)
  rmsnorm_split_kernel<<<ROWS, 256, 0, stream>>>(x, norm_w, u16f, u16b);
  // 2. weight conversions (single launch, x4)
  {
    const int TOT = 2*NPADIN*DHALF + 2*DHALF*DINNER + DMODEL*DMODEL;
    wconv_all_kernel<<<(TOT/4+255)/256, 256, 0, stream>>>(
        f_in_w, b_in_w, f_outp_w, b_outp_w, op_w,
        w16_fin, w16_bin, w16_fout, w16_bout, w16_op);
  }
  // 3. in-proj GEMM, both dirs in one launch; 3-way split epilogue (TM=128)
  gemm_bf16_t<128><<<dim3(NPADIN/128, ROWS/128, 2), 256, 0, stream>>>(
      u16f, u16b, DHALF, w16_fin, w16_bin,
      nullptr, 0, nullptr, nullptr,
      z16f, z16b, DINNER,
      xbc16f, xbc16b, DINNER, CONVDIM,
      draw_f, draw_b, DINNER+CONVDIM, NHEADS,
      0, 0,
      ROWS, DINPROJ, DHALF);
  // 4. conv + silu (bf16 in/out, both dirs per block)
  conv_silu_kernel<<<ROWS, 320, 0, stream>>>(
      xbc16f, xbc16b, f_conv_w, f_conv_b, b_conv_w, b_conv_b, cv16f, cv16b);
  // 5. dt softplus + chunked cumsum
  dtcum_kernel<<<512, 256, 0, stream>>>(
      draw_f, draw_b, f_dt_bias, f_A_log, b_dt_bias, b_A_log, dt_f, dt_b, acs);
  // 6. SSD: G, intra(Y+S), chunk recurrence, inter (-> bf16 yg)
  gemm_g_kernel<<<dim3(32, 4), 256, 0, stream>>>(cv16f, cv16b, G);
  intra_kernel<<<dim3(32, 64), 256, 0, stream>>>(cv16f, cv16b, dt_f, dt_b, acs, G,
                                                 y_f, y_b, S16f, S16b);
  chunkscan_kernel<<<1024, 256, 0, stream>>>(S16f, S16b, acs, hin16);
  inter_kernel<<<dim3(32, 64), 256, 0, stream>>>(cv16f, cv16b, acs, hin16, f_D, b_D,
                                                 y_f, y_b, yg16f, yg16b);
  // 7. gate + rmsnorm (all bf16, in place on yg)
  gate_norm_kernel<<<dim3(ROWS, 2), 256, 0, stream>>>(
      yg16f, yg16b, z16f, z16b, f_gnorm_w, b_gnorm_w);
  // 8. out-proj GEMM, both dirs -> cat16 (dir1 time-flipped, coff=512); TM=64 -> 512 wgs
  gemm_bf16_t<64><<<dim3(DHALF/128, ROWS/64, 2), 256, 0, stream>>>(
      yg16f, yg16b, DINNER, w16_fout, w16_bout,
      nullptr, 0, nullptr, nullptr,
      cat16, cat16, DMODEL,
      nullptr, nullptr, 1<<30, 0,
      nullptr, nullptr, 1<<30, 0,
      DHALF, 1,
      ROWS, DHALF, DINNER);
  // 9. final projection + bias + residual (fp32 out); TM=64 -> 512 wgs
  gemm_bf16_t<64><<<dim3(DMODEL/128, ROWS/64, 1), 256, 0, stream>>>(
      cat16, nullptr, DMODEL, w16_op, nullptr,
      out, DMODEL, op_b, x,
      nullptr, nullptr, 0,
      nullptr, nullptr, 1<<30, 0,
      nullptr, nullptr, 1<<30, 0,
      0, 0,
      ROWS, DMODEL, DMODEL);
}

// Round 10
// 215.836 us; speedup vs baseline: 9.4975x; 1.0325x over previous
//
#include <hip/hip_runtime.h>
#include <math.h>

#define L_SEQ   2048
#define NBATCH  2
#define DMODEL  1024
#define DHALF   512
#define DINNER  1024
#define DSTATE  128
#define NHEADS  16
#define HEADDIM 64
#define CONVDIM 1280
#define DINPROJ 2320
#define ROWS    4096   /* NBATCH * L_SEQ */
#define NPADIN  2432   /* DINPROJ padded to multiple of 128 */

#define QCH     64               /* SSD chunk length */
#define NCH     (L_SEQ / QCH)    /* 32 chunks */

typedef __attribute__((ext_vector_type(8))) short bf16x8;
typedef __attribute__((ext_vector_type(4))) float f32x4;

union US8 { uint4 q; unsigned short s[8]; };
union US4 { uint2 q; unsigned short s[4]; };

__device__ __forceinline__ float siluf(float v){ return v / (1.f + expf(-v)); }
__device__ __forceinline__ float softplusf(float v){ return v > 20.f ? v : log1pf(expf(v)); }
__device__ __forceinline__ unsigned short f2bf(float f){
  union { float f; unsigned u; } x; x.f = f;
  unsigned r = (x.u + 0x7fffu + ((x.u >> 16) & 1u)) >> 16;
  return (unsigned short)r;
}
__device__ __forceinline__ float bf2f(unsigned short u){
  union { unsigned u; float f; } x; x.u = ((unsigned)u) << 16; return x.f;
}
__device__ __forceinline__ void gload16(const void* g, void* l){
  __builtin_amdgcn_global_load_lds((const __attribute__((address_space(1))) void*)g,
                                   (__attribute__((address_space(3))) void*)l, 16, 0, 0);
}
__device__ __forceinline__ int kx(int row){ return ((row ^ (row >> 3)) & 7) << 3; }
// 16B-chunk swizzle for GEMM staging: spreads fragment reads over all 8 bank-groups
__device__ __forceinline__ int sw4(int row){ return (row ^ (row >> 2)) & 3; }

__device__ __forceinline__ float blockReduceSum256(float v, float* red){
  #pragma unroll
  for (int o = 32; o > 0; o >>= 1) v += __shfl_xor(v, o);
  int wid = threadIdx.x >> 6, lane = threadIdx.x & 63;
  if (lane == 0) red[wid] = v;
  __syncthreads();
  return red[0] + red[1] + red[2] + red[3];
}

// ---------------- rmsnorm + split into bf16 u_f and (pre-flipped) u_b ----------------
__global__ void rmsnorm_split_kernel(const float* __restrict__ x, const float* __restrict__ nw,
                                     unsigned short* __restrict__ uf, unsigned short* __restrict__ ub){
  __shared__ float red[4];
  int row = blockIdx.x;                       // b*L + t
  int tid = threadIdx.x;
  float4 v4 = *(const float4*)(x + (size_t)row*DMODEL + tid*4);
  float ss = v4.x*v4.x + v4.y*v4.y + v4.z*v4.z + v4.w*v4.w;
  ss = blockReduceSum256(ss, red);
  float scale = rsqrtf(ss * (1.f/DMODEL) + 1e-5f);
  int t = row & (L_SEQ-1);
  int fliprow = (row ^ t) | (L_SEQ-1-t);
  float4 w4 = *(const float4*)(nw + tid*4);
  US4 o;
  o.s[0] = f2bf(v4.x*scale*w4.x);
  o.s[1] = f2bf(v4.y*scale*w4.y);
  o.s[2] = f2bf(v4.z*scale*w4.z);
  o.s[3] = f2bf(v4.w*scale*w4.w);
  int d = tid*4;
  if (d < DHALF) *(uint2*)&uf[(size_t)row*DHALF + d] = o.q;
  else           *(uint2*)&ub[(size_t)fliprow*DHALF + (d - DHALF)] = o.q;
}

// ---------------- all weight fp32 -> bf16 (+row pad), one launch, x4 vectorized ------
__global__ void wconv_all_kernel(const float* __restrict__ s0, const float* __restrict__ s1,
                                 const float* __restrict__ s2, const float* __restrict__ s3,
                                 const float* __restrict__ s4,
                                 unsigned short* __restrict__ d0, unsigned short* __restrict__ d1,
                                 unsigned short* __restrict__ d2, unsigned short* __restrict__ d3,
                                 unsigned short* __restrict__ d4){
  const int S01 = NPADIN*DHALF;          // kshift 9, rows DINPROJ
  const int S23 = DHALF*DINNER;
  const int S4  = DMODEL*DMODEL;
  int idx = (blockIdx.x*256 + threadIdx.x)*4;
  const float* s; unsigned short* d; int pad_rows = 0;
  if (idx < S01){ s = s0; d = d0; pad_rows = DINPROJ; }
  else if ((idx -= S01) < S01){ s = s1; d = d1; pad_rows = DINPROJ; }
  else if ((idx -= S01) < S23){ s = s2; d = d2; }
  else if ((idx -= S23) < S23){ s = s3; d = d3; }
  else if ((idx -= S23) < S4){ s = s4; d = d4; }
  else return;
  US4 o;
  if (pad_rows && (idx >> 9) >= pad_rows){
    o.s[0] = o.s[1] = o.s[2] = o.s[3] = 0;
  } else {
    float4 v = *(const float4*)&s[idx];
    o.s[0] = f2bf(v.x); o.s[1] = f2bf(v.y); o.s[2] = f2bf(v.z); o.s[3] = f2bf(v.w);
  }
  *(uint2*)&d[idx] = o.q;
}

// ---------------- bf16 MFMA GEMM: dual-dir, 3-slot pipeline, counted vmcnt ----------
// Loads stay 2 tiles in flight (never drained to 0 in the loop); raw s_barrier pairs.
// Staging chunk-swizzled (sw4) on the GLOBAL side; fragment reads apply same XOR.
template<int TM>
__global__ __launch_bounds__(256) void gemm_bf16_t(
    const unsigned short* __restrict__ A0, const unsigned short* __restrict__ A1, int lda,
    const unsigned short* __restrict__ W0, const unsigned short* __restrict__ W1,
    float* __restrict__ Cf, int ldc,
    const float* __restrict__ bias, const float* __restrict__ res,
    unsigned short* __restrict__ O0a, unsigned short* __restrict__ O0b, int ld0,
    unsigned short* __restrict__ O1a, unsigned short* __restrict__ O1b, int n1, int ld1,
    float* __restrict__ O2a, float* __restrict__ O2b, int n2, int ld2,
    int coff1, int flip1,
    int M, int Nreal, int K){
  constexpr int MI = TM/32;                // m-fragments per wave
  constexpr int P = TM/64 + 2;             // vmem instructions per stage (per wave)
  __shared__ unsigned short As[3][TM*32];
  __shared__ unsigned short Bs[3][128*32];
  // XCD-aware swizzle over flattened (z,y,x) grid
  int bid = (blockIdx.z*gridDim.y + blockIdx.y)*gridDim.x + blockIdx.x;
  int nwg = gridDim.x*gridDim.y*gridDim.z;
  int s = bid;
  if ((nwg & 7) == 0){
    int cpx = nwg >> 3;
    s = (bid & 7)*cpx + (bid >> 3);
  }
  int bx = s % gridDim.x;
  int tmp = s / gridDim.x;
  int by = tmp % gridDim.y;
  int dir = tmp / gridDim.y;

  const unsigned short* A = dir ? A1 : A0;
  const unsigned short* W = dir ? W1 : W0;
  unsigned short* O0 = dir ? O0b : O0a;
  unsigned short* O1 = dir ? O1b : O1a;
  float* O2 = dir ? O2b : O2a;
  int coff = dir ? coff1 : 0;
  int flip = dir ? flip1 : 0;

  int bm = by*TM, bn = bx*128;
  int tid = threadIdx.x;
  int lane = tid & 63;
  int wave = tid >> 6;
  int wm = (wave >> 1) * (TM/2), wn = (wave & 1) * 64;
  int l15 = lane & 15, lhi = lane >> 4;    // lhi 0..3
  f32x4 acc[MI][4];
  #pragma unroll
  for (int i = 0; i < MI; i++)
    #pragma unroll
    for (int j = 0; j < 4; j++)
      acc[i][j] = (f32x4){0.f,0.f,0.f,0.f};

  auto stage = [&](int sl, int k0){
    #pragma unroll
    for (int f = tid; f < TM*4; f += 256){
      int row = f >> 2, c = (f & 3) ^ sw4(row);
      gload16(A + (size_t)(bm+row)*lda + k0 + c*8, &As[sl][f*8]);
    }
    #pragma unroll
    for (int f = tid; f < 512; f += 256){
      int row = f >> 2, c = (f & 3) ^ sw4(row);
      gload16(W + (size_t)(bn+row)*K + k0 + c*8, &Bs[sl][f*8]);
    }
  };

  int NK = K >> 5;
  stage(0, 0);
  if (NK > 1) stage(1, 32);
  int sl = 0;
  for (int it = 0; it < NK; ++it){
    if (it + 2 < NK){
      int s2 = sl + 2; if (s2 >= 3) s2 -= 3;
      stage(s2, (it + 2) << 5);
      asm volatile("s_waitcnt vmcnt(%0)" :: "n"(2*P) : "memory");
    } else if (it + 1 < NK){
      asm volatile("s_waitcnt vmcnt(%0)" :: "n"(P) : "memory");
    } else {
      asm volatile("s_waitcnt vmcnt(0)" ::: "memory");
    }
    asm volatile("s_barrier" ::: "memory");   // tile `it` fully in LDS across all waves
    bf16x8 af[MI], bfr[4];
    #pragma unroll
    for (int i = 0; i < MI; i++){
      int r = wm + i*16 + l15;
      af[i] = *(const bf16x8*)&As[sl][(r*4 + (lhi ^ sw4(r)))*8];
    }
    #pragma unroll
    for (int j = 0; j < 4; j++){
      int r = wn + j*16 + l15;
      bfr[j] = *(const bf16x8*)&Bs[sl][(r*4 + (lhi ^ sw4(r)))*8];
    }
    #pragma unroll
    for (int i = 0; i < MI; i++)
      #pragma unroll
      for (int j = 0; j < 4; j++)
        acc[i][j] = __builtin_amdgcn_mfma_f32_16x16x32_bf16(af[i], bfr[j], acc[i][j], 0, 0, 0);
    asm volatile("s_barrier" ::: "memory");   // slot sl free for restage next iter
    sl = (sl + 1 == 3) ? 0 : sl + 1;
  }
  #pragma unroll
  for (int i = 0; i < MI; i++){
    #pragma unroll
    for (int r = 0; r < 4; r++){
      int m = bm + wm + i*16 + lhi*4 + r;
      int mo = m;
      if (flip){ int t = m & (L_SEQ-1); mo = (m ^ t) | (L_SEQ-1-t); }
      #pragma unroll
      for (int j = 0; j < 4; j++){
        int n = bn + wn + j*16 + l15;
        if (n < Nreal){
          float v = acc[i][j][r];
          if (bias) v += bias[n];
          if (res)  v += res[(size_t)mo*ldc + coff + n];
          if (Cf)            Cf[(size_t)mo*ldc + coff + n] = v;
          else if (n < n1)   O0[(size_t)mo*ld0 + coff + n] = f2bf(v);
          else if (n < n2)   O1[(size_t)mo*ld1 + (n - n1)] = f2bf(v);
          else               O2[(size_t)mo*ld2 + (n - n2)] = v;
        }
      }
    }
  }
}

// ---------------- causal depthwise conv (k=4) + silu, bf16 in/out, both dirs/block ---
__global__ void conv_silu_kernel(const unsigned short* __restrict__ xbcf, const unsigned short* __restrict__ xbcb,
                                 const float* __restrict__ cwf, const float* __restrict__ cbf,
                                 const float* __restrict__ cwb, const float* __restrict__ cbb,
                                 unsigned short* __restrict__ cvf, unsigned short* __restrict__ cvb){
  int row = blockIdx.x;
  int tid = threadIdx.x;              // 0..319: dir = tid>=160
  int dir = tid >= 160;
  int slot = tid - dir*160;
  const unsigned short* xbc = dir ? xbcb : xbcf;
  const float* cw = dir ? cwb : cwf;
  const float* cb = dir ? cbb : cbf;
  unsigned short* cv = dir ? cvb : cvf;
  int t = row & (L_SEQ-1);
  int c0 = slot*8;
  const unsigned short* base = xbc + (size_t)row*CONVDIM + c0;
  US8 u3, u2, u1, u0;
  u3.q = *(const uint4*)base;
  u2.q = (t >= 1) ? *(const uint4*)(base - CONVDIM)   : (uint4){0,0,0,0};
  u1.q = (t >= 2) ? *(const uint4*)(base - 2*CONVDIM) : (uint4){0,0,0,0};
  u0.q = (t >= 3) ? *(const uint4*)(base - 3*CONVDIM) : (uint4){0,0,0,0};
  US8 o;
  #pragma unroll
  for (int j = 0; j < 8; j++){
    float4 w = *(const float4*)&cw[(c0+j)*4];
    float v = cb[c0+j];
    v += bf2f(u3.s[j])*w.w + bf2f(u2.s[j])*w.z + bf2f(u1.s[j])*w.y + bf2f(u0.s[j])*w.x;
    o.s[j] = f2bf(siluf(v));
  }
  *(uint4*)&cv[(size_t)row*CONVDIM + c0] = o.q;
}

// ---------------- dt softplus + per-chunk inclusive cumsum of dt*A ----------------
__global__ void dtcum_kernel(const float* __restrict__ drf, const float* __restrict__ drb,
                             const float* __restrict__ dbf, const float* __restrict__ alf,
                             const float* __restrict__ dbb, const float* __restrict__ alb,
                             float* __restrict__ dtf, float* __restrict__ dtb,
                             float* __restrict__ acs){
  int tid = threadIdx.x;
  int wid = blockIdx.x*4 + (tid >> 6);      // 0..2047 = dbh*32 + c
  int tau = tid & 63;
  int c = wid & 31, dbh = wid >> 5;
  int h = dbh & 15, b = (dbh >> 4) & 1, dir = dbh >> 5;
  const float* dr = dir ? drb : drf;
  size_t row = (size_t)b*L_SEQ + c*QCH + tau;
  float raw = dr[row*NHEADS + h];
  float bias = (dir ? dbb : dbf)[h];
  float dtv = softplusf(raw + bias);
  float a = -expf((dir ? alb : alf)[h]);
  (dir ? dtb : dtf)[row*NHEADS + h] = dtv;
  float v = dtv * a;
  #pragma unroll
  for (int off = 1; off < 64; off <<= 1){
    float u = __shfl_up(v, off);
    if (tau >= off) v += u;
  }
  acs[(size_t)dbh*L_SEQ + c*QCH + tau] = v;
}

// ---------------- K_G (MFMA): G[t][s] = C[t]·B[s], per (dir,b,chunk) ----------------
__global__ __launch_bounds__(256) void gemm_g_kernel(
    const unsigned short* __restrict__ cvf, const unsigned short* __restrict__ cvb,
    float* __restrict__ G){
  int c = blockIdx.x, db = blockIdx.y;
  int b = db & 1, dir = db >> 1;
  const unsigned short* cv = dir ? cvb : cvf;
  float* Gp = G + ((size_t)(db*32 + c))*4096;
  int tid = threadIdx.x, lane = tid & 63, w = tid >> 6;
  int l15 = lane & 15, lhi = lane >> 4;
  __shared__ unsigned short sB[64*128];
  __shared__ unsigned short sC[64*128];
  size_t r0 = (size_t)b*L_SEQ + (size_t)c*QCH;
  #pragma unroll
  for (int k = 0; k < 4; k++){
    int cid = k*256 + tid;
    int row = cid >> 4, slot = cid & 15;
    US8 ub, uc;
    ub.q = *(const uint4*)&cv[(r0+row)*CONVDIM + DINNER + slot*8];
    uc.q = *(const uint4*)&cv[(r0+row)*CONVDIM + DINNER + DSTATE + slot*8];
    *(uint4*)&sB[row*128 + (slot*8 ^ kx(row))] = ub.q;
    *(uint4*)&sC[row*128 + (slot*8 ^ kx(row))] = uc.q;
  }
  __syncthreads();
  int t0 = w*16;
  bf16x8 af[4];
  #pragma unroll
  for (int ks = 0; ks < 4; ks++){
    int r = t0 + l15;
    af[ks] = *(const bf16x8*)&sC[r*128 + ((ks*32 + lhi*8) ^ kx(r))];
  }
  f32x4 acc[4];
  #pragma unroll
  for (int j = 0; j < 4; j++) acc[j] = (f32x4){0.f,0.f,0.f,0.f};
  #pragma unroll
  for (int j = 0; j < 4; j++){
    #pragma unroll
    for (int ks = 0; ks < 4; ks++){
      int r = j*16 + l15;
      bf16x8 wf = *(const bf16x8*)&sB[r*128 + ((ks*32 + lhi*8) ^ kx(r))];
      acc[j] = __builtin_amdgcn_mfma_f32_16x16x32_bf16(af[ks], wf, acc[j], 0, 0, 0);
    }
  }
  #pragma unroll
  for (int j = 0; j < 4; j++)
    #pragma unroll
    for (int r = 0; r < 4; r++)
      Gp[(t0 + lhi*4 + r)*64 + j*16 + l15] = acc[j][r];
}

// ---------------- K_Y (MFMA): intra-chunk Y + chunk-state S^T, per (dir,b,h,chunk) ----
__global__ __launch_bounds__(256) void intra_kernel(
    const unsigned short* __restrict__ cvf, const unsigned short* __restrict__ cvb,
    const float* __restrict__ dtf, const float* __restrict__ dtb,
    const float* __restrict__ acs, const float* __restrict__ G,
    float* __restrict__ yf, float* __restrict__ yb,
    unsigned short* __restrict__ S16f, unsigned short* __restrict__ S16b){
  int c = blockIdx.x, dbh = blockIdx.y;
  int h = dbh & 15, b = (dbh >> 4) & 1, dir = dbh >> 5;
  const unsigned short* cv = dir ? cvb : cvf;
  const float* dtp = dir ? dtb : dtf;
  float* y = dir ? yb : yf;
  unsigned short* S16 = dir ? S16b : S16f;
  const float* Gp = G + ((size_t)((dir*2+b)*32 + c))*4096;
  int tid = threadIdx.x, lane = tid & 63, w = tid >> 6;
  int l15 = lane & 15, lhi = lane >> 4;

  __shared__ unsigned short sGh [64*64];   // Gh[t][s]  (A for Y)
  __shared__ unsigned short sDxT[64*64];   // dxT[p][s] (W for Y, A for S^T)
  __shared__ unsigned short sBwT[128*64];  // BwT[n][s] (W for S^T)
  __shared__ float a_sh[QCH], dt_sh[QCH];

  size_t r0 = (size_t)b*L_SEQ + (size_t)c*QCH;
  if (tid < 64){
    a_sh[tid]  = acs[(size_t)dbh*L_SEQ + c*QCH + tid];
    dt_sh[tid] = dtp[(r0 + tid)*NHEADS + h];
  }
  __syncthreads();
  float a63 = a_sh[63];
  // dxT[p][s] = dt[s]*x[s][p], transposed scalar writes (swizzled)
  #pragma unroll
  for (int k = 0; k < 2; k++){
    int cid = k*256 + tid;
    int s = cid >> 3, p0 = (cid & 7)*8;
    US8 u; u.q = *(const uint4*)&cv[(r0+s)*CONVDIM + h*HEADDIM + p0];
    float d = dt_sh[s];
    #pragma unroll
    for (int j = 0; j < 8; j++){
      int p = p0 + j;
      sDxT[p*64 + (s ^ kx(p))] = f2bf(bf2f(u.s[j]) * d);
    }
  }
  // BwT[n][s] = exp(a63-a[s])*B[s][n]
  #pragma unroll
  for (int k = 0; k < 4; k++){
    int cid = k*256 + tid;
    int s = cid >> 4, n0 = (cid & 15)*8;
    US8 u; u.q = *(const uint4*)&cv[(r0+s)*CONVDIM + DINNER + n0];
    float wv = expf(a63 - a_sh[s]);
    #pragma unroll
    for (int j = 0; j < 8; j++){
      int n = n0 + j;
      sBwT[n*64 + (s ^ kx(n))] = f2bf(bf2f(u.s[j]) * wv);
    }
  }
  // Gh[t][s] = (s<=t) ? G[t][s]*exp(a[t]-a[s]) : 0, bf16
  #pragma unroll
  for (int k = 0; k < 4; k++){
    int f = k*256 + tid;
    int t = f >> 4, s0 = (f & 15)*4;
    float4 g = *(const float4*)&Gp[t*64 + s0];
    float at = a_sh[t];
    float v0 = (s0+0 <= t) ? g.x*expf(at - a_sh[s0+0]) : 0.f;
    float v1 = (s0+1 <= t) ? g.y*expf(at - a_sh[s0+1]) : 0.f;
    float v2 = (s0+2 <= t) ? g.z*expf(at - a_sh[s0+2]) : 0.f;
    float v3 = (s0+3 <= t) ? g.w*expf(at - a_sh[s0+3]) : 0.f;
    int addr = t*64 + (s0 ^ kx(t));
    *(unsigned*)&sGh[addr]     = (unsigned)f2bf(v0) | ((unsigned)f2bf(v1) << 16);
    *(unsigned*)&sGh[addr + 2] = (unsigned)f2bf(v2) | ((unsigned)f2bf(v3) << 16);
  }
  __syncthreads();

  int t0 = w*16;                     // Y t-tile; also S^T p-tile
  bf16x8 aY[2], aS[2];
  #pragma unroll
  for (int ks = 0; ks < 2; ks++){
    int rg = t0 + l15;
    aY[ks] = *(const bf16x8*)&sGh [rg*64 + ((ks*32 + lhi*8) ^ kx(rg))];
    aS[ks] = *(const bf16x8*)&sDxT[rg*64 + ((ks*32 + lhi*8) ^ kx(rg))];
  }
  // Y[t][p] = sum_s Gh[t][s] * dxT[p][s]
  f32x4 accY[4];
  #pragma unroll
  for (int j = 0; j < 4; j++) accY[j] = (f32x4){0.f,0.f,0.f,0.f};
  #pragma unroll
  for (int j = 0; j < 4; j++){
    #pragma unroll
    for (int ks = 0; ks < 2; ks++){
      int rp = j*16 + l15;
      bf16x8 wf = *(const bf16x8*)&sDxT[rp*64 + ((ks*32 + lhi*8) ^ kx(rp))];
      accY[j] = __builtin_amdgcn_mfma_f32_16x16x32_bf16(aY[ks], wf, accY[j], 0, 0, 0);
    }
  }
  // S^T[p][n] = sum_s dxT[p][s] * BwT[n][s]
  f32x4 accS[8];
  #pragma unroll
  for (int j = 0; j < 8; j++) accS[j] = (f32x4){0.f,0.f,0.f,0.f};
  #pragma unroll
  for (int j = 0; j < 8; j++){
    #pragma unroll
    for (int ks = 0; ks < 2; ks++){
      int rn = j*16 + l15;
      bf16x8 wf = *(const bf16x8*)&sBwT[rn*64 + ((ks*32 + lhi*8) ^ kx(rn))];
      accS[j] = __builtin_amdgcn_mfma_f32_16x16x32_bf16(aS[ks], wf, accS[j], 0, 0, 0);
    }
  }
  // epilogues
  #pragma unroll
  for (int j = 0; j < 4; j++){
    #pragma unroll
    for (int r = 0; r < 4; r++){
      int t = t0 + lhi*4 + r, p = j*16 + l15;
      y[(r0 + t)*DINNER + h*HEADDIM + p] = accY[j][r];
    }
  }
  size_t sbase = ((size_t)((b*NHEADS + h)*NCH + c))*8192;
  #pragma unroll
  for (int j = 0; j < 8; j++){
    #pragma unroll
    for (int r = 0; r < 4; r++){
      int p = t0 + lhi*4 + r, n = j*16 + l15;
      S16[sbase + p*128 + n] = f2bf(accS[j][r]);
    }
  }
}

// ---------------- K_S: inter-chunk state recurrence (elementwise over [p][n]) --------
__global__ void chunkscan_kernel(const unsigned short* __restrict__ S16f,
                                 const unsigned short* __restrict__ S16b,
                                 const float* __restrict__ acs,
                                 unsigned short* __restrict__ hin16){
  __shared__ float sa[NCH];
  int tid = threadIdx.x;
  int dbh = blockIdx.x >> 4;
  int e0 = ((blockIdx.x & 15)*256 + tid)*2;
  int bh = dbh & 31, dir = dbh >> 5;
  const unsigned short* S16 = dir ? S16b : S16f;
  if (tid < NCH) sa[tid] = expf(acs[(size_t)dbh*L_SEQ + tid*QCH + 63]);
  __syncthreads();
  float h0 = 0.f, h1 = 0.f;
  #pragma unroll 8
  for (int c = 0; c < NCH; ++c){
    size_t sidx = ((size_t)(bh*NCH + c))*8192 + e0;
    size_t hidx = ((size_t)(dbh*NCH + c))*8192 + e0;
    unsigned sv = *(const unsigned*)&S16[sidx];
    unsigned hv = (unsigned)f2bf(h0) | ((unsigned)f2bf(h1) << 16);
    *(unsigned*)&hin16[hidx] = hv;
    float ea = sa[c];
    h0 = ea*h0 + bf2f((unsigned short)(sv & 0xffff));
    h1 = ea*h1 + bf2f((unsigned short)(sv >> 16));
  }
}

// ---------------- K_I (MFMA): Y = y_intra + e[t]*C·h_in + D*x -> bf16 yg -------------
__global__ __launch_bounds__(256) void inter_kernel(
    const unsigned short* __restrict__ cvf, const unsigned short* __restrict__ cvb,
    const float* __restrict__ acs, const unsigned short* __restrict__ hin16,
    const float* __restrict__ Df, const float* __restrict__ Db,
    const float* __restrict__ yf, const float* __restrict__ yb,
    unsigned short* __restrict__ ygf, unsigned short* __restrict__ ygb){
  int c = blockIdx.x, dbh = blockIdx.y;
  int h = dbh & 15, b = (dbh >> 4) & 1, dir = dbh >> 5;
  const unsigned short* cv = dir ? cvb : cvf;
  const float* y = dir ? yb : yf;
  unsigned short* yg = dir ? ygb : ygf;
  float Dh = (dir ? Db : Df)[h];
  int tid = threadIdx.x, lane = tid & 63, w = tid >> 6;
  int l15 = lane & 15, lhi = lane >> 4;
  __shared__ unsigned short sC [64*128];   // C[t][n]  (A)
  __shared__ unsigned short sHT[64*128];   // hT[p][n] (W)
  __shared__ float e_sh[QCH];
  size_t r0 = (size_t)b*L_SEQ + (size_t)c*QCH;
  size_t hbase = ((size_t)(dbh*NCH + c))*8192;
  if (tid < 64) e_sh[tid] = expf(acs[(size_t)dbh*L_SEQ + c*QCH + tid]);
  #pragma unroll
  for (int k = 0; k < 4; k++){
    int cid = k*256 + tid;
    int row = cid >> 4, slot = cid & 15;
    US8 uc, uh;
    uc.q = *(const uint4*)&cv[(r0+row)*CONVDIM + DINNER + DSTATE + slot*8];
    uh.q = *(const uint4*)&hin16[hbase + cid*8];
    *(uint4*)&sC [row*128 + (slot*8 ^ kx(row))] = uc.q;
    *(uint4*)&sHT[row*128 + (slot*8 ^ kx(row))] = uh.q;
  }
  __syncthreads();
  int t0 = w*16;
  bf16x8 af[4];
  #pragma unroll
  for (int ks = 0; ks < 4; ks++){
    int r = t0 + l15;
    af[ks] = *(const bf16x8*)&sC[r*128 + ((ks*32 + lhi*8) ^ kx(r))];
  }
  f32x4 acc[4];
  #pragma unroll
  for (int j = 0; j < 4; j++) acc[j] = (f32x4){0.f,0.f,0.f,0.f};
  #pragma unroll
  for (int j = 0; j < 4; j++){
    #pragma unroll
    for (int ks = 0; ks < 4; ks++){
      int r = j*16 + l15;
      bf16x8 wf = *(const bf16x8*)&sHT[r*128 + ((ks*32 + lhi*8) ^ kx(r))];
      acc[j] = __builtin_amdgcn_mfma_f32_16x16x32_bf16(af[ks], wf, acc[j], 0, 0, 0);
    }
  }
  #pragma unroll
  for (int j = 0; j < 4; j++){
    #pragma unroll
    for (int r = 0; r < 4; r++){
      int t = t0 + lhi*4 + r, p = j*16 + l15;
      size_t row = r0 + t;
      float xv = bf2f(cv[row*CONVDIM + h*HEADDIM + p]);
      float v = y[row*DINNER + h*HEADDIM + p] + e_sh[t]*acc[j][r] + Dh*xv;
      yg[row*DINNER + h*HEADDIM + p] = f2bf(v);
    }
  }
}

// ---------------- gate (silu(z)) + rmsnorm, all bf16, in place on yg ----------------
__global__ void gate_norm_kernel(unsigned short* __restrict__ ygf, unsigned short* __restrict__ ygb,
                                 const unsigned short* __restrict__ z16f, const unsigned short* __restrict__ z16b,
                                 const float* __restrict__ gwf, const float* __restrict__ gwb){
  __shared__ float red[4];
  int row = blockIdx.x; int dir = blockIdx.y;
  int tid = threadIdx.x;
  unsigned short* yg = (dir ? ygb : ygf) + (size_t)row*DINNER;
  const unsigned short* z = (dir ? z16b : z16f) + (size_t)row*DINNER;
  const float* gw = dir ? gwb : gwf;
  int d = tid*4;
  US4 uy, uz;
  uy.q = *(const uint2*)&yg[d];
  uz.q = *(const uint2*)&z[d];
  float v[4]; float ss = 0.f;
  #pragma unroll
  for (int k = 0; k < 4; k++){
    float val = bf2f(uy.s[k]) * siluf(bf2f(uz.s[k]));
    v[k] = val; ss += val*val;
  }
  ss = blockReduceSum256(ss, red);   // __syncthreads inside: reads precede writes
  float scale = rsqrtf(ss*(1.f/DINNER) + 1e-5f);
  float4 w4 = *(const float4*)&gw[d];
  US4 o;
  o.s[0] = f2bf(v[0]*scale*w4.x);
  o.s[1] = f2bf(v[1]*scale*w4.y);
  o.s[2] = f2bf(v[2]*scale*w4.z);
  o.s[3] = f2bf(v[3]*scale*w4.w);
  *(uint2*)&yg[d] = o.q;
}

extern "C" void kernel_launch(void* const* d_in, const int* in_sizes, int n_in,
                              void* d_out, int out_size, void* d_ws, size_t ws_size,
                              hipStream_t stream) {
  const float* x      = (const float*)d_in[0];
  const float* norm_w = (const float*)d_in[1];
  const float* op_w   = (const float*)d_in[2];
  const float* op_b   = (const float*)d_in[3];
  const float* f_in_w    = (const float*)d_in[4];
  const float* f_conv_w  = (const float*)d_in[5];
  const float* f_conv_b  = (const float*)d_in[6];
  const float* f_dt_bias = (const float*)d_in[7];
  const float* f_A_log   = (const float*)d_in[8];
  const float* f_D       = (const float*)d_in[9];
  const float* f_gnorm_w = (const float*)d_in[10];
  const float* f_outp_w  = (const float*)d_in[11];
  const float* b_in_w    = (const float*)d_in[12];
  const float* b_conv_w  = (const float*)d_in[13];
  const float* b_conv_b  = (const float*)d_in[14];
  const float* b_dt_bias = (const float*)d_in[15];
  const float* b_A_log   = (const float*)d_in[16];
  const float* b_D       = (const float*)d_in[17];
  const float* b_gnorm_w = (const float*)d_in[18];
  const float* b_outp_w  = (const float*)d_in[19];
  float* out = (float*)d_out;

  float* ws = (float*)d_ws;
  size_t off = 0;
  unsigned short* u16f = (unsigned short*)(ws + off);
  unsigned short* u16b = u16f + (size_t)ROWS*DHALF;      off += (size_t)ROWS*DHALF;
  unsigned short* z16f = (unsigned short*)(ws + off);    off += (size_t)ROWS*DINNER/2;
  unsigned short* z16b = (unsigned short*)(ws + off);    off += (size_t)ROWS*DINNER/2;
  unsigned short* xbc16f = (unsigned short*)(ws + off);  off += (size_t)ROWS*CONVDIM/2;
  unsigned short* xbc16b = (unsigned short*)(ws + off);  off += (size_t)ROWS*CONVDIM/2;
  float* draw_f = ws + off; off += (size_t)ROWS*NHEADS;
  float* draw_b = ws + off; off += (size_t)ROWS*NHEADS;
  unsigned short* cv16f = (unsigned short*)(ws + off); off += (size_t)ROWS*CONVDIM/2;
  unsigned short* cv16b = (unsigned short*)(ws + off); off += (size_t)ROWS*CONVDIM/2;
  float* dt_f = ws + off; off += (size_t)ROWS*NHEADS;
  float* dt_b = ws + off; off += (size_t)ROWS*NHEADS;
  float* y_f  = ws + off; off += (size_t)ROWS*DINNER;
  float* y_b  = ws + off; off += (size_t)ROWS*DINNER;
  unsigned short* yg16f = (unsigned short*)(ws + off); off += (size_t)ROWS*DINNER/2;
  unsigned short* yg16b = (unsigned short*)(ws + off); off += (size_t)ROWS*DINNER/2;
  float* acs  = ws + off; off += (size_t)64*L_SEQ;
  float* G    = ws + off; off += (size_t)128*QCH*QCH;
  unsigned short* S16f = (unsigned short*)(ws + off); off += (size_t)32*NCH*8192/2;
  unsigned short* S16b = (unsigned short*)(ws + off); off += (size_t)32*NCH*8192/2;
  unsigned short* hin16 = (unsigned short*)(ws + off); off += (size_t)64*NCH*8192/2;
  unsigned short* w16_fin  = (unsigned short*)(ws + off); off += (size_t)NPADIN*DHALF/2;
  unsigned short* w16_bin  = (unsigned short*)(ws + off); off += (size_t)NPADIN*DHALF/2;
  unsigned short* w16_fout = (unsigned short*)(ws + off); off += (size_t)DHALF*DINNER/2;
  unsigned short* w16_bout = (unsigned short*)(ws + off); off += (size_t)DHALF*DINNER/2;
  unsigned short* w16_op   = (unsigned short*)(ws + off); off += (size_t)DMODEL*DMODEL/2;
  // cat (bf16 [ROWS][1024]) overlays z16f+z16b region (dead after gate_norm)
  unsigned short* cat16 = z16f;

  // 1. rmsnorm + split (bf16, backward pre-flipped)
  rmsnorm_split_kernel<<<ROWS, 256, 0, stream>>>(x, norm_w, u16f, u16b);
  // 2. weight conversions (single launch, x4)
  {
    const int TOT = 2*NPADIN*DHALF + 2*DHALF*DINNER + DMODEL*DMODEL;
    wconv_all_kernel<<<(TOT/4+255)/256, 256, 0, stream>>>(
        f_in_w, b_in_w, f_outp_w, b_outp_w, op_w,
        w16_fin, w16_bin, w16_fout, w16_bout, w16_op);
  }
  // 3. in-proj GEMM, both dirs in one launch; 3-way split epilogue (TM=128)
  gemm_bf16_t<128><<<dim3(NPADIN/128, ROWS/128, 2), 256, 0, stream>>>(
      u16f, u16b, DHALF, w16_fin, w16_bin,
      nullptr, 0, nullptr, nullptr,
      z16f, z16b, DINNER,
      xbc16f, xbc16b, DINNER, CONVDIM,
      draw_f, draw_b, DINNER+CONVDIM, NHEADS,
      0, 0,
      ROWS, DINPROJ, DHALF);
  // 4. conv + silu (bf16 in/out, both dirs per block)
  conv_silu_kernel<<<ROWS, 320, 0, stream>>>(
      xbc16f, xbc16b, f_conv_w, f_conv_b, b_conv_w, b_conv_b, cv16f, cv16b);
  // 5. dt softplus + chunked cumsum
  dtcum_kernel<<<512, 256, 0, stream>>>(
      draw_f, draw_b, f_dt_bias, f_A_log, b_dt_bias, b_A_log, dt_f, dt_b, acs);
  // 6. SSD: G, intra(Y+S), chunk recurrence, inter (-> bf16 yg)
  gemm_g_kernel<<<dim3(32, 4), 256, 0, stream>>>(cv16f, cv16b, G);
  intra_kernel<<<dim3(32, 64), 256, 0, stream>>>(cv16f, cv16b, dt_f, dt_b, acs, G,
                                                 y_f, y_b, S16f, S16b);
  chunkscan_kernel<<<1024, 256, 0, stream>>>(S16f, S16b, acs, hin16);
  inter_kernel<<<dim3(32, 64), 256, 0, stream>>>(cv16f, cv16b, acs, hin16, f_D, b_D,
                                                 y_f, y_b, yg16f, yg16b);
  // 7. gate + rmsnorm (all bf16, in place on yg)
  gate_norm_kernel<<<dim3(ROWS, 2), 256, 0, stream>>>(
      yg16f, yg16b, z16f, z16b, f_gnorm_w, b_gnorm_w);
  // 8. out-proj GEMM, both dirs -> cat16 (dir1 time-flipped, coff=512); TM=64 -> 512 wgs
  gemm_bf16_t<64><<<dim3(DHALF/128, ROWS/64, 2), 256, 0, stream>>>(
      yg16f, yg16b, DINNER, w16_fout, w16_bout,
      nullptr, 0, nullptr, nullptr,
      cat16, cat16, DMODEL,
      nullptr, nullptr, 1<<30, 0,
      nullptr, nullptr, 1<<30, 0,
      DHALF, 1,
      ROWS, DHALF, DINNER);
  // 9. final projection + bias + residual (fp32 out); TM=64 -> 512 wgs
  gemm_bf16_t<64><<<dim3(DMODEL/128, ROWS/64, 1), 256, 0, stream>>>(
      cat16, nullptr, DMODEL, w16_op, nullptr,
      out, DMODEL, op_b, x,
      nullptr, nullptr, 0,
      nullptr, nullptr, 1<<30, 0,
      nullptr, nullptr, 1<<30, 0,
      0, 0,
      ROWS, DMODEL, DMODEL);
}

// Round 11
// 213.867 us; speedup vs baseline: 9.5849x; 1.0092x over previous
//
#include <hip/hip_runtime.h>
#include <math.h>

#define L_SEQ   2048
#define NBATCH  2
#define DMODEL  1024
#define DHALF   512
#define DINNER  1024
#define DSTATE  128
#define NHEADS  16
#define HEADDIM 64
#define CONVDIM 1280
#define DINPROJ 2320
#define ROWS    4096   /* NBATCH * L_SEQ */
#define NPADIN  2432   /* DINPROJ padded to multiple of 128 */

#define QCH     64               /* SSD chunk length */
#define NCH     (L_SEQ / QCH)    /* 32 chunks */

typedef __attribute__((ext_vector_type(8))) short bf16x8;
typedef __attribute__((ext_vector_type(4))) float f32x4;

union US8 { uint4 q; unsigned short s[8]; };
union US4 { uint2 q; unsigned short s[4]; };

__device__ __forceinline__ float siluf(float v){ return v / (1.f + expf(-v)); }
__device__ __forceinline__ float softplusf(float v){ return v > 20.f ? v : log1pf(expf(v)); }
__device__ __forceinline__ unsigned short f2bf(float f){
  union { float f; unsigned u; } x; x.f = f;
  unsigned r = (x.u + 0x7fffu + ((x.u >> 16) & 1u)) >> 16;
  return (unsigned short)r;
}
__device__ __forceinline__ float bf2f(unsigned short u){
  union { unsigned u; float f; } x; x.u = ((unsigned)u) << 16; return x.f;
}
__device__ __forceinline__ void gload16(const void* g, void* l){
  __builtin_amdgcn_global_load_lds((const __attribute__((address_space(1))) void*)g,
                                   (__attribute__((address_space(3))) void*)l, 16, 0, 0);
}
__device__ __forceinline__ int kx(int row){ return ((row ^ (row >> 3)) & 7) << 3; }
__device__ __forceinline__ int sw4(int row){ return (row ^ (row >> 2)) & 3; }

__device__ __forceinline__ float blockReduceSum256(float v, float* red){
  #pragma unroll
  for (int o = 32; o > 0; o >>= 1) v += __shfl_xor(v, o);
  int wid = threadIdx.x >> 6, lane = threadIdx.x & 63;
  if (lane == 0) red[wid] = v;
  __syncthreads();
  return red[0] + red[1] + red[2] + red[3];
}

// ---------------- merged prep: rmsnorm+split (blocks < ROWS) | weight conv (rest) ----
__global__ void prep_kernel(const float* __restrict__ x, const float* __restrict__ nw,
                            unsigned short* __restrict__ uf, unsigned short* __restrict__ ub,
                            const float* __restrict__ s0, const float* __restrict__ s1,
                            const float* __restrict__ s2, const float* __restrict__ s3,
                            const float* __restrict__ s4,
                            unsigned short* __restrict__ d0, unsigned short* __restrict__ d1,
                            unsigned short* __restrict__ d2, unsigned short* __restrict__ d3,
                            unsigned short* __restrict__ d4){
  __shared__ float red[4];
  int tid = threadIdx.x;
  if (blockIdx.x < ROWS){
    int row = blockIdx.x;
    float4 v4 = *(const float4*)(x + (size_t)row*DMODEL + tid*4);
    float ss = v4.x*v4.x + v4.y*v4.y + v4.z*v4.z + v4.w*v4.w;
    ss = blockReduceSum256(ss, red);
    float scale = rsqrtf(ss * (1.f/DMODEL) + 1e-5f);
    int t = row & (L_SEQ-1);
    int fliprow = (row ^ t) | (L_SEQ-1-t);
    float4 w4 = *(const float4*)(nw + tid*4);
    US4 o;
    o.s[0] = f2bf(v4.x*scale*w4.x);
    o.s[1] = f2bf(v4.y*scale*w4.y);
    o.s[2] = f2bf(v4.z*scale*w4.z);
    o.s[3] = f2bf(v4.w*scale*w4.w);
    int d = tid*4;
    if (d < DHALF) *(uint2*)&uf[(size_t)row*DHALF + d] = o.q;
    else           *(uint2*)&ub[(size_t)fliprow*DHALF + (d - DHALF)] = o.q;
    return;
  }
  const int S01 = NPADIN*DHALF;
  const int S23 = DHALF*DINNER;
  const int S4  = DMODEL*DMODEL;
  int idx = ((blockIdx.x - ROWS)*256 + tid)*4;
  const float* s; unsigned short* d; int pad_rows = 0;
  if (idx < S01){ s = s0; d = d0; pad_rows = DINPROJ; }
  else if ((idx -= S01) < S01){ s = s1; d = d1; pad_rows = DINPROJ; }
  else if ((idx -= S01) < S23){ s = s2; d = d2; }
  else if ((idx -= S23) < S23){ s = s3; d = d3; }
  else if ((idx -= S23) < S4){ s = s4; d = d4; }
  else return;
  US4 o;
  if (pad_rows && (idx >> 9) >= pad_rows){
    o.s[0] = o.s[1] = o.s[2] = o.s[3] = 0;
  } else {
    float4 v = *(const float4*)&s[idx];
    o.s[0] = f2bf(v.x); o.s[1] = f2bf(v.y); o.s[2] = f2bf(v.z); o.s[3] = f2bf(v.w);
  }
  *(uint2*)&d[idx] = o.q;
}

// ---------------- bf16 MFMA GEMM: dual-dir, 3-slot counted-vmcnt, hoisted addressing --
template<int TM>
__global__ __launch_bounds__(256) void gemm_bf16_t(
    const unsigned short* __restrict__ A0, const unsigned short* __restrict__ A1, int lda,
    const unsigned short* __restrict__ W0, const unsigned short* __restrict__ W1,
    float* __restrict__ Cf, int ldc,
    const float* __restrict__ bias, const float* __restrict__ res,
    unsigned short* __restrict__ O0a, unsigned short* __restrict__ O0b, int ld0,
    unsigned short* __restrict__ O1a, unsigned short* __restrict__ O1b, int n1, int ld1,
    float* __restrict__ O2a, float* __restrict__ O2b, int n2, int ld2,
    int coff1, int flip1,
    int M, int Nreal, int K){
  constexpr int MI = TM/32;                // m-fragments per wave
  constexpr int QA = TM/64;                // A vmem insts per thread per stage
  constexpr int P = QA + 2;                // total vmem insts per stage
  __shared__ unsigned short As[3][TM*32];
  __shared__ unsigned short Bs[3][128*32];
  // XCD-aware swizzle over flattened (z,y,x) grid
  int bid = (blockIdx.z*gridDim.y + blockIdx.y)*gridDim.x + blockIdx.x;
  int nwg = gridDim.x*gridDim.y*gridDim.z;
  int s = bid;
  if ((nwg & 7) == 0){
    int cpx = nwg >> 3;
    s = (bid & 7)*cpx + (bid >> 3);
  }
  int bx = s % gridDim.x;
  int tmp = s / gridDim.x;
  int by = tmp % gridDim.y;
  int dir = tmp / gridDim.y;

  const unsigned short* A = dir ? A1 : A0;
  const unsigned short* W = dir ? W1 : W0;
  unsigned short* O0 = dir ? O0b : O0a;
  unsigned short* O1 = dir ? O1b : O1a;
  float* O2 = dir ? O2b : O2a;
  int coff = dir ? coff1 : 0;
  int flip = dir ? flip1 : 0;

  int bm = by*TM, bn = bx*128;
  int tid = threadIdx.x;
  int lane = tid & 63;
  int wave = tid >> 6;
  int wm = (wave >> 1) * (TM/2), wn = (wave & 1) * 64;
  int l15 = lane & 15, lhi = lane >> 4;

  // hoisted staging pointers (advance via +k0 shorts) and LDS chunk indices
  const unsigned short* pA[QA]; unsigned ldsA[QA];
  #pragma unroll
  for (int q = 0; q < QA; q++){
    int row = (tid >> 2) + q*64;
    pA[q] = A + (size_t)(bm + row)*lda + ((tid & 3) ^ sw4(row))*8;
    ldsA[q] = (unsigned)(tid + q*256)*8;
  }
  const unsigned short* pW[2]; unsigned ldsW[2];
  #pragma unroll
  for (int q = 0; q < 2; q++){
    int row = (tid >> 2) + q*64;
    pW[q] = W + (size_t)(bn + row)*K + ((tid & 3) ^ sw4(row))*8;
    ldsW[q] = (unsigned)(tid + q*256)*8;
  }
  // hoisted fragment LDS offsets (shorts)
  int offA[MI], offB[4];
  #pragma unroll
  for (int i = 0; i < MI; i++){
    int r = wm + i*16 + l15;
    offA[i] = (r*4 + (lhi ^ sw4(r)))*8;
  }
  #pragma unroll
  for (int j = 0; j < 4; j++){
    int r = wn + j*16 + l15;
    offB[j] = (r*4 + (lhi ^ sw4(r)))*8;
  }

  f32x4 acc[MI][4];
  #pragma unroll
  for (int i = 0; i < MI; i++)
    #pragma unroll
    for (int j = 0; j < 4; j++)
      acc[i][j] = (f32x4){0.f,0.f,0.f,0.f};

  auto stage = [&](int sl, int k0){
    #pragma unroll
    for (int q = 0; q < QA; q++) gload16(pA[q] + k0, &As[sl][ldsA[q]]);
    #pragma unroll
    for (int q = 0; q < 2; q++)  gload16(pW[q] + k0, &Bs[sl][ldsW[q]]);
  };

  int NK = K >> 5;
  stage(0, 0);
  if (NK > 1) stage(1, 32);
  int sl = 0;
  for (int it = 0; it < NK; ++it){
    if (it + 2 < NK){
      int s2 = sl + 2; if (s2 >= 3) s2 -= 3;
      stage(s2, (it + 2) << 5);
      asm volatile("s_waitcnt vmcnt(%0)" :: "n"(2*P) : "memory");
    } else if (it + 1 < NK){
      asm volatile("s_waitcnt vmcnt(%0)" :: "n"(P) : "memory");
    } else {
      asm volatile("s_waitcnt vmcnt(0)" ::: "memory");
    }
    asm volatile("s_barrier" ::: "memory");   // tile `it` fully in LDS
    const unsigned short* as = As[sl];
    const unsigned short* bs = Bs[sl];
    bf16x8 af[MI], bfr[4];
    #pragma unroll
    for (int i = 0; i < MI; i++) af[i] = *(const bf16x8*)&as[offA[i]];
    #pragma unroll
    for (int j = 0; j < 4; j++)  bfr[j] = *(const bf16x8*)&bs[offB[j]];
    #pragma unroll
    for (int i = 0; i < MI; i++)
      #pragma unroll
      for (int j = 0; j < 4; j++)
        acc[i][j] = __builtin_amdgcn_mfma_f32_16x16x32_bf16(af[i], bfr[j], acc[i][j], 0, 0, 0);
    asm volatile("s_barrier" ::: "memory");   // slot sl free for restage
    sl = (sl + 1 == 3) ? 0 : sl + 1;
  }
  #pragma unroll
  for (int i = 0; i < MI; i++){
    #pragma unroll
    for (int r = 0; r < 4; r++){
      int m = bm + wm + i*16 + lhi*4 + r;
      int mo = m;
      if (flip){ int t = m & (L_SEQ-1); mo = (m ^ t) | (L_SEQ-1-t); }
      #pragma unroll
      for (int j = 0; j < 4; j++){
        int n = bn + wn + j*16 + l15;
        if (n < Nreal){
          float v = acc[i][j][r];
          if (bias) v += bias[n];
          if (res)  v += res[(size_t)mo*ldc + coff + n];
          if (Cf)            Cf[(size_t)mo*ldc + coff + n] = v;
          else if (n < n1)   O0[(size_t)mo*ld0 + coff + n] = f2bf(v);
          else if (n < n2)   O1[(size_t)mo*ld1 + (n - n1)] = f2bf(v);
          else               O2[(size_t)mo*ld2 + (n - n2)] = v;
        }
      }
    }
  }
}

// ---------------- causal depthwise conv (k=4) + silu, bf16 in/out, both dirs/block ---
__global__ void conv_silu_kernel(const unsigned short* __restrict__ xbcf, const unsigned short* __restrict__ xbcb,
                                 const float* __restrict__ cwf, const float* __restrict__ cbf,
                                 const float* __restrict__ cwb, const float* __restrict__ cbb,
                                 unsigned short* __restrict__ cvf, unsigned short* __restrict__ cvb){
  int row = blockIdx.x;
  int tid = threadIdx.x;              // 0..319: dir = tid>=160
  int dir = tid >= 160;
  int slot = tid - dir*160;
  const unsigned short* xbc = dir ? xbcb : xbcf;
  const float* cw = dir ? cwb : cwf;
  const float* cb = dir ? cbb : cbf;
  unsigned short* cv = dir ? cvb : cvf;
  int t = row & (L_SEQ-1);
  int c0 = slot*8;
  const unsigned short* base = xbc + (size_t)row*CONVDIM + c0;
  US8 u3, u2, u1, u0;
  u3.q = *(const uint4*)base;
  u2.q = (t >= 1) ? *(const uint4*)(base - CONVDIM)   : (uint4){0,0,0,0};
  u1.q = (t >= 2) ? *(const uint4*)(base - 2*CONVDIM) : (uint4){0,0,0,0};
  u0.q = (t >= 3) ? *(const uint4*)(base - 3*CONVDIM) : (uint4){0,0,0,0};
  US8 o;
  #pragma unroll
  for (int j = 0; j < 8; j++){
    float4 w = *(const float4*)&cw[(c0+j)*4];
    float v = cb[c0+j];
    v += bf2f(u3.s[j])*w.w + bf2f(u2.s[j])*w.z + bf2f(u1.s[j])*w.y + bf2f(u0.s[j])*w.x;
    o.s[j] = f2bf(siluf(v));
  }
  *(uint4*)&cv[(size_t)row*CONVDIM + c0] = o.q;
}

// ---------------- dt softplus + per-chunk inclusive cumsum of dt*A ----------------
__global__ void dtcum_kernel(const float* __restrict__ drf, const float* __restrict__ drb,
                             const float* __restrict__ dbf, const float* __restrict__ alf,
                             const float* __restrict__ dbb, const float* __restrict__ alb,
                             float* __restrict__ dtf, float* __restrict__ dtb,
                             float* __restrict__ acs){
  int tid = threadIdx.x;
  int wid = blockIdx.x*4 + (tid >> 6);      // 0..2047 = dbh*32 + c
  int tau = tid & 63;
  int c = wid & 31, dbh = wid >> 5;
  int h = dbh & 15, b = (dbh >> 4) & 1, dir = dbh >> 5;
  const float* dr = dir ? drb : drf;
  size_t row = (size_t)b*L_SEQ + c*QCH + tau;
  float raw = dr[row*NHEADS + h];
  float bias = (dir ? dbb : dbf)[h];
  float dtv = softplusf(raw + bias);
  float a = -expf((dir ? alb : alf)[h]);
  (dir ? dtb : dtf)[row*NHEADS + h] = dtv;
  float v = dtv * a;
  #pragma unroll
  for (int off = 1; off < 64; off <<= 1){
    float u = __shfl_up(v, off);
    if (tau >= off) v += u;
  }
  acs[(size_t)dbh*L_SEQ + c*QCH + tau] = v;
}

// ---------------- K_Y (MFMA, fused G): intra Y + chunk-state S^T, per (dir,b,h,chunk)
// Phase 1: stage C[t][n], B[s][n]; G = C·B^T (16 MFMA, registers).
// Phase 2: BwT[n][s] (overlays sC, reads sBr). Phase 3: Gh (from regs) + dxT
// (overlay sBr). Phase 4: Y = Gh·dxT^T, S^T = dxT·BwT^T.
__global__ __launch_bounds__(256) void intra_kernel(
    const unsigned short* __restrict__ cvf, const unsigned short* __restrict__ cvb,
    const float* __restrict__ dtf, const float* __restrict__ dtb,
    const float* __restrict__ acs,
    float* __restrict__ yf, float* __restrict__ yb,
    unsigned short* __restrict__ S16f, unsigned short* __restrict__ S16b){
  int c = blockIdx.x, dbh = blockIdx.y;
  int h = dbh & 15, b = (dbh >> 4) & 1, dir = dbh >> 5;
  const unsigned short* cv = dir ? cvb : cvf;
  const float* dtp = dir ? dtb : dtf;
  float* y = dir ? yb : yf;
  unsigned short* S16 = dir ? S16b : S16f;
  int tid = threadIdx.x, lane = tid & 63, w = tid >> 6;
  int l15 = lane & 15, lhi = lane >> 4;

  __shared__ __align__(16) unsigned short smem[2*64*128];   // 32KB, phased reuse
  unsigned short* sC   = smem;               // phase1: C[t][n]   (16KB)
  unsigned short* sBr  = smem + 8192;        // phase1: B[s][n]   (16KB)
  unsigned short* sBwT = smem;               // phase2: BwT[n][s] (16KB, overlays sC)
  unsigned short* sGh  = smem + 8192;        // phase3: Gh[t][s]  (8KB, overlays sBr)
  unsigned short* sDxT = smem + 8192 + 4096; // phase3: dxT[p][s] (8KB)
  __shared__ float a_sh[QCH], dt_sh[QCH], w_sh[QCH];

  size_t r0 = (size_t)b*L_SEQ + (size_t)c*QCH;
  if (tid < 64){
    a_sh[tid]  = acs[(size_t)dbh*L_SEQ + c*QCH + tid];
    dt_sh[tid] = dtp[(r0 + tid)*NHEADS + h];
  }
  // stage C and B (row-major, kx chunk swizzle)
  #pragma unroll
  for (int k = 0; k < 4; k++){
    int cid = k*256 + tid;
    int row = cid >> 4, slot = cid & 15;
    US8 ub_, uc_;
    ub_.q = *(const uint4*)&cv[(r0+row)*CONVDIM + DINNER + slot*8];
    uc_.q = *(const uint4*)&cv[(r0+row)*CONVDIM + DINNER + DSTATE + slot*8];
    *(uint4*)&sBr[row*128 + (slot*8 ^ kx(row))] = ub_.q;
    *(uint4*)&sC [row*128 + (slot*8 ^ kx(row))] = uc_.q;
  }
  // x into regs (dxT source)
  US8 xq[2];
  #pragma unroll
  for (int k = 0; k < 2; k++){
    int cid = k*256 + tid;
    int s2 = cid >> 3, p0 = (cid & 7)*8;
    xq[k].q = *(const uint4*)&cv[(r0+s2)*CONVDIM + h*HEADDIM + p0];
  }
  __syncthreads();
  if (tid < 64) w_sh[tid] = expf(a_sh[63] - a_sh[tid]);
  // G[t][s] = sum_n C[t][n]*B[s][n]
  int t0 = w*16;
  bf16x8 cf[4];
  #pragma unroll
  for (int ks = 0; ks < 4; ks++){
    int r = t0 + l15;
    cf[ks] = *(const bf16x8*)&sC[r*128 + ((ks*32 + lhi*8) ^ kx(r))];
  }
  f32x4 accG[4];
  #pragma unroll
  for (int j = 0; j < 4; j++) accG[j] = (f32x4){0.f,0.f,0.f,0.f};
  #pragma unroll
  for (int j = 0; j < 4; j++){
    #pragma unroll
    for (int ks = 0; ks < 4; ks++){
      int r = j*16 + l15;
      bf16x8 wf = *(const bf16x8*)&sBr[r*128 + ((ks*32 + lhi*8) ^ kx(r))];
      accG[j] = __builtin_amdgcn_mfma_f32_16x16x32_bf16(cf[ks], wf, accG[j], 0, 0, 0);
    }
  }
  __syncthreads();   // sC dead -> sBwT region writable; sBr still live
  // BwT[n][s] = w_sh[s]*B[s][n], from LDS
  #pragma unroll
  for (int k = 0; k < 4; k++){
    int cid = k*256 + tid;
    int s2 = cid >> 4, n0 = (cid & 15)*8;
    US8 u; u.q = *(const uint4*)&sBr[s2*128 + (n0 ^ kx(s2))];
    float wv = w_sh[s2];
    #pragma unroll
    for (int j = 0; j < 8; j++){
      int n = n0 + j;
      sBwT[n*64 + (s2 ^ kx(n))] = f2bf(bf2f(u.s[j]) * wv);
    }
  }
  __syncthreads();   // sBr dead -> sGh/sDxT region writable
  // Gh[t][s] = (s<=t) ? G*exp(a[t]-a[s]) : 0 (from accG regs)
  #pragma unroll
  for (int j = 0; j < 4; j++){
    int s2 = j*16 + l15;
    float as2 = a_sh[s2];
    #pragma unroll
    for (int r = 0; r < 4; r++){
      int t = t0 + lhi*4 + r;
      float v = (s2 <= t) ? accG[j][r]*expf(a_sh[t] - as2) : 0.f;
      sGh[t*64 + (s2 ^ kx(t))] = f2bf(v);
    }
  }
  // dxT[p][s] = dt[s]*x[s][p]
  #pragma unroll
  for (int k = 0; k < 2; k++){
    int cid = k*256 + tid;
    int s2 = cid >> 3, p0 = (cid & 7)*8;
    float d = dt_sh[s2];
    #pragma unroll
    for (int j = 0; j < 8; j++){
      int p = p0 + j;
      sDxT[p*64 + (s2 ^ kx(p))] = f2bf(bf2f(xq[k].s[j]) * d);
    }
  }
  __syncthreads();

  bf16x8 aY[2], aS[2];
  #pragma unroll
  for (int ks = 0; ks < 2; ks++){
    int rg = t0 + l15;
    aY[ks] = *(const bf16x8*)&sGh [rg*64 + ((ks*32 + lhi*8) ^ kx(rg))];
    aS[ks] = *(const bf16x8*)&sDxT[rg*64 + ((ks*32 + lhi*8) ^ kx(rg))];
  }
  // Y[t][p] = sum_s Gh[t][s] * dxT[p][s]
  f32x4 accY[4];
  #pragma unroll
  for (int j = 0; j < 4; j++) accY[j] = (f32x4){0.f,0.f,0.f,0.f};
  #pragma unroll
  for (int j = 0; j < 4; j++){
    #pragma unroll
    for (int ks = 0; ks < 2; ks++){
      int rp = j*16 + l15;
      bf16x8 wf = *(const bf16x8*)&sDxT[rp*64 + ((ks*32 + lhi*8) ^ kx(rp))];
      accY[j] = __builtin_amdgcn_mfma_f32_16x16x32_bf16(aY[ks], wf, accY[j], 0, 0, 0);
    }
  }
  // S^T[p][n] = sum_s dxT[p][s] * BwT[n][s]
  f32x4 accS[8];
  #pragma unroll
  for (int j = 0; j < 8; j++) accS[j] = (f32x4){0.f,0.f,0.f,0.f};
  #pragma unroll
  for (int j = 0; j < 8; j++){
    #pragma unroll
    for (int ks = 0; ks < 2; ks++){
      int rn = j*16 + l15;
      bf16x8 wf = *(const bf16x8*)&sBwT[rn*64 + ((ks*32 + lhi*8) ^ kx(rn))];
      accS[j] = __builtin_amdgcn_mfma_f32_16x16x32_bf16(aS[ks], wf, accS[j], 0, 0, 0);
    }
  }
  // epilogues
  #pragma unroll
  for (int j = 0; j < 4; j++){
    #pragma unroll
    for (int r = 0; r < 4; r++){
      int t = t0 + lhi*4 + r, p = j*16 + l15;
      y[(r0 + t)*DINNER + h*HEADDIM + p] = accY[j][r];
    }
  }
  size_t sbase = ((size_t)((b*NHEADS + h)*NCH + c))*8192;
  #pragma unroll
  for (int j = 0; j < 8; j++){
    #pragma unroll
    for (int r = 0; r < 4; r++){
      int p = t0 + lhi*4 + r, n = j*16 + l15;
      S16[sbase + p*128 + n] = f2bf(accS[j][r]);
    }
  }
}

// ---------------- K_S: inter-chunk state recurrence (elementwise over [p][n]) --------
__global__ void chunkscan_kernel(const unsigned short* __restrict__ S16f,
                                 const unsigned short* __restrict__ S16b,
                                 const float* __restrict__ acs,
                                 unsigned short* __restrict__ hin16){
  __shared__ float sa[NCH];
  int tid = threadIdx.x;
  int dbh = blockIdx.x >> 4;
  int e0 = ((blockIdx.x & 15)*256 + tid)*2;
  int bh = dbh & 31, dir = dbh >> 5;
  const unsigned short* S16 = dir ? S16b : S16f;
  if (tid < NCH) sa[tid] = expf(acs[(size_t)dbh*L_SEQ + tid*QCH + 63]);
  __syncthreads();
  float h0 = 0.f, h1 = 0.f;
  #pragma unroll 8
  for (int c = 0; c < NCH; ++c){
    size_t sidx = ((size_t)(bh*NCH + c))*8192 + e0;
    size_t hidx = ((size_t)(dbh*NCH + c))*8192 + e0;
    unsigned sv = *(const unsigned*)&S16[sidx];
    unsigned hv = (unsigned)f2bf(h0) | ((unsigned)f2bf(h1) << 16);
    *(unsigned*)&hin16[hidx] = hv;
    float ea = sa[c];
    h0 = ea*h0 + bf2f((unsigned short)(sv & 0xffff));
    h1 = ea*h1 + bf2f((unsigned short)(sv >> 16));
  }
}

// ---------------- K_I (MFMA): Y = y_intra + e[t]*C·h_in + D*x -> bf16 yg -------------
__global__ __launch_bounds__(256) void inter_kernel(
    const unsigned short* __restrict__ cvf, const unsigned short* __restrict__ cvb,
    const float* __restrict__ acs, const unsigned short* __restrict__ hin16,
    const float* __restrict__ Df, const float* __restrict__ Db,
    const float* __restrict__ yf, const float* __restrict__ yb,
    unsigned short* __restrict__ ygf, unsigned short* __restrict__ ygb){
  int c = blockIdx.x, dbh = blockIdx.y;
  int h = dbh & 15, b = (dbh >> 4) & 1, dir = dbh >> 5;
  const unsigned short* cv = dir ? cvb : cvf;
  const float* y = dir ? yb : yf;
  unsigned short* yg = dir ? ygb : ygf;
  float Dh = (dir ? Db : Df)[h];
  int tid = threadIdx.x, lane = tid & 63, w = tid >> 6;
  int l15 = lane & 15, lhi = lane >> 4;
  __shared__ unsigned short sC [64*128];   // C[t][n]  (A)
  __shared__ unsigned short sHT[64*128];   // hT[p][n] (W)
  __shared__ float e_sh[QCH];
  size_t r0 = (size_t)b*L_SEQ + (size_t)c*QCH;
  size_t hbase = ((size_t)(dbh*NCH + c))*8192;
  if (tid < 64) e_sh[tid] = expf(acs[(size_t)dbh*L_SEQ + c*QCH + tid]);
  #pragma unroll
  for (int k = 0; k < 4; k++){
    int cid = k*256 + tid;
    int row = cid >> 4, slot = cid & 15;
    US8 uc, uh;
    uc.q = *(const uint4*)&cv[(r0+row)*CONVDIM + DINNER + DSTATE + slot*8];
    uh.q = *(const uint4*)&hin16[hbase + cid*8];
    *(uint4*)&sC [row*128 + (slot*8 ^ kx(row))] = uc.q;
    *(uint4*)&sHT[row*128 + (slot*8 ^ kx(row))] = uh.q;
  }
  __syncthreads();
  int t0 = w*16;
  bf16x8 af[4];
  #pragma unroll
  for (int ks = 0; ks < 4; ks++){
    int r = t0 + l15;
    af[ks] = *(const bf16x8*)&sC[r*128 + ((ks*32 + lhi*8) ^ kx(r))];
  }
  f32x4 acc[4];
  #pragma unroll
  for (int j = 0; j < 4; j++) acc[j] = (f32x4){0.f,0.f,0.f,0.f};
  #pragma unroll
  for (int j = 0; j < 4; j++){
    #pragma unroll
    for (int ks = 0; ks < 4; ks++){
      int r = j*16 + l15;
      bf16x8 wf = *(const bf16x8*)&sHT[r*128 + ((ks*32 + lhi*8) ^ kx(r))];
      acc[j] = __builtin_amdgcn_mfma_f32_16x16x32_bf16(af[ks], wf, acc[j], 0, 0, 0);
    }
  }
  #pragma unroll
  for (int j = 0; j < 4; j++){
    #pragma unroll
    for (int r = 0; r < 4; r++){
      int t = t0 + lhi*4 + r, p = j*16 + l15;
      size_t row = r0 + t;
      float xv = bf2f(cv[row*CONVDIM + h*HEADDIM + p]);
      float v = y[row*DINNER + h*HEADDIM + p] + e_sh[t]*acc[j][r] + Dh*xv;
      yg[row*DINNER + h*HEADDIM + p] = f2bf(v);
    }
  }
}

// ---------------- gate (silu(z)) + rmsnorm, all bf16, in place on yg ----------------
__global__ void gate_norm_kernel(unsigned short* __restrict__ ygf, unsigned short* __restrict__ ygb,
                                 const unsigned short* __restrict__ z16f, const unsigned short* __restrict__ z16b,
                                 const float* __restrict__ gwf, const float* __restrict__ gwb){
  __shared__ float red[4];
  int row = blockIdx.x; int dir = blockIdx.y;
  int tid = threadIdx.x;
  unsigned short* yg = (dir ? ygb : ygf) + (size_t)row*DINNER;
  const unsigned short* z = (dir ? z16b : z16f) + (size_t)row*DINNER;
  const float* gw = dir ? gwb : gwf;
  int d = tid*4;
  US4 uy, uz;
  uy.q = *(const uint2*)&yg[d];
  uz.q = *(const uint2*)&z[d];
  float v[4]; float ss = 0.f;
  #pragma unroll
  for (int k = 0; k < 4; k++){
    float val = bf2f(uy.s[k]) * siluf(bf2f(uz.s[k]));
    v[k] = val; ss += val*val;
  }
  ss = blockReduceSum256(ss, red);   // __syncthreads inside: reads precede writes
  float scale = rsqrtf(ss*(1.f/DINNER) + 1e-5f);
  float4 w4 = *(const float4*)&gw[d];
  US4 o;
  o.s[0] = f2bf(v[0]*scale*w4.x);
  o.s[1] = f2bf(v[1]*scale*w4.y);
  o.s[2] = f2bf(v[2]*scale*w4.z);
  o.s[3] = f2bf(v[3]*scale*w4.w);
  *(uint2*)&yg[d] = o.q;
}

extern "C" void kernel_launch(void* const* d_in, const int* in_sizes, int n_in,
                              void* d_out, int out_size, void* d_ws, size_t ws_size,
                              hipStream_t stream) {
  const float* x      = (const float*)d_in[0];
  const float* norm_w = (const float*)d_in[1];
  const float* op_w   = (const float*)d_in[2];
  const float* op_b   = (const float*)d_in[3];
  const float* f_in_w    = (const float*)d_in[4];
  const float* f_conv_w  = (const float*)d_in[5];
  const float* f_conv_b  = (const float*)d_in[6];
  const float* f_dt_bias = (const float*)d_in[7];
  const float* f_A_log   = (const float*)d_in[8];
  const float* f_D       = (const float*)d_in[9];
  const float* f_gnorm_w = (const float*)d_in[10];
  const float* f_outp_w  = (const float*)d_in[11];
  const float* b_in_w    = (const float*)d_in[12];
  const float* b_conv_w  = (const float*)d_in[13];
  const float* b_conv_b  = (const float*)d_in[14];
  const float* b_dt_bias = (const float*)d_in[15];
  const float* b_A_log   = (const float*)d_in[16];
  const float* b_D       = (const float*)d_in[17];
  const float* b_gnorm_w = (const float*)d_in[18];
  const float* b_outp_w  = (const float*)d_in[19];
  float* out = (float*)d_out;

  float* ws = (float*)d_ws;
  size_t off = 0;
  unsigned short* u16f = (unsigned short*)(ws + off);
  unsigned short* u16b = u16f + (size_t)ROWS*DHALF;      off += (size_t)ROWS*DHALF;
  unsigned short* z16f = (unsigned short*)(ws + off);    off += (size_t)ROWS*DINNER/2;
  unsigned short* z16b = (unsigned short*)(ws + off);    off += (size_t)ROWS*DINNER/2;
  unsigned short* xbc16f = (unsigned short*)(ws + off);  off += (size_t)ROWS*CONVDIM/2;
  unsigned short* xbc16b = (unsigned short*)(ws + off);  off += (size_t)ROWS*CONVDIM/2;
  float* draw_f = ws + off; off += (size_t)ROWS*NHEADS;
  float* draw_b = ws + off; off += (size_t)ROWS*NHEADS;
  unsigned short* cv16f = (unsigned short*)(ws + off); off += (size_t)ROWS*CONVDIM/2;
  unsigned short* cv16b = (unsigned short*)(ws + off); off += (size_t)ROWS*CONVDIM/2;
  float* dt_f = ws + off; off += (size_t)ROWS*NHEADS;
  float* dt_b = ws + off; off += (size_t)ROWS*NHEADS;
  float* y_f  = ws + off; off += (size_t)ROWS*DINNER;
  float* y_b  = ws + off; off += (size_t)ROWS*DINNER;
  unsigned short* yg16f = (unsigned short*)(ws + off); off += (size_t)ROWS*DINNER/2;
  unsigned short* yg16b = (unsigned short*)(ws + off); off += (size_t)ROWS*DINNER/2;
  float* acs  = ws + off; off += (size_t)64*L_SEQ;
  unsigned short* S16f = (unsigned short*)(ws + off); off += (size_t)32*NCH*8192/2;
  unsigned short* S16b = (unsigned short*)(ws + off); off += (size_t)32*NCH*8192/2;
  unsigned short* hin16 = (unsigned short*)(ws + off); off += (size_t)64*NCH*8192/2;
  unsigned short* w16_fin  = (unsigned short*)(ws + off); off += (size_t)NPADIN*DHALF/2;
  unsigned short* w16_bin  = (unsigned short*)(ws + off); off += (size_t)NPADIN*DHALF/2;
  unsigned short* w16_fout = (unsigned short*)(ws + off); off += (size_t)DHALF*DINNER/2;
  unsigned short* w16_bout = (unsigned short*)(ws + off); off += (size_t)DHALF*DINNER/2;
  unsigned short* w16_op   = (unsigned short*)(ws + off); off += (size_t)DMODEL*DMODEL/2;
  // cat (bf16 [ROWS][1024]) overlays z16f+z16b region (dead after gate_norm)
  unsigned short* cat16 = z16f;

  // 1. merged prep: rmsnorm+split | weight conversions (one launch)
  {
    const int TOT = 2*NPADIN*DHALF + 2*DHALF*DINNER + DMODEL*DMODEL;
    prep_kernel<<<ROWS + TOT/4/256, 256, 0, stream>>>(
        x, norm_w, u16f, u16b,
        f_in_w, b_in_w, f_outp_w, b_outp_w, op_w,
        w16_fin, w16_bin, w16_fout, w16_bout, w16_op);
  }
  // 2. in-proj GEMM, both dirs in one launch; 3-way split epilogue (TM=128)
  gemm_bf16_t<128><<<dim3(NPADIN/128, ROWS/128, 2), 256, 0, stream>>>(
      u16f, u16b, DHALF, w16_fin, w16_bin,
      nullptr, 0, nullptr, nullptr,
      z16f, z16b, DINNER,
      xbc16f, xbc16b, DINNER, CONVDIM,
      draw_f, draw_b, DINNER+CONVDIM, NHEADS,
      0, 0,
      ROWS, DINPROJ, DHALF);
  // 3. conv + silu (bf16 in/out, both dirs per block)
  conv_silu_kernel<<<ROWS, 320, 0, stream>>>(
      xbc16f, xbc16b, f_conv_w, f_conv_b, b_conv_w, b_conv_b, cv16f, cv16b);
  // 4. dt softplus + chunked cumsum
  dtcum_kernel<<<512, 256, 0, stream>>>(
      draw_f, draw_b, f_dt_bias, f_A_log, b_dt_bias, b_A_log, dt_f, dt_b, acs);
  // 5. SSD: intra (G fused in), chunk recurrence, inter (-> bf16 yg)
  intra_kernel<<<dim3(32, 64), 256, 0, stream>>>(cv16f, cv16b, dt_f, dt_b, acs,
                                                 y_f, y_b, S16f, S16b);
  chunkscan_kernel<<<1024, 256, 0, stream>>>(S16f, S16b, acs, hin16);
  inter_kernel<<<dim3(32, 64), 256, 0, stream>>>(cv16f, cv16b, acs, hin16, f_D, b_D,
                                                 y_f, y_b, yg16f, yg16b);
  // 6. gate + rmsnorm (all bf16, in place on yg)
  gate_norm_kernel<<<dim3(ROWS, 2), 256, 0, stream>>>(
      yg16f, yg16b, z16f, z16b, f_gnorm_w, b_gnorm_w);
  // 7. out-proj GEMM, both dirs -> cat16 (dir1 time-flipped, coff=512); TM=64
  gemm_bf16_t<64><<<dim3(DHALF/128, ROWS/64, 2), 256, 0, stream>>>(
      yg16f, yg16b, DINNER, w16_fout, w16_bout,
      nullptr, 0, nullptr, nullptr,
      cat16, cat16, DMODEL,
      nullptr, nullptr, 1<<30, 0,
      nullptr, nullptr, 1<<30, 0,
      DHALF, 1,
      ROWS, DHALF, DINNER);
  // 8. final projection + bias + residual (fp32 out); TM=64
  gemm_bf16_t<64><<<dim3(DMODEL/128, ROWS/64, 1), 256, 0, stream>>>(
      cat16, nullptr, DMODEL, w16_op, nullptr,
      out, DMODEL, op_b, x,
      nullptr, nullptr, 0,
      nullptr, nullptr, 1<<30, 0,
      nullptr, nullptr, 1<<30, 0,
      0, 0,
      ROWS, DMODEL, DMODEL);
}